// Round 5
// baseline (381.633 us; speedup 1.0000x reference)
//
#include <hip/hip_runtime.h>
#include <hip/hip_bf16.h>
#include <math.h>

// ---------------------------------------------------------------------------
// PatentCitationMoEModule — MI355X implementation, round 11
//  Round 9 (356.3 us) base [round-10 launch_bounds(256,8) REVERTED: forcing
//  32 VGPR killed gather MLP — 59->62us + L2 thrash; keep 72-VGPR codegen],
//  keeping round-10's pack-in-pool merge, plus:
//   - HEAD FOLDING: logits are linear in eo, so W3h[e] = W3_e @ head_W
//     ([1024,16] bf16, pad 10->16) and b3h[e] = b3_e @ head_W are computed at
//     prep time (256 blocks replace the 1024-block W3 transpose). GEMM-3
//     becomes N=16 (MFMA/4, B 8.4MB->0.26MB, Oc 9.4MB->0.3MB); head becomes
//     80 trivial blocks (was 2048 blocks x 20KB head_W reads).
//  Fixed harness overhead (ws poison fill + d_in restore) untouched.
// ---------------------------------------------------------------------------

#define LN_EPS 1e-5f

typedef __bf16 bf16_t;
typedef __bf16 bf16x8 __attribute__((ext_vector_type(8)));
typedef float f32x4 __attribute__((ext_vector_type(4)));

struct f4x2 { float4 a, b; };
__device__ __forceinline__ f4x2 ldA8(const float* p) {
  f4x2 v; v.a = *(const float4*)p; v.b = *(const float4*)(p + 4); return v;
}
__device__ __forceinline__ bf16x8 cvt8(const f4x2& v) {
  bf16x8 o;
  o[0] = (bf16_t)v.a.x; o[1] = (bf16_t)v.a.y; o[2] = (bf16_t)v.a.z; o[3] = (bf16_t)v.a.w;
  o[4] = (bf16_t)v.b.x; o[5] = (bf16_t)v.b.y; o[6] = (bf16_t)v.b.z; o[7] = (bf16_t)v.b.w;
  return o;
}

// ----------------------------- prep_kq --------------------------------------
// kq_out[0..255] = Wk @ (gc@Wq + bq);  kq_out[256] = (gc@Wq + bq) . bk
// Also zeroes the pool->pack completion counter (ws is poisoned every iter).
__global__ __launch_bounds__(256)
void prep_kq_kernel(const float* __restrict__ Wq, const float* __restrict__ bq,
                    const float* __restrict__ Wk, const float* __restrict__ bk,
                    const float* __restrict__ gc, float* __restrict__ kq_out,
                    int* __restrict__ done_ctr) {
  __shared__ float q[256];
  __shared__ float red[4];
  const int t = threadIdx.x, bi = blockIdx.x;
  if (bi == 0 && t == 0) *done_ctr = 0;
  float s = bq[t];
  for (int d = 0; d < 256; d++) s += gc[d] * Wq[d * 256 + t];
  q[t] = s;
  __syncthreads();
  const int rl = t >> 5, sl = t & 31;
  const int r = bi * 8 + rl;
  float p = 0.f;
#pragma unroll
  for (int i = 0; i < 8; i++) { const int d = sl + 32 * i; p += Wk[r * 256 + d] * q[d]; }
#pragma unroll
  for (int o = 16; o > 0; o >>= 1) p += __shfl_down(p, o, 32);
  if (sl == 0) kq_out[r] = p;
  if (bi == 0) {
    float z2 = q[t] * bk[t];
    const int lane = t & 63, wave = t >> 6;
#pragma unroll
    for (int o = 32; o > 0; o >>= 1) z2 += __shfl_down(z2, o);
    if (lane == 0) red[wave] = z2;
    __syncthreads();
    if (t == 0) kq_out[256] = red[0] + red[1] + red[2] + red[3];
  }
}

// ------- merged: xbar (bid<2048) + W1/W2 transpose + W3@head_W fold ---------
// FT-B: frag (nt,kt) = 64 lanes x 8 bf16; lane holds n=nt*16+(lane&15),
// k = kt*32+(lane>>4)*8 .. +7.  Flat elem offset: ((nt*(K/32)+kt)*64+lane)*8.
__global__ __launch_bounds__(256)
void xbar_transpose(const float* __restrict__ W1, const float* __restrict__ W2,
                    const float* __restrict__ W3, bf16_t* __restrict__ B1,
                    bf16_t* __restrict__ B2, bf16_t* __restrict__ B3h,
                    float* __restrict__ b3h_g,
                    const float* __restrict__ b3, const float* __restrict__ head_W,
                    const int* __restrict__ ipc_idx, const int* __restrict__ role_idx,
                    const int* __restrict__ maskp,
                    const float* __restrict__ ipc_emb, const float* __restrict__ role_emb,
                    const float* __restrict__ kq_qbk, float* __restrict__ xbar_g) {
  __shared__ __align__(16) float smem[4480];  // 17.9 KB, aliased per path
  const int bid = blockIdx.x;
  const int t = threadIdx.x, lane = t & 63;

  if (bid < 2048) {
    // ================= xbar path (round-9 register-index version) ==========
    const int b = bid, wave = t >> 6;
    float* sred = smem;                 // [4 waves][64 lanes][17] partials
    float* scores_s = smem + 4352;      // [64]
    float* attn_s = smem + 4416;        // [64]
    const float4 kq = *(const float4*)(kq_qbk + lane * 4);
    const float qbk = kq_qbk[256];
    const int rbase = b * 64 + wave * 16;
    int4 m4[4], i4[4], r4[4];
#pragma unroll
    for (int j = 0; j < 4; j++) {
      m4[j] = *(const int4*)(maskp + rbase + j * 4);
      i4[j] = *(const int4*)(ipc_idx + rbase + j * 4);
      r4[j] = *(const int4*)(role_idx + rbase + j * 4);
    }
    // phase A: branch-free gather (masked -> zero padding row 0) + per-lane dot
#pragma unroll
    for (int i = 0; i < 16; i++) {
      const int mki = (&m4[i / 4].x)[i % 4];
      const int ii = mki ? (&i4[i / 4].x)[i % 4] : 0;
      const int ri = mki ? (&r4[i / 4].x)[i % 4] : 0;
      const float4 xe = *(const float4*)(ipc_emb + (size_t)ii * 256 + lane * 4);
      const float4 re = *(const float4*)(role_emb + (size_t)ri * 256 + lane * 4);
      sred[(wave * 64 + lane) * 17 + i] =
          (xe.x + re.x) * kq.x + (xe.y + re.y) * kq.y +
          (xe.z + re.z) * kq.z + (xe.w + re.w) * kq.w;
    }
    __syncthreads();
    // phase B: per-wave LDS-transpose reduce
    {
      const int i_r = lane & 15, g = lane >> 4;
      float s = 0.f;
#pragma unroll
      for (int j = 0; j < 16; j++) s += sred[(wave * 64 + g * 16 + j) * 17 + i_r];
      s += __shfl_xor(s, 16);
      s += __shfl_xor(s, 32);
      const int mval = (&m4[i_r / 4].x)[i_r % 4];
      if (lane < 16) scores_s[wave * 16 + lane] = mval ? (s + qbk) : -1e9f;
    }
    __syncthreads();
    // phase C: softmax over 64 scores (wave 0)
    if (wave == 0) {
      const float sv = scores_s[lane];
      float m = sv;
#pragma unroll
      for (int o = 32; o > 0; o >>= 1) m = fmaxf(m, __shfl_xor(m, o));
      const float ev = expf(sv - m);
      float sum = ev;
#pragma unroll
      for (int o = 32; o > 0; o >>= 1) sum += __shfl_xor(sum, o);
      attn_s[lane] = ev / sum;
    }
    __syncthreads();
    // phase D: branch-free re-gather (L2-hot) + attn-weighted sum
    float p0 = 0.f, p1 = 0.f, p2 = 0.f, p3 = 0.f;
#pragma unroll
    for (int i = 0; i < 16; i++) {
      const int mki = (&m4[i / 4].x)[i % 4];
      const int ii = mki ? (&i4[i / 4].x)[i % 4] : 0;
      const int ri = mki ? (&r4[i / 4].x)[i % 4] : 0;
      const float a = attn_s[wave * 16 + i];  // exactly 0 for masked rows
      const float4 xe = *(const float4*)(ipc_emb + (size_t)ii * 256 + lane * 4);
      const float4 re = *(const float4*)(role_emb + (size_t)ri * 256 + lane * 4);
      p0 += a * (xe.x + re.x); p1 += a * (xe.y + re.y);
      p2 += a * (xe.z + re.z); p3 += a * (xe.w + re.w);
    }
    __syncthreads();  // sred region no longer read; reuse as part[4][256]
    *(float4*)&smem[wave * 256 + lane * 4] = make_float4(p0, p1, p2, p3);
    __syncthreads();
    xbar_g[(size_t)b * 256 + t] = smem[t] + smem[256 + t] + smem[512 + t] + smem[768 + t];
    return;
  }

  const int bid2 = bid - 2048;
  if (bid2 >= 3072) {
    // ============ W3@head_W fold: 256 blocks, (e, kt) = (q>>5, q&31) ========
    const int q = bid2 - 3072;
    const int e = q >> 5, kt = q & 31;
    const int wave = t >> 6;
    float* w3h_s = smem;  // [32][16]
    for (int i = t; i < 32 * 16; i += 256) w3h_s[i] = 0.f;
    __syncthreads();
    const int ob = lane * 8;
#pragma unroll
    for (int r = 0; r < 8; r++) {
      const int kl = wave * 8 + r;                 // local k in [0,32)
      const int k = kt * 32 + kl;
      const f4x2 wv = ldA8(W3 + ((size_t)e * 1024 + k) * 512 + ob);
      for (int c = 0; c < 10; c++) {
        float p = wv.a.x * head_W[(ob + 0) * 10 + c] + wv.a.y * head_W[(ob + 1) * 10 + c] +
                  wv.a.z * head_W[(ob + 2) * 10 + c] + wv.a.w * head_W[(ob + 3) * 10 + c] +
                  wv.b.x * head_W[(ob + 4) * 10 + c] + wv.b.y * head_W[(ob + 5) * 10 + c] +
                  wv.b.z * head_W[(ob + 6) * 10 + c] + wv.b.w * head_W[(ob + 7) * 10 + c];
#pragma unroll
        for (int o = 32; o > 0; o >>= 1) p += __shfl_down(p, o);
        if (lane == 0) w3h_s[kl * 16 + c] = p;
      }
    }
    __syncthreads();
    if (wave == 0) {
      // write FT-B fragment for this kt (NT=16 -> single nt)
      bf16x8 o8;
      const int n_l = lane & 15, k_l = (lane >> 4) * 8;
#pragma unroll
      for (int j = 0; j < 8; j++) o8[j] = (bf16_t)w3h_s[(k_l + j) * 16 + n_l];
      *(bf16x8*)(B3h + (size_t)e * 16 * 1024 + ((size_t)kt * 64 + lane) * 8) = o8;
    }
    if (kt == 0 && wave == 1) {
      // b3h[e] = b3_e @ head_W (pad to 16 with zeros)
      for (int c = 0; c < 10; c++) {
        float p = 0.f;
#pragma unroll
        for (int j = 0; j < 8; j++) p += b3[e * 512 + ob + j] * head_W[(ob + j) * 10 + c];
#pragma unroll
        for (int o = 32; o > 0; o >>= 1) p += __shfl_down(p, o);
        if (lane == 0) b3h_g[e * 16 + c] = p;
      }
      if (lane >= 10 && lane < 16) b3h_g[e * 16 + lane] = 0.f;
    }
    return;
  }

  // ================= W1/W2 transpose path =================
  const float* W; bf16_t* Bft; int K, N, e, n0, k0;
  if (bid2 < 1024) {            // W1: K=512, N=1024, 128 tiles/expert
    W = W1; Bft = B1; K = 512; N = 1024;
    e = bid2 >> 7; const int r = bid2 & 127;
    n0 = (r & 15) * 64; k0 = (r >> 4) * 64;
  } else {                      // W2: K=1024, N=1024, 256 tiles/expert
    W = W2; Bft = B2; K = 1024; N = 1024;
    const int q = bid2 - 1024; e = q >> 8; const int r = q & 255;
    n0 = (r & 15) * 64; k0 = (r >> 4) * 64;
  }
  float (*tile)[65] = (float(*)[65])smem;  // 64x65 fits in 4480 floats
  const float* Wp = W + (size_t)e * K * N;
  bf16_t* Bp = Bft + (size_t)e * N * K;
  const int tq = t & 15, th = t >> 4;  // 16 x 16
#pragma unroll
  for (int i = 0; i < 4; i++) {
    const int row = th + 16 * i;  // k-dim
    *(float4*)&tile[row][tq * 4] = *(const float4*)(Wp + (size_t)(k0 + row) * N + n0 + tq * 4);
  }
  __syncthreads();
  const int sub = t >> 6;
  const int nk = K >> 5;
#pragma unroll
  for (int it = 0; it < 2; it++) {
    const int fid = sub + it * 4;            // 8 frag-tiles in a 64x64 tile
    const int ntl = fid & 3, ktl = fid >> 2;
    const int n_l = ntl * 16 + (lane & 15);
    const int k_l = ktl * 32 + (lane >> 4) * 8;
    bf16x8 o;
#pragma unroll
    for (int j = 0; j < 8; j++) o[j] = (bf16_t)tile[k_l + j][n_l];
    const size_t idx = ((((size_t)(n0 >> 4) + ntl) * nk + (k0 >> 5) + ktl) * 64 + lane) * 8;
    *(bf16x8*)(Bp + idx) = o;
  }
}

// ------------- pool: pooled = xbar@Wv + bv, LN, gate, top2 ------------------
// Waves split the d(K)-range so Wv is read once per block (64 MB total).
// Last block to finish (device-scope counter) runs the pack stage inline.
__global__ __launch_bounds__(256)
void pool_kernel(const float* __restrict__ xbar_g, const float* __restrict__ Wv,
                 const float* __restrict__ bvec,
                 const float* __restrict__ ln_g, const float* __restrict__ ln_b,
                 const float* __restrict__ gate_W, const float* __restrict__ gate_b,
                 const float* __restrict__ expert_biases,
                 float* __restrict__ out_idx_f, int* __restrict__ ws_idx,
                 float* __restrict__ ws_gw, int* __restrict__ done_ctr,
                 int* __restrict__ list_token, int* __restrict__ a_of,
                 int* __restrict__ offsets_g) {
  const int rb = blockIdx.x * 8;
  __shared__ __align__(16) float xs[8][256];       // 8 input rows
  __shared__ __align__(16) float pp[4][8][256];    // per-wave d-partials
  __shared__ int is_last;
  const int t = threadIdx.x, wave = t >> 6, lane = t & 63;
  for (int i = t; i < 512; i += 256)
    ((float4*)xs)[i] = ((const float4*)(xbar_g + (size_t)rb * 256))[i];
  __syncthreads();
  f32x4 acc[8];
#pragma unroll
  for (int r = 0; r < 8; r++) acc[r] = (f32x4){0.f, 0.f, 0.f, 0.f};
  const int dbase = wave * 64;
  for (int dd = 0; dd < 64; dd += 4) {
    float4 xr[8];
#pragma unroll
    for (int r = 0; r < 8; r++) xr[r] = *(const float4*)&xs[r][dbase + dd];  // broadcast
#pragma unroll
    for (int j = 0; j < 4; j++) {
      const float4 wv = *(const float4*)(Wv + (size_t)(dbase + dd + j) * 256 + lane * 4);
#pragma unroll
      for (int r = 0; r < 8; r++) {
        const float xv = (&xr[r].x)[j];
        acc[r][0] += xv * wv.x; acc[r][1] += xv * wv.y;
        acc[r][2] += xv * wv.z; acc[r][3] += xv * wv.w;
      }
    }
  }
#pragma unroll
  for (int r = 0; r < 8; r++) *(f32x4*)&pp[wave][r][lane * 4] = acc[r];
  __syncthreads();
  const float4 bvv = *(const float4*)(bvec + lane * 4);
  const float4 lg = *(const float4*)(ln_g + lane * 4);
  const float4 lb = *(const float4*)(ln_b + lane * 4);
#pragma unroll
  for (int rr = 0; rr < 2; rr++) {
    const int r = wave * 2 + rr;
    f32x4 v = *(const f32x4*)&pp[0][r][lane * 4];
#pragma unroll
    for (int w2 = 1; w2 < 4; w2++) {
      const f32x4 qv = *(const f32x4*)&pp[w2][r][lane * 4];
      v[0] += qv[0]; v[1] += qv[1]; v[2] += qv[2]; v[3] += qv[3];
    }
    v[0] += bvv.x; v[1] += bvv.y; v[2] += bvv.z; v[3] += bvv.w;
    float s1 = v[0] + v[1] + v[2] + v[3];
#pragma unroll
    for (int o = 32; o > 0; o >>= 1) s1 += __shfl_xor(s1, o);
    const float mu = s1 * (1.f / 256.f);
    const float4 df = make_float4(v[0] - mu, v[1] - mu, v[2] - mu, v[3] - mu);
    float s2 = df.x * df.x + df.y * df.y + df.z * df.z + df.w * df.w;
#pragma unroll
    for (int o = 32; o > 0; o >>= 1) s2 += __shfl_xor(s2, o);
    const float inv = 1.f / sqrtf(s2 * (1.f / 256.f) + LN_EPS);
    f32x4 rv;
    rv[0] = df.x * inv * lg.x + lb.x; rv[1] = df.y * inv * lg.y + lb.y;
    rv[2] = df.z * inv * lg.z + lb.z; rv[3] = df.w * inv * lg.w + lb.w;
    f32x4 pa = {0.f, 0.f, 0.f, 0.f}, pb = {0.f, 0.f, 0.f, 0.f};
#pragma unroll
    for (int k = 0; k < 4; k++) {
      const int d = lane * 4 + k;
      const f32x4 g0 = *(const f32x4*)(gate_W + d * 8);
      const f32x4 g1 = *(const f32x4*)(gate_W + d * 8 + 4);
      pa += rv[k] * g0;
      pb += rv[k] * g1;
    }
#pragma unroll
    for (int o = 32; o > 0; o >>= 1) {
      pa[0] += __shfl_down(pa[0], o); pa[1] += __shfl_down(pa[1], o);
      pa[2] += __shfl_down(pa[2], o); pa[3] += __shfl_down(pa[3], o);
      pb[0] += __shfl_down(pb[0], o); pb[1] += __shfl_down(pb[1], o);
      pb[2] += __shfl_down(pb[2], o); pb[3] += __shfl_down(pb[3], o);
    }
    if (lane == 0) {
      float aff[8];
#pragma unroll
      for (int j = 0; j < 4; j++) { aff[j] = pa[j] + gate_b[j]; aff[4 + j] = pb[j] + gate_b[4 + j]; }
      float b0 = -1e30f; int i0 = 0;
#pragma unroll
      for (int j = 0; j < 8; j++) {
        const float s = aff[j] + expert_biases[j];
        if (s > b0) { b0 = s; i0 = j; }
      }
      float b1v = -1e30f; int i1 = 0;
#pragma unroll
      for (int j = 0; j < 8; j++) {
        const float s = aff[j] + expert_biases[j];
        if (j != i0 && s > b1v) { b1v = s; i1 = j; }
      }
      const float a0 = aff[i0], a1 = aff[i1];
      const float m = fmaxf(a0, a1);
      const float e0 = expf(a0 - m), e1 = expf(a1 - m);
      const float invs = 1.f / (e0 + e1);
      const int bg = rb + r;
      ws_idx[bg * 2] = i0; ws_idx[bg * 2 + 1] = i1;
      ws_gw[bg * 2] = e0 * invs; ws_gw[bg * 2 + 1] = e1 * invs;
      out_idx_f[bg * 2] = (float)i0; out_idx_f[bg * 2 + 1] = (float)i1;
    }
  }
  // ---- last-block-done: run pack inline (device-scope handoff) ----
  __syncthreads();
  if (t == 0) {
    __threadfence();                       // release this block's ws_idx
    const int prev = atomicAdd(done_ctr, 1);
    is_last = (prev == (int)gridDim.x - 1);
  }
  __syncthreads();
  if (is_last) {
    __threadfence();                       // acquire all blocks' ws_idx
    __shared__ int cnt[8]; __shared__ int offp[9]; __shared__ int fill[8];
    if (t < 8) cnt[t] = 0;
    __syncthreads();
    for (int a = t; a < 4096; a += 256) atomicAdd(&cnt[ws_idx[a]], 1);
    __syncthreads();
    if (t == 0) {
      offp[0] = 0;
      for (int e = 0; e < 8; e++) offp[e + 1] = offp[e] + ((cnt[e] + 63) & ~63);
    }
    __syncthreads();
    if (t < 8) fill[t] = offp[t];
    if (t < 9) offsets_g[t] = offp[t];
    for (int a = t; a < 4608; a += 256) list_token[a] = 0;  // pad rows -> token 0
    __syncthreads();
    for (int a = t; a < 4096; a += 256) {
      const int e = ws_idx[a];
      const int pos = atomicAdd(&fill[e], 1);
      list_token[pos] = a >> 1;
      a_of[a] = pos;
    }
  }
}

// --------- GEMM-1: fused bib gather (fp32->bf16 in-register), FT-B ----------
// C[rows,NT] = cvt_bf16(bib[list_token[row]]) @ B1_e ; K=512.
template <int NT, bool RELU>
__global__ __launch_bounds__(256)
void expert_gemm_g1(const float* __restrict__ bib, const int* __restrict__ list_token,
                    const bf16_t* __restrict__ Bft, const float* __restrict__ bias,
                    bf16_t* __restrict__ C, const int* __restrict__ offsets) {
  constexpr int K = 512, nk = K / 32;
  const int e = blockIdx.z;
  const int seg_hi = offsets[e + 1];
  const int blk_row = offsets[e] + blockIdx.y * 128;
  if (blk_row >= seg_hi) return;
  const int wave = threadIdx.x >> 6, lane = threadIdx.x & 63;
  const int row0 = blk_row + wave * 32;
  if (row0 >= seg_hi) return;
  const int n0 = blockIdx.x * 64;
  const int tok0 = list_token[row0 + (lane & 15)];
  const int tok1 = list_token[row0 + 16 + (lane & 15)];
  const float* Ap0 = bib + (size_t)tok0 * 512 + (lane >> 4) * 8;
  const float* Ap1 = bib + (size_t)tok1 * 512 + (lane >> 4) * 8;
  const bf16_t* Bp = Bft + (size_t)e * NT * K + ((size_t)(n0 >> 4) * nk * 512 + lane * 8);
  f32x4 acc[2][4];
#pragma unroll
  for (int i = 0; i < 2; i++)
#pragma unroll
    for (int j = 0; j < 4; j++) acc[i][j] = (f32x4){0.f, 0.f, 0.f, 0.f};
  f4x2 aS[2][2]; bf16x8 bX[2][4];
  aS[0][0] = ldA8(Ap0); aS[0][1] = ldA8(Ap1);
#pragma unroll
  for (int ni = 0; ni < 4; ni++) bX[0][ni] = *(const bf16x8*)(Bp + (size_t)ni * nk * 512);
#pragma unroll
  for (int kt = 0; kt < nk; kt++) {
    const int cur = kt & 1, nxt = cur ^ 1;
    if (kt + 1 < nk) {
      aS[nxt][0] = ldA8(Ap0 + (kt + 1) * 32);
      aS[nxt][1] = ldA8(Ap1 + (kt + 1) * 32);
#pragma unroll
      for (int ni = 0; ni < 4; ni++)
        bX[nxt][ni] = *(const bf16x8*)(Bp + ((size_t)ni * nk + kt + 1) * 512);
    }
    const bf16x8 a0 = cvt8(aS[cur][0]), a1 = cvt8(aS[cur][1]);
#pragma unroll
    for (int ni = 0; ni < 4; ni++) {
      acc[0][ni] = __builtin_amdgcn_mfma_f32_16x16x32_bf16(a0, bX[cur][ni], acc[0][ni], 0, 0, 0);
      acc[1][ni] = __builtin_amdgcn_mfma_f32_16x16x32_bf16(a1, bX[cur][ni], acc[1][ni], 0, 0, 0);
    }
  }
  const int fr = lane & 15, q = lane >> 4;
#pragma unroll
  for (int ni = 0; ni < 4; ni++) {
    const int col = n0 + ni * 16 + fr;
    const float bv = bias[e * NT + col];
#pragma unroll
    for (int mi = 0; mi < 2; mi++) {
#pragma unroll
      for (int r = 0; r < 4; r++) {
        const int row = row0 + mi * 16 + q * 4 + r;
        float v = acc[mi][ni][r] + bv;
        if (RELU) v = fmaxf(v, 0.f);
        C[(size_t)row * NT + col] = (bf16_t)v;
      }
    }
  }
}

// ---------------- expert GEMM: LDS-free, barrier-free, FT-B -----------------
// NFRAG n-fragments of 16 per block (block covers 16*NFRAG output cols).
template <int K, int NT, int NFRAG, bool RELU, typename OUT_T>
__global__ __launch_bounds__(256)
void expert_gemm_ft(const bf16_t* __restrict__ A, const bf16_t* __restrict__ Bft,
                    const float* __restrict__ bias, OUT_T* __restrict__ C,
                    const int* __restrict__ offsets) {
  constexpr int nk = K / 32;
  const int e = blockIdx.z;
  const int seg_hi = offsets[e + 1];
  const int blk_row = offsets[e] + blockIdx.y * 128;
  if (blk_row >= seg_hi) return;
  const int wave = threadIdx.x >> 6, lane = threadIdx.x & 63;
  const int row0 = blk_row + wave * 32;
  if (row0 >= seg_hi) return;  // wave-uniform
  const int n0 = blockIdx.x * (16 * NFRAG);
  const bf16_t* Ap = A + (size_t)(row0 + (lane & 15)) * K + ((lane >> 4) * 8);
  const bf16_t* Bp = Bft + (size_t)e * NT * K + ((size_t)(n0 >> 4) * nk * 512 + lane * 8);
  f32x4 acc[2][NFRAG];
#pragma unroll
  for (int i = 0; i < 2; i++)
#pragma unroll
    for (int j = 0; j < NFRAG; j++) acc[i][j] = (f32x4){0.f, 0.f, 0.f, 0.f};
  bf16x8 aX[2][2], bX[2][NFRAG];
#pragma unroll
  for (int mi = 0; mi < 2; mi++) aX[0][mi] = *(const bf16x8*)(Ap + mi * 16 * K);
#pragma unroll
  for (int ni = 0; ni < NFRAG; ni++) bX[0][ni] = *(const bf16x8*)(Bp + (size_t)ni * nk * 512);
#pragma unroll
  for (int kt = 0; kt < nk; kt++) {
    const int cur = kt & 1, nxt = cur ^ 1;
    if (kt + 1 < nk) {
#pragma unroll
      for (int mi = 0; mi < 2; mi++)
        aX[nxt][mi] = *(const bf16x8*)(Ap + mi * 16 * K + (kt + 1) * 32);
#pragma unroll
      for (int ni = 0; ni < NFRAG; ni++)
        bX[nxt][ni] = *(const bf16x8*)(Bp + ((size_t)ni * nk + kt + 1) * 512);
    }
#pragma unroll
    for (int mi = 0; mi < 2; mi++)
#pragma unroll
      for (int ni = 0; ni < NFRAG; ni++)
        acc[mi][ni] = __builtin_amdgcn_mfma_f32_16x16x32_bf16(aX[cur][mi], bX[cur][ni], acc[mi][ni], 0, 0, 0);
  }
  const int fr = lane & 15, q = lane >> 4;
#pragma unroll
  for (int ni = 0; ni < NFRAG; ni++) {
    const int col = n0 + ni * 16 + fr;
    const float bv = bias[e * NT + col];
#pragma unroll
    for (int mi = 0; mi < 2; mi++) {
#pragma unroll
      for (int r = 0; r < 4; r++) {
        const int row = row0 + mi * 16 + q * 4 + r;
        float v = acc[mi][ni][r] + bv;
        if (RELU) v = fmaxf(v, 0.f);
        C[(size_t)row * NT + col] = (OUT_T)v;
      }
    }
  }
}

// --------------------- head: combine folded logits -------------------------
// logits[b,c] = g0*OcH[a0,c] + g1*OcH[a1,c] + head_b[c]  (b3h already in OcH)
__global__ __launch_bounds__(256)
void head_small(const float* __restrict__ OcH, const int* __restrict__ a_of,
                const float* __restrict__ ws_gw, const float* __restrict__ head_b,
                float* __restrict__ out) {
  const int tid = blockIdx.x * 256 + threadIdx.x;
  if (tid >= 20480) return;
  const int b = tid / 10, c = tid - b * 10;
  const int a0 = a_of[b * 2], a1 = a_of[b * 2 + 1];
  const float g0 = ws_gw[b * 2], g1 = ws_gw[b * 2 + 1];
  out[tid] = g0 * OcH[(size_t)a0 * 16 + c] + g1 * OcH[(size_t)a1 * 16 + c] + head_b[c];
}

// ------------------------------ launch --------------------------------------
extern "C" void kernel_launch(void* const* d_in, const int* in_sizes, int n_in,
                              void* d_out, int out_size, void* d_ws, size_t ws_size,
                              hipStream_t stream) {
  const int* ipc_idx = (const int*)d_in[0];
  const int* role_idx = (const int*)d_in[1];
  const float* bib = (const float*)d_in[2];
  const int* maskp = (const int*)d_in[3];
  const float* ipc_emb = (const float*)d_in[5];
  const float* role_emb = (const float*)d_in[6];
  const float* Wq = (const float*)d_in[7];
  const float* bq = (const float*)d_in[8];
  const float* Wk = (const float*)d_in[9];
  const float* bk = (const float*)d_in[10];
  const float* Wv = (const float*)d_in[11];
  const float* bv = (const float*)d_in[12];
  const float* gc = (const float*)d_in[13];
  const float* ln_g = (const float*)d_in[14];
  const float* ln_b = (const float*)d_in[15];
  const float* gate_W = (const float*)d_in[16];
  const float* gate_b = (const float*)d_in[17];
  const float* exp_b = (const float*)d_in[18];
  const float* W1 = (const float*)d_in[19];
  const float* b1 = (const float*)d_in[20];
  const float* W2 = (const float*)d_in[21];
  const float* b2 = (const float*)d_in[22];
  const float* W3 = (const float*)d_in[23];
  const float* b3 = (const float*)d_in[24];
  const float* head_W = (const float*)d_in[25];
  const float* head_b = (const float*)d_in[26];

  char* ws = (char*)d_ws;
  size_t off = 0;
  auto alloc = [&](size_t bytes) -> char* {
    char* p = ws + off;
    off += (bytes + 255) & ~(size_t)255;
    return p;
  };
  float* kq_qbk = (float*)alloc(257 * 4);
  float* xbar_g = (float*)alloc((size_t)2048 * 256 * 4);
  int* ws_idx = (int*)alloc(4096 * 4);
  float* ws_gw = (float*)alloc(4096 * 4);
  int* list_tok = (int*)alloc(4608 * 4);
  int* a_of = (int*)alloc(4096 * 4);
  int* offs = (int*)alloc(9 * 4);
  int* done_ctr = (int*)alloc(4);
  float* b3h = (float*)alloc(8 * 16 * 4);
  bf16_t* W1t = (bf16_t*)alloc((size_t)8 * 1024 * 512 * 2);
  bf16_t* W2t = (bf16_t*)alloc((size_t)8 * 1024 * 1024 * 2);
  bf16_t* B3h = (bf16_t*)alloc((size_t)8 * 16 * 1024 * 2);
  bf16_t* H1c = (bf16_t*)alloc((size_t)4608 * 1024 * 2);
  bf16_t* H2c = (bf16_t*)alloc((size_t)4608 * 1024 * 2);
  float* OcH = (float*)alloc((size_t)4608 * 16 * 4);
  (void)in_sizes; (void)n_in; (void)out_size; (void)ws_size;

  float* out_logits = (float*)d_out;          // [2048*10]
  float* out_idx = (float*)d_out + 20480;     // [2048*2] as float

  prep_kq_kernel<<<32, 256, 0, stream>>>(Wq, bq, Wk, bk, gc, kq_qbk, done_ctr);
  // 2048 xbar + 1024 W1-transpose + 2048 W2-transpose + 256 W3h-fold = 5376
  xbar_transpose<<<5376, 256, 0, stream>>>(W1, W2, W3, W1t, W2t, B3h, b3h,
                                           b3, head_W,
                                           ipc_idx, role_idx, maskp,
                                           ipc_emb, role_emb, kq_qbk, xbar_g);
  pool_kernel<<<256, 256, 0, stream>>>(xbar_g, Wv, bv, ln_g, ln_b, gate_W, gate_b,
                                       exp_b, out_idx, ws_idx, ws_gw,
                                       done_ctr, list_tok, a_of, offs);
  expert_gemm_g1<1024, true><<<dim3(16, 36, 8), 256, 0, stream>>>(bib, list_tok, W1t, b1, H1c, offs);
  expert_gemm_ft<1024, 1024, 4, true, bf16_t><<<dim3(16, 36, 8), 256, 0, stream>>>(H1c, W2t, b2, H2c, offs);
  expert_gemm_ft<1024, 16, 1, false, float><<<dim3(1, 36, 8), 256, 0, stream>>>(H2c, B3h, b3h, OcH, offs);
  head_small<<<80, 256, 0, stream>>>(OcH, a_of, ws_gw, head_b, out_logits);
}

// Round 6
// 350.922 us; speedup vs baseline: 1.0875x; 1.0875x over previous
//
#include <hip/hip_runtime.h>
#include <hip/hip_bf16.h>
#include <math.h>

// ---------------------------------------------------------------------------
// PatentCitationMoEModule — MI355X implementation, round 12
//  Round 11 (381.6 us, FAILED fold) fixed:
//   - W3@head_W fold reimplemented as a real MFMA mini-GEMM (64 blocks inside
//     the fused kernel): A = fp32 W3 rows w/ in-register bf16 cvt (gemm_g1
//     pattern, coalesced), B = head_W packed to FT fragments by prep_kq,
//     C scatter-written straight into B3h's FT-B layout. Replaces the 256
//     serial-shfl straggler blocks (~50us tail + sector storms) with ~2us.
//   - b3h (= b3 @ head_W) computed in prep_kq (lane-parallel, 8 blocks).
//  Keeps: r9 xbar (register indices, 72 VGPR), pack-in-pool merge, N=16
//  GEMM-3, trivial head. Fixed harness overhead untouched.
// ---------------------------------------------------------------------------

#define LN_EPS 1e-5f

typedef __bf16 bf16_t;
typedef __bf16 bf16x8 __attribute__((ext_vector_type(8)));
typedef float f32x4 __attribute__((ext_vector_type(4)));

struct f4x2 { float4 a, b; };
__device__ __forceinline__ f4x2 ldA8(const float* p) {
  f4x2 v; v.a = *(const float4*)p; v.b = *(const float4*)(p + 4); return v;
}
__device__ __forceinline__ bf16x8 cvt8(const f4x2& v) {
  bf16x8 o;
  o[0] = (bf16_t)v.a.x; o[1] = (bf16_t)v.a.y; o[2] = (bf16_t)v.a.z; o[3] = (bf16_t)v.a.w;
  o[4] = (bf16_t)v.b.x; o[5] = (bf16_t)v.b.y; o[6] = (bf16_t)v.b.z; o[7] = (bf16_t)v.b.w;
  return o;
}

// ----------------------------- prep_kq --------------------------------------
// kq_out[0..255] = Wk @ (gc@Wq + bq);  kq_out[256] = (gc@Wq + bq) . bk
// Extras: zero done_ctr; pack head_W into FT fragments (hwft, K=512,NT=16);
// b3h[e] = b3_e @ head_W (pad 10->16 with zeros).
__global__ __launch_bounds__(256)
void prep_kq_kernel(const float* __restrict__ Wq, const float* __restrict__ bq,
                    const float* __restrict__ Wk, const float* __restrict__ bk,
                    const float* __restrict__ gc, float* __restrict__ kq_out,
                    int* __restrict__ done_ctr,
                    const float* __restrict__ head_W, const float* __restrict__ b3,
                    bf16_t* __restrict__ hwft, float* __restrict__ b3h_g) {
  __shared__ float q[256];
  __shared__ float red[4];
  const int t = threadIdx.x, bi = blockIdx.x;
  const int lane = t & 63, wave = t >> 6;
  if (bi == 0 && t == 0) *done_ctr = 0;
  float s = bq[t];
  for (int d = 0; d < 256; d++) s += gc[d] * Wq[d * 256 + t];
  q[t] = s;
  __syncthreads();
  const int rl = t >> 5, sl = t & 31;
  const int r = bi * 8 + rl;
  float p = 0.f;
#pragma unroll
  for (int i = 0; i < 8; i++) { const int d = sl + 32 * i; p += Wk[r * 256 + d] * q[d]; }
#pragma unroll
  for (int o = 16; o > 0; o >>= 1) p += __shfl_down(p, o, 32);
  if (sl == 0) kq_out[r] = p;
  if (bi == 0) {
    float z2 = q[t] * bk[t];
#pragma unroll
    for (int o = 32; o > 0; o >>= 1) z2 += __shfl_down(z2, o);
    if (lane == 0) red[wave] = z2;
    __syncthreads();
    if (t == 0) kq_out[256] = red[0] + red[1] + red[2] + red[3];
  }
  // ---- head_W -> FT fragment kt=bi (blocks 0..15, wave 1) ----
  if (bi < 16 && wave == 1) {
    bf16x8 o8;
    const int c = lane & 15, koff = (lane >> 4) * 8;
#pragma unroll
    for (int j = 0; j < 8; j++) {
      const int k = bi * 32 + koff + j;
      o8[j] = (c < 10) ? (bf16_t)head_W[k * 10 + c] : (bf16_t)0.f;
    }
    *(bf16x8*)(hwft + ((size_t)bi * 64 + lane) * 8) = o8;
  }
  // ---- b3h[e] = b3_e @ head_W (blocks 16..23, wave 2) ----
  if (bi >= 16 && bi < 24 && wave == 2) {
    const int e = bi - 16;
    float pc[10];
#pragma unroll
    for (int c = 0; c < 10; c++) pc[c] = 0.f;
    for (int jj = 0; jj < 8; jj++) {
      const int j = lane + jj * 64;
      const float bv = b3[e * 512 + j];
#pragma unroll
      for (int c = 0; c < 10; c++) pc[c] += bv * head_W[j * 10 + c];
    }
#pragma unroll
    for (int c = 0; c < 10; c++) {
#pragma unroll
      for (int o = 32; o > 0; o >>= 1) pc[c] += __shfl_down(pc[c], o);
    }
    if (lane == 0) {
#pragma unroll
      for (int c = 0; c < 10; c++) b3h_g[e * 16 + c] = pc[c];
#pragma unroll
      for (int c = 10; c < 16; c++) b3h_g[e * 16 + c] = 0.f;
    }
  }
}

// ---- merged: xbar (bid<2048) + W1/W2 transpose + MFMA W3@head_W fold -------
// FT-B: frag (nt,kt) = 64 lanes x 8 bf16; lane holds n=nt*16+(lane&15),
// k = kt*32+(lane>>4)*8 .. +7.  Flat elem offset: ((nt*(K/32)+kt)*64+lane)*8.
__global__ __launch_bounds__(256)
void xbar_transpose(const float* __restrict__ W1, const float* __restrict__ W2,
                    const float* __restrict__ W3, bf16_t* __restrict__ B1,
                    bf16_t* __restrict__ B2, bf16_t* __restrict__ B3h,
                    const bf16_t* __restrict__ hwft,
                    const int* __restrict__ ipc_idx, const int* __restrict__ role_idx,
                    const int* __restrict__ maskp,
                    const float* __restrict__ ipc_emb, const float* __restrict__ role_emb,
                    const float* __restrict__ kq_qbk, float* __restrict__ xbar_g) {
  __shared__ __align__(16) float smem[4480];  // 17.9 KB, aliased per path
  const int bid = blockIdx.x;
  const int t = threadIdx.x, lane = t & 63;

  if (bid < 2048) {
    // ================= xbar path (register indices, r9) =================
    const int b = bid, wave = t >> 6;
    float* sred = smem;                 // [4 waves][64 lanes][17] partials
    float* scores_s = smem + 4352;      // [64]
    float* attn_s = smem + 4416;        // [64]
    const float4 kq = *(const float4*)(kq_qbk + lane * 4);
    const float qbk = kq_qbk[256];
    const int rbase = b * 64 + wave * 16;
    int4 m4[4], i4[4], r4[4];
#pragma unroll
    for (int j = 0; j < 4; j++) {
      m4[j] = *(const int4*)(maskp + rbase + j * 4);
      i4[j] = *(const int4*)(ipc_idx + rbase + j * 4);
      r4[j] = *(const int4*)(role_idx + rbase + j * 4);
    }
    // phase A: branch-free gather (masked -> zero padding row 0) + per-lane dot
#pragma unroll
    for (int i = 0; i < 16; i++) {
      const int mki = (&m4[i / 4].x)[i % 4];
      const int ii = mki ? (&i4[i / 4].x)[i % 4] : 0;
      const int ri = mki ? (&r4[i / 4].x)[i % 4] : 0;
      const float4 xe = *(const float4*)(ipc_emb + (size_t)ii * 256 + lane * 4);
      const float4 re = *(const float4*)(role_emb + (size_t)ri * 256 + lane * 4);
      sred[(wave * 64 + lane) * 17 + i] =
          (xe.x + re.x) * kq.x + (xe.y + re.y) * kq.y +
          (xe.z + re.z) * kq.z + (xe.w + re.w) * kq.w;
    }
    __syncthreads();
    // phase B: per-wave LDS-transpose reduce
    {
      const int i_r = lane & 15, g = lane >> 4;
      float s = 0.f;
#pragma unroll
      for (int j = 0; j < 16; j++) s += sred[(wave * 64 + g * 16 + j) * 17 + i_r];
      s += __shfl_xor(s, 16);
      s += __shfl_xor(s, 32);
      const int mval = (&m4[i_r / 4].x)[i_r % 4];
      if (lane < 16) scores_s[wave * 16 + lane] = mval ? (s + qbk) : -1e9f;
    }
    __syncthreads();
    // phase C: softmax over 64 scores (wave 0)
    if (wave == 0) {
      const float sv = scores_s[lane];
      float m = sv;
#pragma unroll
      for (int o = 32; o > 0; o >>= 1) m = fmaxf(m, __shfl_xor(m, o));
      const float ev = expf(sv - m);
      float sum = ev;
#pragma unroll
      for (int o = 32; o > 0; o >>= 1) sum += __shfl_xor(sum, o);
      attn_s[lane] = ev / sum;
    }
    __syncthreads();
    // phase D: branch-free re-gather (L2-hot) + attn-weighted sum
    float p0 = 0.f, p1 = 0.f, p2 = 0.f, p3 = 0.f;
#pragma unroll
    for (int i = 0; i < 16; i++) {
      const int mki = (&m4[i / 4].x)[i % 4];
      const int ii = mki ? (&i4[i / 4].x)[i % 4] : 0;
      const int ri = mki ? (&r4[i / 4].x)[i % 4] : 0;
      const float a = attn_s[wave * 16 + i];  // exactly 0 for masked rows
      const float4 xe = *(const float4*)(ipc_emb + (size_t)ii * 256 + lane * 4);
      const float4 re = *(const float4*)(role_emb + (size_t)ri * 256 + lane * 4);
      p0 += a * (xe.x + re.x); p1 += a * (xe.y + re.y);
      p2 += a * (xe.z + re.z); p3 += a * (xe.w + re.w);
    }
    __syncthreads();  // sred region no longer read; reuse as part[4][256]
    *(float4*)&smem[wave * 256 + lane * 4] = make_float4(p0, p1, p2, p3);
    __syncthreads();
    xbar_g[(size_t)b * 256 + t] = smem[t] + smem[256 + t] + smem[512 + t] + smem[768 + t];
    return;
  }

  const int bid2 = bid - 2048;
  if (bid2 >= 3072) {
    // ===== MFMA fold: B3h_ft[e] = bf16(W3_e) @ hwft, 64 blocks =====
    const int q = bid2 - 3072;            // 0..63
    const int e = q >> 3, chunk = q & 7;
    const int wave = t >> 6;
    const int row0 = chunk * 128 + wave * 32;
    const float* Ap0 = W3 + ((size_t)e * 1024 + row0 + (lane & 15)) * 512 + (lane >> 4) * 8;
    const float* Ap1 = Ap0 + (size_t)16 * 512;
    const bf16_t* Bp = hwft + lane * 8;
    f32x4 acc[2];
    acc[0] = (f32x4){0.f, 0.f, 0.f, 0.f};
    acc[1] = (f32x4){0.f, 0.f, 0.f, 0.f};
#pragma unroll
    for (int kt = 0; kt < 16; kt++) {
      const bf16x8 a0 = cvt8(ldA8(Ap0 + kt * 32));
      const bf16x8 a1 = cvt8(ldA8(Ap1 + kt * 32));
      const bf16x8 bfr = *(const bf16x8*)(Bp + kt * 512);
      acc[0] = __builtin_amdgcn_mfma_f32_16x16x32_bf16(a0, bfr, acc[0], 0, 0, 0);
      acc[1] = __builtin_amdgcn_mfma_f32_16x16x32_bf16(a1, bfr, acc[1], 0, 0, 0);
    }
    // scatter C into B3h FT-B layout: value (krow, col) -> frag kt'=krow>>5,
    // lane' = col | (((krow>>3)&3)<<4), j' = krow&7.
    const int col = lane & 15, qq = lane >> 4;
#pragma unroll
    for (int mi = 0; mi < 2; mi++) {
#pragma unroll
      for (int r2 = 0; r2 < 4; r2++) {
        const int krow = row0 + mi * 16 + qq * 4 + r2;
        const int ktp = krow >> 5;
        const int lanep = col | (((krow >> 3) & 3) << 4);
        const int jp = krow & 7;
        B3h[(size_t)e * 16 * 1024 + ((size_t)ktp * 64 + lanep) * 8 + jp] = (bf16_t)acc[mi][r2];
      }
    }
    return;
  }

  // ================= W1/W2 transpose path =================
  const float* W; bf16_t* Bft; int K, N, e, n0, k0;
  if (bid2 < 1024) {            // W1: K=512, N=1024, 128 tiles/expert
    W = W1; Bft = B1; K = 512; N = 1024;
    e = bid2 >> 7; const int r = bid2 & 127;
    n0 = (r & 15) * 64; k0 = (r >> 4) * 64;
  } else {                      // W2: K=1024, N=1024, 256 tiles/expert
    W = W2; Bft = B2; K = 1024; N = 1024;
    const int q = bid2 - 1024; e = q >> 8; const int r = q & 255;
    n0 = (r & 15) * 64; k0 = (r >> 4) * 64;
  }
  float (*tile)[65] = (float(*)[65])smem;  // 64x65 fits in 4480 floats
  const float* Wp = W + (size_t)e * K * N;
  bf16_t* Bp = Bft + (size_t)e * N * K;
  const int tq = t & 15, th = t >> 4;  // 16 x 16
#pragma unroll
  for (int i = 0; i < 4; i++) {
    const int row = th + 16 * i;  // k-dim
    *(float4*)&tile[row][tq * 4] = *(const float4*)(Wp + (size_t)(k0 + row) * N + n0 + tq * 4);
  }
  __syncthreads();
  const int sub = t >> 6;
  const int nk = K >> 5;
#pragma unroll
  for (int it = 0; it < 2; it++) {
    const int fid = sub + it * 4;            // 8 frag-tiles in a 64x64 tile
    const int ntl = fid & 3, ktl = fid >> 2;
    const int n_l = ntl * 16 + (lane & 15);
    const int k_l = ktl * 32 + (lane >> 4) * 8;
    bf16x8 o;
#pragma unroll
    for (int j = 0; j < 8; j++) o[j] = (bf16_t)tile[k_l + j][n_l];
    const size_t idx = ((((size_t)(n0 >> 4) + ntl) * nk + (k0 >> 5) + ktl) * 64 + lane) * 8;
    *(bf16x8*)(Bp + idx) = o;
  }
}

// ------------- pool: pooled = xbar@Wv + bv, LN, gate, top2 ------------------
// Waves split the d(K)-range so Wv is read once per block (64 MB total).
// Last block to finish (device-scope counter) runs the pack stage inline.
__global__ __launch_bounds__(256)
void pool_kernel(const float* __restrict__ xbar_g, const float* __restrict__ Wv,
                 const float* __restrict__ bvec,
                 const float* __restrict__ ln_g, const float* __restrict__ ln_b,
                 const float* __restrict__ gate_W, const float* __restrict__ gate_b,
                 const float* __restrict__ expert_biases,
                 float* __restrict__ out_idx_f, int* __restrict__ ws_idx,
                 float* __restrict__ ws_gw, int* __restrict__ done_ctr,
                 int* __restrict__ list_token, int* __restrict__ a_of,
                 int* __restrict__ offsets_g) {
  const int rb = blockIdx.x * 8;
  __shared__ __align__(16) float xs[8][256];       // 8 input rows
  __shared__ __align__(16) float pp[4][8][256];    // per-wave d-partials
  __shared__ int is_last;
  const int t = threadIdx.x, wave = t >> 6, lane = t & 63;
  for (int i = t; i < 512; i += 256)
    ((float4*)xs)[i] = ((const float4*)(xbar_g + (size_t)rb * 256))[i];
  __syncthreads();
  f32x4 acc[8];
#pragma unroll
  for (int r = 0; r < 8; r++) acc[r] = (f32x4){0.f, 0.f, 0.f, 0.f};
  const int dbase = wave * 64;
  for (int dd = 0; dd < 64; dd += 4) {
    float4 xr[8];
#pragma unroll
    for (int r = 0; r < 8; r++) xr[r] = *(const float4*)&xs[r][dbase + dd];  // broadcast
#pragma unroll
    for (int j = 0; j < 4; j++) {
      const float4 wv = *(const float4*)(Wv + (size_t)(dbase + dd + j) * 256 + lane * 4);
#pragma unroll
      for (int r = 0; r < 8; r++) {
        const float xv = (&xr[r].x)[j];
        acc[r][0] += xv * wv.x; acc[r][1] += xv * wv.y;
        acc[r][2] += xv * wv.z; acc[r][3] += xv * wv.w;
      }
    }
  }
#pragma unroll
  for (int r = 0; r < 8; r++) *(f32x4*)&pp[wave][r][lane * 4] = acc[r];
  __syncthreads();
  const float4 bvv = *(const float4*)(bvec + lane * 4);
  const float4 lg = *(const float4*)(ln_g + lane * 4);
  const float4 lb = *(const float4*)(ln_b + lane * 4);
#pragma unroll
  for (int rr = 0; rr < 2; rr++) {
    const int r = wave * 2 + rr;
    f32x4 v = *(const f32x4*)&pp[0][r][lane * 4];
#pragma unroll
    for (int w2 = 1; w2 < 4; w2++) {
      const f32x4 qv = *(const f32x4*)&pp[w2][r][lane * 4];
      v[0] += qv[0]; v[1] += qv[1]; v[2] += qv[2]; v[3] += qv[3];
    }
    v[0] += bvv.x; v[1] += bvv.y; v[2] += bvv.z; v[3] += bvv.w;
    float s1 = v[0] + v[1] + v[2] + v[3];
#pragma unroll
    for (int o = 32; o > 0; o >>= 1) s1 += __shfl_xor(s1, o);
    const float mu = s1 * (1.f / 256.f);
    const float4 df = make_float4(v[0] - mu, v[1] - mu, v[2] - mu, v[3] - mu);
    float s2 = df.x * df.x + df.y * df.y + df.z * df.z + df.w * df.w;
#pragma unroll
    for (int o = 32; o > 0; o >>= 1) s2 += __shfl_xor(s2, o);
    const float inv = 1.f / sqrtf(s2 * (1.f / 256.f) + LN_EPS);
    f32x4 rv;
    rv[0] = df.x * inv * lg.x + lb.x; rv[1] = df.y * inv * lg.y + lb.y;
    rv[2] = df.z * inv * lg.z + lb.z; rv[3] = df.w * inv * lg.w + lb.w;
    f32x4 pa = {0.f, 0.f, 0.f, 0.f}, pb = {0.f, 0.f, 0.f, 0.f};
#pragma unroll
    for (int k = 0; k < 4; k++) {
      const int d = lane * 4 + k;
      const f32x4 g0 = *(const f32x4*)(gate_W + d * 8);
      const f32x4 g1 = *(const f32x4*)(gate_W + d * 8 + 4);
      pa += rv[k] * g0;
      pb += rv[k] * g1;
    }
#pragma unroll
    for (int o = 32; o > 0; o >>= 1) {
      pa[0] += __shfl_down(pa[0], o); pa[1] += __shfl_down(pa[1], o);
      pa[2] += __shfl_down(pa[2], o); pa[3] += __shfl_down(pa[3], o);
      pb[0] += __shfl_down(pb[0], o); pb[1] += __shfl_down(pb[1], o);
      pb[2] += __shfl_down(pb[2], o); pb[3] += __shfl_down(pb[3], o);
    }
    if (lane == 0) {
      float aff[8];
#pragma unroll
      for (int j = 0; j < 4; j++) { aff[j] = pa[j] + gate_b[j]; aff[4 + j] = pb[j] + gate_b[4 + j]; }
      float b0 = -1e30f; int i0 = 0;
#pragma unroll
      for (int j = 0; j < 8; j++) {
        const float s = aff[j] + expert_biases[j];
        if (s > b0) { b0 = s; i0 = j; }
      }
      float b1v = -1e30f; int i1 = 0;
#pragma unroll
      for (int j = 0; j < 8; j++) {
        const float s = aff[j] + expert_biases[j];
        if (j != i0 && s > b1v) { b1v = s; i1 = j; }
      }
      const float a0 = aff[i0], a1 = aff[i1];
      const float m = fmaxf(a0, a1);
      const float e0 = expf(a0 - m), e1 = expf(a1 - m);
      const float invs = 1.f / (e0 + e1);
      const int bg = rb + r;
      ws_idx[bg * 2] = i0; ws_idx[bg * 2 + 1] = i1;
      ws_gw[bg * 2] = e0 * invs; ws_gw[bg * 2 + 1] = e1 * invs;
      out_idx_f[bg * 2] = (float)i0; out_idx_f[bg * 2 + 1] = (float)i1;
    }
  }
  // ---- last-block-done: run pack inline (device-scope handoff) ----
  __syncthreads();
  if (t == 0) {
    __threadfence();                       // release this block's ws_idx
    const int prev = atomicAdd(done_ctr, 1);
    is_last = (prev == (int)gridDim.x - 1);
  }
  __syncthreads();
  if (is_last) {
    __threadfence();                       // acquire all blocks' ws_idx
    __shared__ int cnt[8]; __shared__ int offp[9]; __shared__ int fill[8];
    if (t < 8) cnt[t] = 0;
    __syncthreads();
    for (int a = t; a < 4096; a += 256) atomicAdd(&cnt[ws_idx[a]], 1);
    __syncthreads();
    if (t == 0) {
      offp[0] = 0;
      for (int e = 0; e < 8; e++) offp[e + 1] = offp[e] + ((cnt[e] + 63) & ~63);
    }
    __syncthreads();
    if (t < 8) fill[t] = offp[t];
    if (t < 9) offsets_g[t] = offp[t];
    for (int a = t; a < 4608; a += 256) list_token[a] = 0;  // pad rows -> token 0
    __syncthreads();
    for (int a = t; a < 4096; a += 256) {
      const int e = ws_idx[a];
      const int pos = atomicAdd(&fill[e], 1);
      list_token[pos] = a >> 1;
      a_of[a] = pos;
    }
  }
}

// --------- GEMM-1: fused bib gather (fp32->bf16 in-register), FT-B ----------
// C[rows,NT] = cvt_bf16(bib[list_token[row]]) @ B1_e ; K=512.
template <int NT, bool RELU>
__global__ __launch_bounds__(256)
void expert_gemm_g1(const float* __restrict__ bib, const int* __restrict__ list_token,
                    const bf16_t* __restrict__ Bft, const float* __restrict__ bias,
                    bf16_t* __restrict__ C, const int* __restrict__ offsets) {
  constexpr int K = 512, nk = K / 32;
  const int e = blockIdx.z;
  const int seg_hi = offsets[e + 1];
  const int blk_row = offsets[e] + blockIdx.y * 128;
  if (blk_row >= seg_hi) return;
  const int wave = threadIdx.x >> 6, lane = threadIdx.x & 63;
  const int row0 = blk_row + wave * 32;
  if (row0 >= seg_hi) return;
  const int n0 = blockIdx.x * 64;
  const int tok0 = list_token[row0 + (lane & 15)];
  const int tok1 = list_token[row0 + 16 + (lane & 15)];
  const float* Ap0 = bib + (size_t)tok0 * 512 + (lane >> 4) * 8;
  const float* Ap1 = bib + (size_t)tok1 * 512 + (lane >> 4) * 8;
  const bf16_t* Bp = Bft + (size_t)e * NT * K + ((size_t)(n0 >> 4) * nk * 512 + lane * 8);
  f32x4 acc[2][4];
#pragma unroll
  for (int i = 0; i < 2; i++)
#pragma unroll
    for (int j = 0; j < 4; j++) acc[i][j] = (f32x4){0.f, 0.f, 0.f, 0.f};
  f4x2 aS[2][2]; bf16x8 bX[2][4];
  aS[0][0] = ldA8(Ap0); aS[0][1] = ldA8(Ap1);
#pragma unroll
  for (int ni = 0; ni < 4; ni++) bX[0][ni] = *(const bf16x8*)(Bp + (size_t)ni * nk * 512);
#pragma unroll
  for (int kt = 0; kt < nk; kt++) {
    const int cur = kt & 1, nxt = cur ^ 1;
    if (kt + 1 < nk) {
      aS[nxt][0] = ldA8(Ap0 + (kt + 1) * 32);
      aS[nxt][1] = ldA8(Ap1 + (kt + 1) * 32);
#pragma unroll
      for (int ni = 0; ni < 4; ni++)
        bX[nxt][ni] = *(const bf16x8*)(Bp + ((size_t)ni * nk + kt + 1) * 512);
    }
    const bf16x8 a0 = cvt8(aS[cur][0]), a1 = cvt8(aS[cur][1]);
#pragma unroll
    for (int ni = 0; ni < 4; ni++) {
      acc[0][ni] = __builtin_amdgcn_mfma_f32_16x16x32_bf16(a0, bX[cur][ni], acc[0][ni], 0, 0, 0);
      acc[1][ni] = __builtin_amdgcn_mfma_f32_16x16x32_bf16(a1, bX[cur][ni], acc[1][ni], 0, 0, 0);
    }
  }
  const int fr = lane & 15, q = lane >> 4;
#pragma unroll
  for (int ni = 0; ni < 4; ni++) {
    const int col = n0 + ni * 16 + fr;
    const float bv = bias[e * NT + col];
#pragma unroll
    for (int mi = 0; mi < 2; mi++) {
#pragma unroll
      for (int r = 0; r < 4; r++) {
        const int row = row0 + mi * 16 + q * 4 + r;
        float v = acc[mi][ni][r] + bv;
        if (RELU) v = fmaxf(v, 0.f);
        C[(size_t)row * NT + col] = (bf16_t)v;
      }
    }
  }
}

// ---------------- expert GEMM: LDS-free, barrier-free, FT-B -----------------
// NFRAG n-fragments of 16 per block (block covers 16*NFRAG output cols).
template <int K, int NT, int NFRAG, bool RELU, typename OUT_T>
__global__ __launch_bounds__(256)
void expert_gemm_ft(const bf16_t* __restrict__ A, const bf16_t* __restrict__ Bft,
                    const float* __restrict__ bias, OUT_T* __restrict__ C,
                    const int* __restrict__ offsets) {
  constexpr int nk = K / 32;
  const int e = blockIdx.z;
  const int seg_hi = offsets[e + 1];
  const int blk_row = offsets[e] + blockIdx.y * 128;
  if (blk_row >= seg_hi) return;
  const int wave = threadIdx.x >> 6, lane = threadIdx.x & 63;
  const int row0 = blk_row + wave * 32;
  if (row0 >= seg_hi) return;  // wave-uniform
  const int n0 = blockIdx.x * (16 * NFRAG);
  const bf16_t* Ap = A + (size_t)(row0 + (lane & 15)) * K + ((lane >> 4) * 8);
  const bf16_t* Bp = Bft + (size_t)e * NT * K + ((size_t)(n0 >> 4) * nk * 512 + lane * 8);
  f32x4 acc[2][NFRAG];
#pragma unroll
  for (int i = 0; i < 2; i++)
#pragma unroll
    for (int j = 0; j < NFRAG; j++) acc[i][j] = (f32x4){0.f, 0.f, 0.f, 0.f};
  bf16x8 aX[2][2], bX[2][NFRAG];
#pragma unroll
  for (int mi = 0; mi < 2; mi++) aX[0][mi] = *(const bf16x8*)(Ap + mi * 16 * K);
#pragma unroll
  for (int ni = 0; ni < NFRAG; ni++) bX[0][ni] = *(const bf16x8*)(Bp + (size_t)ni * nk * 512);
#pragma unroll
  for (int kt = 0; kt < nk; kt++) {
    const int cur = kt & 1, nxt = cur ^ 1;
    if (kt + 1 < nk) {
#pragma unroll
      for (int mi = 0; mi < 2; mi++)
        aX[nxt][mi] = *(const bf16x8*)(Ap + mi * 16 * K + (kt + 1) * 32);
#pragma unroll
      for (int ni = 0; ni < NFRAG; ni++)
        bX[nxt][ni] = *(const bf16x8*)(Bp + ((size_t)ni * nk + kt + 1) * 512);
    }
#pragma unroll
    for (int mi = 0; mi < 2; mi++)
#pragma unroll
      for (int ni = 0; ni < NFRAG; ni++)
        acc[mi][ni] = __builtin_amdgcn_mfma_f32_16x16x32_bf16(aX[cur][mi], bX[cur][ni], acc[mi][ni], 0, 0, 0);
  }
  const int fr = lane & 15, q = lane >> 4;
#pragma unroll
  for (int ni = 0; ni < NFRAG; ni++) {
    const int col = n0 + ni * 16 + fr;
    const float bv = bias[e * NT + col];
#pragma unroll
    for (int mi = 0; mi < 2; mi++) {
#pragma unroll
      for (int r = 0; r < 4; r++) {
        const int row = row0 + mi * 16 + q * 4 + r;
        float v = acc[mi][ni][r] + bv;
        if (RELU) v = fmaxf(v, 0.f);
        C[(size_t)row * NT + col] = (OUT_T)v;
      }
    }
  }
}

// --------------------- head: combine folded logits -------------------------
// logits[b,c] = g0*OcH[a0,c] + g1*OcH[a1,c] + head_b[c]  (b3h already in OcH)
__global__ __launch_bounds__(256)
void head_small(const float* __restrict__ OcH, const int* __restrict__ a_of,
                const float* __restrict__ ws_gw, const float* __restrict__ head_b,
                float* __restrict__ out) {
  const int tid = blockIdx.x * 256 + threadIdx.x;
  if (tid >= 20480) return;
  const int b = tid / 10, c = tid - b * 10;
  const int a0 = a_of[b * 2], a1 = a_of[b * 2 + 1];
  const float g0 = ws_gw[b * 2], g1 = ws_gw[b * 2 + 1];
  out[tid] = g0 * OcH[(size_t)a0 * 16 + c] + g1 * OcH[(size_t)a1 * 16 + c] + head_b[c];
}

// ------------------------------ launch --------------------------------------
extern "C" void kernel_launch(void* const* d_in, const int* in_sizes, int n_in,
                              void* d_out, int out_size, void* d_ws, size_t ws_size,
                              hipStream_t stream) {
  const int* ipc_idx = (const int*)d_in[0];
  const int* role_idx = (const int*)d_in[1];
  const float* bib = (const float*)d_in[2];
  const int* maskp = (const int*)d_in[3];
  const float* ipc_emb = (const float*)d_in[5];
  const float* role_emb = (const float*)d_in[6];
  const float* Wq = (const float*)d_in[7];
  const float* bq = (const float*)d_in[8];
  const float* Wk = (const float*)d_in[9];
  const float* bk = (const float*)d_in[10];
  const float* Wv = (const float*)d_in[11];
  const float* bv = (const float*)d_in[12];
  const float* gc = (const float*)d_in[13];
  const float* ln_g = (const float*)d_in[14];
  const float* ln_b = (const float*)d_in[15];
  const float* gate_W = (const float*)d_in[16];
  const float* gate_b = (const float*)d_in[17];
  const float* exp_b = (const float*)d_in[18];
  const float* W1 = (const float*)d_in[19];
  const float* b1 = (const float*)d_in[20];
  const float* W2 = (const float*)d_in[21];
  const float* b2 = (const float*)d_in[22];
  const float* W3 = (const float*)d_in[23];
  const float* b3 = (const float*)d_in[24];
  const float* head_W = (const float*)d_in[25];
  const float* head_b = (const float*)d_in[26];

  char* ws = (char*)d_ws;
  size_t off = 0;
  auto alloc = [&](size_t bytes) -> char* {
    char* p = ws + off;
    off += (bytes + 255) & ~(size_t)255;
    return p;
  };
  float* kq_qbk = (float*)alloc(257 * 4);
  float* xbar_g = (float*)alloc((size_t)2048 * 256 * 4);
  int* ws_idx = (int*)alloc(4096 * 4);
  float* ws_gw = (float*)alloc(4096 * 4);
  int* list_tok = (int*)alloc(4608 * 4);
  int* a_of = (int*)alloc(4096 * 4);
  int* offs = (int*)alloc(9 * 4);
  int* done_ctr = (int*)alloc(4);
  float* b3h = (float*)alloc(8 * 16 * 4);
  bf16_t* hwft = (bf16_t*)alloc((size_t)16 * 64 * 8 * 2);
  bf16_t* W1t = (bf16_t*)alloc((size_t)8 * 1024 * 512 * 2);
  bf16_t* W2t = (bf16_t*)alloc((size_t)8 * 1024 * 1024 * 2);
  bf16_t* B3h = (bf16_t*)alloc((size_t)8 * 16 * 1024 * 2);
  bf16_t* H1c = (bf16_t*)alloc((size_t)4608 * 1024 * 2);
  bf16_t* H2c = (bf16_t*)alloc((size_t)4608 * 1024 * 2);
  float* OcH = (float*)alloc((size_t)4608 * 16 * 4);
  (void)in_sizes; (void)n_in; (void)out_size; (void)ws_size;

  float* out_logits = (float*)d_out;          // [2048*10]
  float* out_idx = (float*)d_out + 20480;     // [2048*2] as float

  prep_kq_kernel<<<32, 256, 0, stream>>>(Wq, bq, Wk, bk, gc, kq_qbk, done_ctr,
                                         head_W, b3, hwft, b3h);
  // 2048 xbar + 1024 W1-transpose + 2048 W2-transpose + 64 MFMA-fold = 5184
  xbar_transpose<<<5184, 256, 0, stream>>>(W1, W2, W3, W1t, W2t, B3h, hwft,
                                           ipc_idx, role_idx, maskp,
                                           ipc_emb, role_emb, kq_qbk, xbar_g);
  pool_kernel<<<256, 256, 0, stream>>>(xbar_g, Wv, bv, ln_g, ln_b, gate_W, gate_b,
                                       exp_b, out_idx, ws_idx, ws_gw,
                                       done_ctr, list_tok, a_of, offs);
  expert_gemm_g1<1024, true><<<dim3(16, 36, 8), 256, 0, stream>>>(bib, list_tok, W1t, b1, H1c, offs);
  expert_gemm_ft<1024, 1024, 4, true, bf16_t><<<dim3(16, 36, 8), 256, 0, stream>>>(H1c, W2t, b2, H2c, offs);
  expert_gemm_ft<1024, 16, 1, false, float><<<dim3(1, 36, 8), 256, 0, stream>>>(H2c, B3h, b3h, OcH, offs);
  head_small<<<80, 256, 0, stream>>>(OcH, a_of, ws_gw, head_b, out_logits);
}

// Round 7
// 342.731 us; speedup vs baseline: 1.1135x; 1.0239x over previous
//
#include <hip/hip_runtime.h>
#include <hip/hip_bf16.h>
#include <math.h>

// ---------------------------------------------------------------------------
// PatentCitationMoEModule — MI355X implementation, round 13
//  Round 12 (350.9 us) plus:
//   - fold blocks moved to the FRONT of the fused grid (bid 0..63): their
//     cold 16.8 MB W3 read now overlaps the xbar gather phase instead of
//     running as a 64-block straggler tail in the fractional last dispatch
//     wave (r12's fused kernel regression 59->86.5us).
//   - B3h scatter stores vectorized: 4 consecutive bf16 (jp = qq*4 + 0..3)
//     packed into one 8 B store.
//  Keeps: r9 xbar (register indices), pack-in-pool merge, MFMA fold, N=16
//  GEMM-3, trivial head. Fixed harness overhead untouched.
// ---------------------------------------------------------------------------

#define LN_EPS 1e-5f

typedef __bf16 bf16_t;
typedef __bf16 bf16x8 __attribute__((ext_vector_type(8)));
typedef __bf16 bf16x4 __attribute__((ext_vector_type(4)));
typedef float f32x4 __attribute__((ext_vector_type(4)));

struct f4x2 { float4 a, b; };
__device__ __forceinline__ f4x2 ldA8(const float* p) {
  f4x2 v; v.a = *(const float4*)p; v.b = *(const float4*)(p + 4); return v;
}
__device__ __forceinline__ bf16x8 cvt8(const f4x2& v) {
  bf16x8 o;
  o[0] = (bf16_t)v.a.x; o[1] = (bf16_t)v.a.y; o[2] = (bf16_t)v.a.z; o[3] = (bf16_t)v.a.w;
  o[4] = (bf16_t)v.b.x; o[5] = (bf16_t)v.b.y; o[6] = (bf16_t)v.b.z; o[7] = (bf16_t)v.b.w;
  return o;
}

// ----------------------------- prep_kq --------------------------------------
// kq_out[0..255] = Wk @ (gc@Wq + bq);  kq_out[256] = (gc@Wq + bq) . bk
// Extras: zero done_ctr; pack head_W into FT fragments (hwft, K=512,NT=16);
// b3h[e] = b3_e @ head_W (pad 10->16 with zeros).
__global__ __launch_bounds__(256)
void prep_kq_kernel(const float* __restrict__ Wq, const float* __restrict__ bq,
                    const float* __restrict__ Wk, const float* __restrict__ bk,
                    const float* __restrict__ gc, float* __restrict__ kq_out,
                    int* __restrict__ done_ctr,
                    const float* __restrict__ head_W, const float* __restrict__ b3,
                    bf16_t* __restrict__ hwft, float* __restrict__ b3h_g) {
  __shared__ float q[256];
  __shared__ float red[4];
  const int t = threadIdx.x, bi = blockIdx.x;
  const int lane = t & 63, wave = t >> 6;
  if (bi == 0 && t == 0) *done_ctr = 0;
  float s = bq[t];
  for (int d = 0; d < 256; d++) s += gc[d] * Wq[d * 256 + t];
  q[t] = s;
  __syncthreads();
  const int rl = t >> 5, sl = t & 31;
  const int r = bi * 8 + rl;
  float p = 0.f;
#pragma unroll
  for (int i = 0; i < 8; i++) { const int d = sl + 32 * i; p += Wk[r * 256 + d] * q[d]; }
#pragma unroll
  for (int o = 16; o > 0; o >>= 1) p += __shfl_down(p, o, 32);
  if (sl == 0) kq_out[r] = p;
  if (bi == 0) {
    float z2 = q[t] * bk[t];
#pragma unroll
    for (int o = 32; o > 0; o >>= 1) z2 += __shfl_down(z2, o);
    if (lane == 0) red[wave] = z2;
    __syncthreads();
    if (t == 0) kq_out[256] = red[0] + red[1] + red[2] + red[3];
  }
  // ---- head_W -> FT fragment kt=bi (blocks 0..15, wave 1) ----
  if (bi < 16 && wave == 1) {
    bf16x8 o8;
    const int c = lane & 15, koff = (lane >> 4) * 8;
#pragma unroll
    for (int j = 0; j < 8; j++) {
      const int k = bi * 32 + koff + j;
      o8[j] = (c < 10) ? (bf16_t)head_W[k * 10 + c] : (bf16_t)0.f;
    }
    *(bf16x8*)(hwft + ((size_t)bi * 64 + lane) * 8) = o8;
  }
  // ---- b3h[e] = b3_e @ head_W (blocks 16..23, wave 2) ----
  if (bi >= 16 && bi < 24 && wave == 2) {
    const int e = bi - 16;
    float pc[10];
#pragma unroll
    for (int c = 0; c < 10; c++) pc[c] = 0.f;
    for (int jj = 0; jj < 8; jj++) {
      const int j = lane + jj * 64;
      const float bv = b3[e * 512 + j];
#pragma unroll
      for (int c = 0; c < 10; c++) pc[c] += bv * head_W[j * 10 + c];
    }
#pragma unroll
    for (int c = 0; c < 10; c++) {
#pragma unroll
      for (int o = 32; o > 0; o >>= 1) pc[c] += __shfl_down(pc[c], o);
    }
    if (lane == 0) {
#pragma unroll
      for (int c = 0; c < 10; c++) b3h_g[e * 16 + c] = pc[c];
#pragma unroll
      for (int c = 10; c < 16; c++) b3h_g[e * 16 + c] = 0.f;
    }
  }
}

// -- merged: MFMA W3@head_W fold (bid<64) + xbar (64..2111) + W1/W2 transpose
// FT-B: frag (nt,kt) = 64 lanes x 8 bf16; lane holds n=nt*16+(lane&15),
// k = kt*32+(lane>>4)*8 .. +7.  Flat elem offset: ((nt*(K/32)+kt)*64+lane)*8.
__global__ __launch_bounds__(256)
void xbar_transpose(const float* __restrict__ W1, const float* __restrict__ W2,
                    const float* __restrict__ W3, bf16_t* __restrict__ B1,
                    bf16_t* __restrict__ B2, bf16_t* __restrict__ B3h,
                    const bf16_t* __restrict__ hwft,
                    const int* __restrict__ ipc_idx, const int* __restrict__ role_idx,
                    const int* __restrict__ maskp,
                    const float* __restrict__ ipc_emb, const float* __restrict__ role_emb,
                    const float* __restrict__ kq_qbk, float* __restrict__ xbar_g) {
  __shared__ __align__(16) float smem[4480];  // 17.9 KB, aliased per path
  const int bid = blockIdx.x;
  const int t = threadIdx.x, lane = t & 63;

  if (bid < 64) {
    // ===== MFMA fold: B3h_ft[e] = bf16(W3_e) @ hwft — FIRST so its cold
    // W3 stream overlaps the xbar gather phase =====
    const int e = bid >> 3, chunk = bid & 7;
    const int wave = t >> 6;
    const int row0 = chunk * 128 + wave * 32;
    const float* Ap0 = W3 + ((size_t)e * 1024 + row0 + (lane & 15)) * 512 + (lane >> 4) * 8;
    const float* Ap1 = Ap0 + (size_t)16 * 512;
    const bf16_t* Bp = hwft + lane * 8;
    f32x4 acc[2];
    acc[0] = (f32x4){0.f, 0.f, 0.f, 0.f};
    acc[1] = (f32x4){0.f, 0.f, 0.f, 0.f};
#pragma unroll
    for (int kt = 0; kt < 16; kt++) {
      const bf16x8 a0 = cvt8(ldA8(Ap0 + kt * 32));
      const bf16x8 a1 = cvt8(ldA8(Ap1 + kt * 32));
      const bf16x8 bfr = *(const bf16x8*)(Bp + kt * 512);
      acc[0] = __builtin_amdgcn_mfma_f32_16x16x32_bf16(a0, bfr, acc[0], 0, 0, 0);
      acc[1] = __builtin_amdgcn_mfma_f32_16x16x32_bf16(a1, bfr, acc[1], 0, 0, 0);
    }
    // scatter C into B3h FT-B layout. krow = row0+mi*16+qq*4+r2; jp=krow&7 is
    // 4-consecutive over r2 -> one 8 B store per mi.
    const int col = lane & 15, qq = lane >> 4;
#pragma unroll
    for (int mi = 0; mi < 2; mi++) {
      const int krow = row0 + mi * 16 + qq * 4;
      const int ktp = krow >> 5;
      const int lanep = col | (((krow >> 3) & 3) << 4);
      const int jp = krow & 7;
      bf16x4 o4;
      o4[0] = (bf16_t)acc[mi][0]; o4[1] = (bf16_t)acc[mi][1];
      o4[2] = (bf16_t)acc[mi][2]; o4[3] = (bf16_t)acc[mi][3];
      *(bf16x4*)(B3h + (size_t)e * 16 * 1024 + ((size_t)ktp * 64 + lanep) * 8 + jp) = o4;
    }
    return;
  }

  if (bid < 2112) {
    // ================= xbar path (register indices, r9) =================
    const int b = bid - 64, wave = t >> 6;
    float* sred = smem;                 // [4 waves][64 lanes][17] partials
    float* scores_s = smem + 4352;      // [64]
    float* attn_s = smem + 4416;        // [64]
    const float4 kq = *(const float4*)(kq_qbk + lane * 4);
    const float qbk = kq_qbk[256];
    const int rbase = b * 64 + wave * 16;
    int4 m4[4], i4[4], r4[4];
#pragma unroll
    for (int j = 0; j < 4; j++) {
      m4[j] = *(const int4*)(maskp + rbase + j * 4);
      i4[j] = *(const int4*)(ipc_idx + rbase + j * 4);
      r4[j] = *(const int4*)(role_idx + rbase + j * 4);
    }
    // phase A: branch-free gather (masked -> zero padding row 0) + per-lane dot
#pragma unroll
    for (int i = 0; i < 16; i++) {
      const int mki = (&m4[i / 4].x)[i % 4];
      const int ii = mki ? (&i4[i / 4].x)[i % 4] : 0;
      const int ri = mki ? (&r4[i / 4].x)[i % 4] : 0;
      const float4 xe = *(const float4*)(ipc_emb + (size_t)ii * 256 + lane * 4);
      const float4 re = *(const float4*)(role_emb + (size_t)ri * 256 + lane * 4);
      sred[(wave * 64 + lane) * 17 + i] =
          (xe.x + re.x) * kq.x + (xe.y + re.y) * kq.y +
          (xe.z + re.z) * kq.z + (xe.w + re.w) * kq.w;
    }
    __syncthreads();
    // phase B: per-wave LDS-transpose reduce
    {
      const int i_r = lane & 15, g = lane >> 4;
      float s = 0.f;
#pragma unroll
      for (int j = 0; j < 16; j++) s += sred[(wave * 64 + g * 16 + j) * 17 + i_r];
      s += __shfl_xor(s, 16);
      s += __shfl_xor(s, 32);
      const int mval = (&m4[i_r / 4].x)[i_r % 4];
      if (lane < 16) scores_s[wave * 16 + lane] = mval ? (s + qbk) : -1e9f;
    }
    __syncthreads();
    // phase C: softmax over 64 scores (wave 0)
    if (wave == 0) {
      const float sv = scores_s[lane];
      float m = sv;
#pragma unroll
      for (int o = 32; o > 0; o >>= 1) m = fmaxf(m, __shfl_xor(m, o));
      const float ev = expf(sv - m);
      float sum = ev;
#pragma unroll
      for (int o = 32; o > 0; o >>= 1) sum += __shfl_xor(sum, o);
      attn_s[lane] = ev / sum;
    }
    __syncthreads();
    // phase D: branch-free re-gather (L2-hot) + attn-weighted sum
    float p0 = 0.f, p1 = 0.f, p2 = 0.f, p3 = 0.f;
#pragma unroll
    for (int i = 0; i < 16; i++) {
      const int mki = (&m4[i / 4].x)[i % 4];
      const int ii = mki ? (&i4[i / 4].x)[i % 4] : 0;
      const int ri = mki ? (&r4[i / 4].x)[i % 4] : 0;
      const float a = attn_s[wave * 16 + i];  // exactly 0 for masked rows
      const float4 xe = *(const float4*)(ipc_emb + (size_t)ii * 256 + lane * 4);
      const float4 re = *(const float4*)(role_emb + (size_t)ri * 256 + lane * 4);
      p0 += a * (xe.x + re.x); p1 += a * (xe.y + re.y);
      p2 += a * (xe.z + re.z); p3 += a * (xe.w + re.w);
    }
    __syncthreads();  // sred region no longer read; reuse as part[4][256]
    *(float4*)&smem[wave * 256 + lane * 4] = make_float4(p0, p1, p2, p3);
    __syncthreads();
    xbar_g[(size_t)b * 256 + t] = smem[t] + smem[256 + t] + smem[512 + t] + smem[768 + t];
    return;
  }

  // ================= W1/W2 transpose path =================
  const int bid2 = bid - 2112;
  const float* W; bf16_t* Bft; int K, N, e, n0, k0;
  if (bid2 < 1024) {            // W1: K=512, N=1024, 128 tiles/expert
    W = W1; Bft = B1; K = 512; N = 1024;
    e = bid2 >> 7; const int r = bid2 & 127;
    n0 = (r & 15) * 64; k0 = (r >> 4) * 64;
  } else {                      // W2: K=1024, N=1024, 256 tiles/expert
    W = W2; Bft = B2; K = 1024; N = 1024;
    const int q = bid2 - 1024; e = q >> 8; const int r = q & 255;
    n0 = (r & 15) * 64; k0 = (r >> 4) * 64;
  }
  float (*tile)[65] = (float(*)[65])smem;  // 64x65 fits in 4480 floats
  const float* Wp = W + (size_t)e * K * N;
  bf16_t* Bp = Bft + (size_t)e * N * K;
  const int tq = t & 15, th = t >> 4;  // 16 x 16
#pragma unroll
  for (int i = 0; i < 4; i++) {
    const int row = th + 16 * i;  // k-dim
    *(float4*)&tile[row][tq * 4] = *(const float4*)(Wp + (size_t)(k0 + row) * N + n0 + tq * 4);
  }
  __syncthreads();
  const int sub = t >> 6;
  const int nk = K >> 5;
#pragma unroll
  for (int it = 0; it < 2; it++) {
    const int fid = sub + it * 4;            // 8 frag-tiles in a 64x64 tile
    const int ntl = fid & 3, ktl = fid >> 2;
    const int n_l = ntl * 16 + (lane & 15);
    const int k_l = ktl * 32 + (lane >> 4) * 8;
    bf16x8 o;
#pragma unroll
    for (int j = 0; j < 8; j++) o[j] = (bf16_t)tile[k_l + j][n_l];
    const size_t idx = ((((size_t)(n0 >> 4) + ntl) * nk + (k0 >> 5) + ktl) * 64 + lane) * 8;
    *(bf16x8*)(Bp + idx) = o;
  }
}

// ------------- pool: pooled = xbar@Wv + bv, LN, gate, top2 ------------------
// Waves split the d(K)-range so Wv is read once per block (64 MB total).
// Last block to finish (device-scope counter) runs the pack stage inline.
__global__ __launch_bounds__(256)
void pool_kernel(const float* __restrict__ xbar_g, const float* __restrict__ Wv,
                 const float* __restrict__ bvec,
                 const float* __restrict__ ln_g, const float* __restrict__ ln_b,
                 const float* __restrict__ gate_W, const float* __restrict__ gate_b,
                 const float* __restrict__ expert_biases,
                 float* __restrict__ out_idx_f, int* __restrict__ ws_idx,
                 float* __restrict__ ws_gw, int* __restrict__ done_ctr,
                 int* __restrict__ list_token, int* __restrict__ a_of,
                 int* __restrict__ offsets_g) {
  const int rb = blockIdx.x * 8;
  __shared__ __align__(16) float xs[8][256];       // 8 input rows
  __shared__ __align__(16) float pp[4][8][256];    // per-wave d-partials
  __shared__ int is_last;
  const int t = threadIdx.x, wave = t >> 6, lane = t & 63;
  for (int i = t; i < 512; i += 256)
    ((float4*)xs)[i] = ((const float4*)(xbar_g + (size_t)rb * 256))[i];
  __syncthreads();
  f32x4 acc[8];
#pragma unroll
  for (int r = 0; r < 8; r++) acc[r] = (f32x4){0.f, 0.f, 0.f, 0.f};
  const int dbase = wave * 64;
  for (int dd = 0; dd < 64; dd += 4) {
    float4 xr[8];
#pragma unroll
    for (int r = 0; r < 8; r++) xr[r] = *(const float4*)&xs[r][dbase + dd];  // broadcast
#pragma unroll
    for (int j = 0; j < 4; j++) {
      const float4 wv = *(const float4*)(Wv + (size_t)(dbase + dd + j) * 256 + lane * 4);
#pragma unroll
      for (int r = 0; r < 8; r++) {
        const float xv = (&xr[r].x)[j];
        acc[r][0] += xv * wv.x; acc[r][1] += xv * wv.y;
        acc[r][2] += xv * wv.z; acc[r][3] += xv * wv.w;
      }
    }
  }
#pragma unroll
  for (int r = 0; r < 8; r++) *(f32x4*)&pp[wave][r][lane * 4] = acc[r];
  __syncthreads();
  const float4 bvv = *(const float4*)(bvec + lane * 4);
  const float4 lg = *(const float4*)(ln_g + lane * 4);
  const float4 lb = *(const float4*)(ln_b + lane * 4);
#pragma unroll
  for (int rr = 0; rr < 2; rr++) {
    const int r = wave * 2 + rr;
    f32x4 v = *(const f32x4*)&pp[0][r][lane * 4];
#pragma unroll
    for (int w2 = 1; w2 < 4; w2++) {
      const f32x4 qv = *(const f32x4*)&pp[w2][r][lane * 4];
      v[0] += qv[0]; v[1] += qv[1]; v[2] += qv[2]; v[3] += qv[3];
    }
    v[0] += bvv.x; v[1] += bvv.y; v[2] += bvv.z; v[3] += bvv.w;
    float s1 = v[0] + v[1] + v[2] + v[3];
#pragma unroll
    for (int o = 32; o > 0; o >>= 1) s1 += __shfl_xor(s1, o);
    const float mu = s1 * (1.f / 256.f);
    const float4 df = make_float4(v[0] - mu, v[1] - mu, v[2] - mu, v[3] - mu);
    float s2 = df.x * df.x + df.y * df.y + df.z * df.z + df.w * df.w;
#pragma unroll
    for (int o = 32; o > 0; o >>= 1) s2 += __shfl_xor(s2, o);
    const float inv = 1.f / sqrtf(s2 * (1.f / 256.f) + LN_EPS);
    f32x4 rv;
    rv[0] = df.x * inv * lg.x + lb.x; rv[1] = df.y * inv * lg.y + lb.y;
    rv[2] = df.z * inv * lg.z + lb.z; rv[3] = df.w * inv * lg.w + lb.w;
    f32x4 pa = {0.f, 0.f, 0.f, 0.f}, pb = {0.f, 0.f, 0.f, 0.f};
#pragma unroll
    for (int k = 0; k < 4; k++) {
      const int d = lane * 4 + k;
      const f32x4 g0 = *(const f32x4*)(gate_W + d * 8);
      const f32x4 g1 = *(const f32x4*)(gate_W + d * 8 + 4);
      pa += rv[k] * g0;
      pb += rv[k] * g1;
    }
#pragma unroll
    for (int o = 32; o > 0; o >>= 1) {
      pa[0] += __shfl_down(pa[0], o); pa[1] += __shfl_down(pa[1], o);
      pa[2] += __shfl_down(pa[2], o); pa[3] += __shfl_down(pa[3], o);
      pb[0] += __shfl_down(pb[0], o); pb[1] += __shfl_down(pb[1], o);
      pb[2] += __shfl_down(pb[2], o); pb[3] += __shfl_down(pb[3], o);
    }
    if (lane == 0) {
      float aff[8];
#pragma unroll
      for (int j = 0; j < 4; j++) { aff[j] = pa[j] + gate_b[j]; aff[4 + j] = pb[j] + gate_b[4 + j]; }
      float b0 = -1e30f; int i0 = 0;
#pragma unroll
      for (int j = 0; j < 8; j++) {
        const float s = aff[j] + expert_biases[j];
        if (s > b0) { b0 = s; i0 = j; }
      }
      float b1v = -1e30f; int i1 = 0;
#pragma unroll
      for (int j = 0; j < 8; j++) {
        const float s = aff[j] + expert_biases[j];
        if (j != i0 && s > b1v) { b1v = s; i1 = j; }
      }
      const float a0 = aff[i0], a1 = aff[i1];
      const float m = fmaxf(a0, a1);
      const float e0 = expf(a0 - m), e1 = expf(a1 - m);
      const float invs = 1.f / (e0 + e1);
      const int bg = rb + r;
      ws_idx[bg * 2] = i0; ws_idx[bg * 2 + 1] = i1;
      ws_gw[bg * 2] = e0 * invs; ws_gw[bg * 2 + 1] = e1 * invs;
      out_idx_f[bg * 2] = (float)i0; out_idx_f[bg * 2 + 1] = (float)i1;
    }
  }
  // ---- last-block-done: run pack inline (device-scope handoff) ----
  __syncthreads();
  if (t == 0) {
    __threadfence();                       // release this block's ws_idx
    const int prev = atomicAdd(done_ctr, 1);
    is_last = (prev == (int)gridDim.x - 1);
  }
  __syncthreads();
  if (is_last) {
    __threadfence();                       // acquire all blocks' ws_idx
    __shared__ int cnt[8]; __shared__ int offp[9]; __shared__ int fill[8];
    if (t < 8) cnt[t] = 0;
    __syncthreads();
    for (int a = t; a < 4096; a += 256) atomicAdd(&cnt[ws_idx[a]], 1);
    __syncthreads();
    if (t == 0) {
      offp[0] = 0;
      for (int e = 0; e < 8; e++) offp[e + 1] = offp[e] + ((cnt[e] + 63) & ~63);
    }
    __syncthreads();
    if (t < 8) fill[t] = offp[t];
    if (t < 9) offsets_g[t] = offp[t];
    for (int a = t; a < 4608; a += 256) list_token[a] = 0;  // pad rows -> token 0
    __syncthreads();
    for (int a = t; a < 4096; a += 256) {
      const int e = ws_idx[a];
      const int pos = atomicAdd(&fill[e], 1);
      list_token[pos] = a >> 1;
      a_of[a] = pos;
    }
  }
}

// --------- GEMM-1: fused bib gather (fp32->bf16 in-register), FT-B ----------
// C[rows,NT] = cvt_bf16(bib[list_token[row]]) @ B1_e ; K=512.
template <int NT, bool RELU>
__global__ __launch_bounds__(256)
void expert_gemm_g1(const float* __restrict__ bib, const int* __restrict__ list_token,
                    const bf16_t* __restrict__ Bft, const float* __restrict__ bias,
                    bf16_t* __restrict__ C, const int* __restrict__ offsets) {
  constexpr int K = 512, nk = K / 32;
  const int e = blockIdx.z;
  const int seg_hi = offsets[e + 1];
  const int blk_row = offsets[e] + blockIdx.y * 128;
  if (blk_row >= seg_hi) return;
  const int wave = threadIdx.x >> 6, lane = threadIdx.x & 63;
  const int row0 = blk_row + wave * 32;
  if (row0 >= seg_hi) return;
  const int n0 = blockIdx.x * 64;
  const int tok0 = list_token[row0 + (lane & 15)];
  const int tok1 = list_token[row0 + 16 + (lane & 15)];
  const float* Ap0 = bib + (size_t)tok0 * 512 + (lane >> 4) * 8;
  const float* Ap1 = bib + (size_t)tok1 * 512 + (lane >> 4) * 8;
  const bf16_t* Bp = Bft + (size_t)e * NT * K + ((size_t)(n0 >> 4) * nk * 512 + lane * 8);
  f32x4 acc[2][4];
#pragma unroll
  for (int i = 0; i < 2; i++)
#pragma unroll
    for (int j = 0; j < 4; j++) acc[i][j] = (f32x4){0.f, 0.f, 0.f, 0.f};
  f4x2 aS[2][2]; bf16x8 bX[2][4];
  aS[0][0] = ldA8(Ap0); aS[0][1] = ldA8(Ap1);
#pragma unroll
  for (int ni = 0; ni < 4; ni++) bX[0][ni] = *(const bf16x8*)(Bp + (size_t)ni * nk * 512);
#pragma unroll
  for (int kt = 0; kt < nk; kt++) {
    const int cur = kt & 1, nxt = cur ^ 1;
    if (kt + 1 < nk) {
      aS[nxt][0] = ldA8(Ap0 + (kt + 1) * 32);
      aS[nxt][1] = ldA8(Ap1 + (kt + 1) * 32);
#pragma unroll
      for (int ni = 0; ni < 4; ni++)
        bX[nxt][ni] = *(const bf16x8*)(Bp + ((size_t)ni * nk + kt + 1) * 512);
    }
    const bf16x8 a0 = cvt8(aS[cur][0]), a1 = cvt8(aS[cur][1]);
#pragma unroll
    for (int ni = 0; ni < 4; ni++) {
      acc[0][ni] = __builtin_amdgcn_mfma_f32_16x16x32_bf16(a0, bX[cur][ni], acc[0][ni], 0, 0, 0);
      acc[1][ni] = __builtin_amdgcn_mfma_f32_16x16x32_bf16(a1, bX[cur][ni], acc[1][ni], 0, 0, 0);
    }
  }
  const int fr = lane & 15, q = lane >> 4;
#pragma unroll
  for (int ni = 0; ni < 4; ni++) {
    const int col = n0 + ni * 16 + fr;
    const float bv = bias[e * NT + col];
#pragma unroll
    for (int mi = 0; mi < 2; mi++) {
#pragma unroll
      for (int r = 0; r < 4; r++) {
        const int row = row0 + mi * 16 + q * 4 + r;
        float v = acc[mi][ni][r] + bv;
        if (RELU) v = fmaxf(v, 0.f);
        C[(size_t)row * NT + col] = (bf16_t)v;
      }
    }
  }
}

// ---------------- expert GEMM: LDS-free, barrier-free, FT-B -----------------
// NFRAG n-fragments of 16 per block (block covers 16*NFRAG output cols).
template <int K, int NT, int NFRAG, bool RELU, typename OUT_T>
__global__ __launch_bounds__(256)
void expert_gemm_ft(const bf16_t* __restrict__ A, const bf16_t* __restrict__ Bft,
                    const float* __restrict__ bias, OUT_T* __restrict__ C,
                    const int* __restrict__ offsets) {
  constexpr int nk = K / 32;
  const int e = blockIdx.z;
  const int seg_hi = offsets[e + 1];
  const int blk_row = offsets[e] + blockIdx.y * 128;
  if (blk_row >= seg_hi) return;
  const int wave = threadIdx.x >> 6, lane = threadIdx.x & 63;
  const int row0 = blk_row + wave * 32;
  if (row0 >= seg_hi) return;  // wave-uniform
  const int n0 = blockIdx.x * (16 * NFRAG);
  const bf16_t* Ap = A + (size_t)(row0 + (lane & 15)) * K + ((lane >> 4) * 8);
  const bf16_t* Bp = Bft + (size_t)e * NT * K + ((size_t)(n0 >> 4) * nk * 512 + lane * 8);
  f32x4 acc[2][NFRAG];
#pragma unroll
  for (int i = 0; i < 2; i++)
#pragma unroll
    for (int j = 0; j < NFRAG; j++) acc[i][j] = (f32x4){0.f, 0.f, 0.f, 0.f};
  bf16x8 aX[2][2], bX[2][NFRAG];
#pragma unroll
  for (int mi = 0; mi < 2; mi++) aX[0][mi] = *(const bf16x8*)(Ap + mi * 16 * K);
#pragma unroll
  for (int ni = 0; ni < NFRAG; ni++) bX[0][ni] = *(const bf16x8*)(Bp + (size_t)ni * nk * 512);
#pragma unroll
  for (int kt = 0; kt < nk; kt++) {
    const int cur = kt & 1, nxt = cur ^ 1;
    if (kt + 1 < nk) {
#pragma unroll
      for (int mi = 0; mi < 2; mi++)
        aX[nxt][mi] = *(const bf16x8*)(Ap + mi * 16 * K + (kt + 1) * 32);
#pragma unroll
      for (int ni = 0; ni < NFRAG; ni++)
        bX[nxt][ni] = *(const bf16x8*)(Bp + ((size_t)ni * nk + kt + 1) * 512);
    }
#pragma unroll
    for (int mi = 0; mi < 2; mi++)
#pragma unroll
      for (int ni = 0; ni < NFRAG; ni++)
        acc[mi][ni] = __builtin_amdgcn_mfma_f32_16x16x32_bf16(aX[cur][mi], bX[cur][ni], acc[mi][ni], 0, 0, 0);
  }
  const int fr = lane & 15, q = lane >> 4;
#pragma unroll
  for (int ni = 0; ni < NFRAG; ni++) {
    const int col = n0 + ni * 16 + fr;
    const float bv = bias[e * NT + col];
#pragma unroll
    for (int mi = 0; mi < 2; mi++) {
#pragma unroll
      for (int r = 0; r < 4; r++) {
        const int row = row0 + mi * 16 + q * 4 + r;
        float v = acc[mi][ni][r] + bv;
        if (RELU) v = fmaxf(v, 0.f);
        C[(size_t)row * NT + col] = (OUT_T)v;
      }
    }
  }
}

// --------------------- head: combine folded logits -------------------------
// logits[b,c] = g0*OcH[a0,c] + g1*OcH[a1,c] + head_b[c]  (b3h already in OcH)
__global__ __launch_bounds__(256)
void head_small(const float* __restrict__ OcH, const int* __restrict__ a_of,
                const float* __restrict__ ws_gw, const float* __restrict__ head_b,
                float* __restrict__ out) {
  const int tid = blockIdx.x * 256 + threadIdx.x;
  if (tid >= 20480) return;
  const int b = tid / 10, c = tid - b * 10;
  const int a0 = a_of[b * 2], a1 = a_of[b * 2 + 1];
  const float g0 = ws_gw[b * 2], g1 = ws_gw[b * 2 + 1];
  out[tid] = g0 * OcH[(size_t)a0 * 16 + c] + g1 * OcH[(size_t)a1 * 16 + c] + head_b[c];
}

// ------------------------------ launch --------------------------------------
extern "C" void kernel_launch(void* const* d_in, const int* in_sizes, int n_in,
                              void* d_out, int out_size, void* d_ws, size_t ws_size,
                              hipStream_t stream) {
  const int* ipc_idx = (const int*)d_in[0];
  const int* role_idx = (const int*)d_in[1];
  const float* bib = (const float*)d_in[2];
  const int* maskp = (const int*)d_in[3];
  const float* ipc_emb = (const float*)d_in[5];
  const float* role_emb = (const float*)d_in[6];
  const float* Wq = (const float*)d_in[7];
  const float* bq = (const float*)d_in[8];
  const float* Wk = (const float*)d_in[9];
  const float* bk = (const float*)d_in[10];
  const float* Wv = (const float*)d_in[11];
  const float* bv = (const float*)d_in[12];
  const float* gc = (const float*)d_in[13];
  const float* ln_g = (const float*)d_in[14];
  const float* ln_b = (const float*)d_in[15];
  const float* gate_W = (const float*)d_in[16];
  const float* gate_b = (const float*)d_in[17];
  const float* exp_b = (const float*)d_in[18];
  const float* W1 = (const float*)d_in[19];
  const float* b1 = (const float*)d_in[20];
  const float* W2 = (const float*)d_in[21];
  const float* b2 = (const float*)d_in[22];
  const float* W3 = (const float*)d_in[23];
  const float* b3 = (const float*)d_in[24];
  const float* head_W = (const float*)d_in[25];
  const float* head_b = (const float*)d_in[26];

  char* ws = (char*)d_ws;
  size_t off = 0;
  auto alloc = [&](size_t bytes) -> char* {
    char* p = ws + off;
    off += (bytes + 255) & ~(size_t)255;
    return p;
  };
  float* kq_qbk = (float*)alloc(257 * 4);
  float* xbar_g = (float*)alloc((size_t)2048 * 256 * 4);
  int* ws_idx = (int*)alloc(4096 * 4);
  float* ws_gw = (float*)alloc(4096 * 4);
  int* list_tok = (int*)alloc(4608 * 4);
  int* a_of = (int*)alloc(4096 * 4);
  int* offs = (int*)alloc(9 * 4);
  int* done_ctr = (int*)alloc(4);
  float* b3h = (float*)alloc(8 * 16 * 4);
  bf16_t* hwft = (bf16_t*)alloc((size_t)16 * 64 * 8 * 2);
  bf16_t* W1t = (bf16_t*)alloc((size_t)8 * 1024 * 512 * 2);
  bf16_t* W2t = (bf16_t*)alloc((size_t)8 * 1024 * 1024 * 2);
  bf16_t* B3h = (bf16_t*)alloc((size_t)8 * 16 * 1024 * 2);
  bf16_t* H1c = (bf16_t*)alloc((size_t)4608 * 1024 * 2);
  bf16_t* H2c = (bf16_t*)alloc((size_t)4608 * 1024 * 2);
  float* OcH = (float*)alloc((size_t)4608 * 16 * 4);
  (void)in_sizes; (void)n_in; (void)out_size; (void)ws_size;

  float* out_logits = (float*)d_out;          // [2048*10]
  float* out_idx = (float*)d_out + 20480;     // [2048*2] as float

  prep_kq_kernel<<<32, 256, 0, stream>>>(Wq, bq, Wk, bk, gc, kq_qbk, done_ctr,
                                         head_W, b3, hwft, b3h);
  // 64 MFMA-fold + 2048 xbar + 1024 W1-transpose + 2048 W2-transpose = 5184
  xbar_transpose<<<5184, 256, 0, stream>>>(W1, W2, W3, W1t, W2t, B3h, hwft,
                                           ipc_idx, role_idx, maskp,
                                           ipc_emb, role_emb, kq_qbk, xbar_g);
  pool_kernel<<<256, 256, 0, stream>>>(xbar_g, Wv, bv, ln_g, ln_b, gate_W, gate_b,
                                       exp_b, out_idx, ws_idx, ws_gw,
                                       done_ctr, list_tok, a_of, offs);
  expert_gemm_g1<1024, true><<<dim3(16, 36, 8), 256, 0, stream>>>(bib, list_tok, W1t, b1, H1c, offs);
  expert_gemm_ft<1024, 1024, 4, true, bf16_t><<<dim3(16, 36, 8), 256, 0, stream>>>(H1c, W2t, b2, H2c, offs);
  expert_gemm_ft<1024, 16, 1, false, float><<<dim3(1, 36, 8), 256, 0, stream>>>(H2c, B3h, b3h, OcH, offs);
  head_small<<<80, 256, 0, stream>>>(OcH, a_of, ws_gw, head_b, out_logits);
}

// Round 8
// 342.330 us; speedup vs baseline: 1.1148x; 1.0012x over previous
//
#include <hip/hip_runtime.h>
#include <hip/hip_bf16.h>
#include <math.h>

// ---------------------------------------------------------------------------
// PatentCitationMoEModule — MI355X implementation, round 14
//  Round 13 (342.7 us) plus:
//   - W3@head_W fold EVICTED from the fused kernel into the prep dispatch
//     (prep had 32 blocks on 256 CUs; fold's 128 blocks overlap its serial
//     q-chain). hwft dependency removed: each fold block stages head_W
//     (20 KB) in LDS and builds B-fragments locally (<=2-way bank aliasing).
//   - fused kernel reverts to exactly r9's two-path form (2048 xbar + 3072
//     W1/W2 transpose): restores the 72-VGPR xbar codegen that r12/r13's
//     co-compiled fold path degraded to 80 VGPR (+13.5us).
//  Keeps: pack-in-pool merge, N=16 GEMM-3, trivial head.
// ---------------------------------------------------------------------------

#define LN_EPS 1e-5f

typedef __bf16 bf16_t;
typedef __bf16 bf16x8 __attribute__((ext_vector_type(8)));
typedef __bf16 bf16x4 __attribute__((ext_vector_type(4)));
typedef float f32x4 __attribute__((ext_vector_type(4)));

struct f4x2 { float4 a, b; };
__device__ __forceinline__ f4x2 ldA8(const float* p) {
  f4x2 v; v.a = *(const float4*)p; v.b = *(const float4*)(p + 4); return v;
}
__device__ __forceinline__ bf16x8 cvt8(const f4x2& v) {
  bf16x8 o;
  o[0] = (bf16_t)v.a.x; o[1] = (bf16_t)v.a.y; o[2] = (bf16_t)v.a.z; o[3] = (bf16_t)v.a.w;
  o[4] = (bf16_t)v.b.x; o[5] = (bf16_t)v.b.y; o[6] = (bf16_t)v.b.z; o[7] = (bf16_t)v.b.w;
  return o;
}

// -------------------- prep: kq + b3h + MFMA W3@head_W fold ------------------
// bi<32  : kq_out[0..255] = Wk @ (gc@Wq + bq); kq_out[256] = q.bk;
//          blocks 16..23 (wave 2) also b3h[e] = b3_e @ head_W (pad 10->16).
// bi>=32 : fold — B3h_ft[e] = bf16(W3_e) @ bf16(head_W) straight into FT-B
//          layout. 128 blocks, 64 rows each (1 m-tile/wave). head_W staged
//          in LDS per block (no cross-block dependency).
__global__ __launch_bounds__(256)
void prep_kernel(const float* __restrict__ Wq, const float* __restrict__ bq,
                 const float* __restrict__ Wk, const float* __restrict__ bk,
                 const float* __restrict__ gc, float* __restrict__ kq_out,
                 int* __restrict__ done_ctr,
                 const float* __restrict__ head_W, const float* __restrict__ b3,
                 const float* __restrict__ W3, bf16_t* __restrict__ B3h,
                 float* __restrict__ b3h_g) {
  __shared__ __align__(16) float smem[5120];   // prep: q[256]+red[4]; fold: head_W
  const int t = threadIdx.x, bi = blockIdx.x;
  const int lane = t & 63, wave = t >> 6;

  if (bi >= 32) {
    // ================= fold path =================
    const int bi2 = bi - 32;                  // 0..127
    const int e = bi2 >> 4, chunk = bi2 & 15;
    // stage head_W (512x10 fp32 = 20 KB) into LDS
    for (int i = t; i < 5120; i += 256) smem[i] = head_W[i];
    __syncthreads();
    const int row0 = chunk * 64 + wave * 16;
    const int c = lane & 15, koff = (lane >> 4) * 8;
    const float* Ap = W3 + ((size_t)e * 1024 + row0 + (lane & 15)) * 512 + (lane >> 4) * 8;
    f32x4 acc = (f32x4){0.f, 0.f, 0.f, 0.f};
#pragma unroll
    for (int kt = 0; kt < 16; kt++) {
      const bf16x8 a0 = cvt8(ldA8(Ap + kt * 32));
      bf16x8 b8;
#pragma unroll
      for (int j = 0; j < 8; j++) {
        const int k = kt * 32 + koff + j;
        b8[j] = (c < 10) ? (bf16_t)smem[k * 10 + c] : (bf16_t)0.f;
      }
      acc = __builtin_amdgcn_mfma_f32_16x16x32_bf16(a0, b8, acc, 0, 0, 0);
    }
    // scatter into B3h FT-B layout; jp 4-consecutive -> one 8 B store
    const int qq = lane >> 4;
    const int krow = row0 + qq * 4;
    const int ktp = krow >> 5;
    const int lanep = c | (((krow >> 3) & 3) << 4);
    const int jp = krow & 7;
    bf16x4 o4;
    o4[0] = (bf16_t)acc[0]; o4[1] = (bf16_t)acc[1];
    o4[2] = (bf16_t)acc[2]; o4[3] = (bf16_t)acc[3];
    *(bf16x4*)(B3h + (size_t)e * 16 * 1024 + ((size_t)ktp * 64 + lanep) * 8 + jp) = o4;
    return;
  }

  // ================= prep path =================
  float* q = smem;            // [256]
  float* red = smem + 256;    // [4]
  if (bi == 0 && t == 0) *done_ctr = 0;
  float s = bq[t];
  for (int d = 0; d < 256; d++) s += gc[d] * Wq[d * 256 + t];
  q[t] = s;
  __syncthreads();
  const int rl = t >> 5, sl = t & 31;
  const int r = bi * 8 + rl;
  float p = 0.f;
#pragma unroll
  for (int i = 0; i < 8; i++) { const int d = sl + 32 * i; p += Wk[r * 256 + d] * q[d]; }
#pragma unroll
  for (int o = 16; o > 0; o >>= 1) p += __shfl_down(p, o, 32);
  if (sl == 0) kq_out[r] = p;
  if (bi == 0) {
    float z2 = q[t] * bk[t];
#pragma unroll
    for (int o = 32; o > 0; o >>= 1) z2 += __shfl_down(z2, o);
    if (lane == 0) red[wave] = z2;
    __syncthreads();
    if (t == 0) kq_out[256] = red[0] + red[1] + red[2] + red[3];
  }
  // ---- b3h[e] = b3_e @ head_W (blocks 16..23, wave 2) ----
  if (bi >= 16 && bi < 24 && wave == 2) {
    const int e = bi - 16;
    float pc[10];
#pragma unroll
    for (int c2 = 0; c2 < 10; c2++) pc[c2] = 0.f;
    for (int jj = 0; jj < 8; jj++) {
      const int j = lane + jj * 64;
      const float bv = b3[e * 512 + j];
#pragma unroll
      for (int c2 = 0; c2 < 10; c2++) pc[c2] += bv * head_W[j * 10 + c2];
    }
#pragma unroll
    for (int c2 = 0; c2 < 10; c2++) {
#pragma unroll
      for (int o = 32; o > 0; o >>= 1) pc[c2] += __shfl_down(pc[c2], o);
    }
    if (lane == 0) {
#pragma unroll
      for (int c2 = 0; c2 < 10; c2++) b3h_g[e * 16 + c2] = pc[c2];
#pragma unroll
      for (int c2 = 10; c2 < 16; c2++) b3h_g[e * 16 + c2] = 0.f;
    }
  }
}

// ---------------- merged: xbar (bid<2048) + W1/W2 transpose -----------------
// FT-B: frag (nt,kt) = 64 lanes x 8 bf16; lane holds n=nt*16+(lane&15),
// k = kt*32+(lane>>4)*8 .. +7.  Flat elem offset: ((nt*(K/32)+kt)*64+lane)*8.
__global__ __launch_bounds__(256)
void xbar_transpose(const float* __restrict__ W1, const float* __restrict__ W2,
                    bf16_t* __restrict__ B1, bf16_t* __restrict__ B2,
                    const int* __restrict__ ipc_idx, const int* __restrict__ role_idx,
                    const int* __restrict__ maskp,
                    const float* __restrict__ ipc_emb, const float* __restrict__ role_emb,
                    const float* __restrict__ kq_qbk, float* __restrict__ xbar_g) {
  __shared__ __align__(16) float smem[4480];  // 17.9 KB, aliased per path
  const int bid = blockIdx.x;
  const int t = threadIdx.x, lane = t & 63;

  if (bid < 2048) {
    // ================= xbar path (register indices, r9) =================
    const int b = bid, wave = t >> 6;
    float* sred = smem;                 // [4 waves][64 lanes][17] partials
    float* scores_s = smem + 4352;      // [64]
    float* attn_s = smem + 4416;        // [64]
    const float4 kq = *(const float4*)(kq_qbk + lane * 4);
    const float qbk = kq_qbk[256];
    const int rbase = b * 64 + wave * 16;
    int4 m4[4], i4[4], r4[4];
#pragma unroll
    for (int j = 0; j < 4; j++) {
      m4[j] = *(const int4*)(maskp + rbase + j * 4);
      i4[j] = *(const int4*)(ipc_idx + rbase + j * 4);
      r4[j] = *(const int4*)(role_idx + rbase + j * 4);
    }
    // phase A: branch-free gather (masked -> zero padding row 0) + per-lane dot
#pragma unroll
    for (int i = 0; i < 16; i++) {
      const int mki = (&m4[i / 4].x)[i % 4];
      const int ii = mki ? (&i4[i / 4].x)[i % 4] : 0;
      const int ri = mki ? (&r4[i / 4].x)[i % 4] : 0;
      const float4 xe = *(const float4*)(ipc_emb + (size_t)ii * 256 + lane * 4);
      const float4 re = *(const float4*)(role_emb + (size_t)ri * 256 + lane * 4);
      sred[(wave * 64 + lane) * 17 + i] =
          (xe.x + re.x) * kq.x + (xe.y + re.y) * kq.y +
          (xe.z + re.z) * kq.z + (xe.w + re.w) * kq.w;
    }
    __syncthreads();
    // phase B: per-wave LDS-transpose reduce
    {
      const int i_r = lane & 15, g = lane >> 4;
      float s = 0.f;
#pragma unroll
      for (int j = 0; j < 16; j++) s += sred[(wave * 64 + g * 16 + j) * 17 + i_r];
      s += __shfl_xor(s, 16);
      s += __shfl_xor(s, 32);
      const int mval = (&m4[i_r / 4].x)[i_r % 4];
      if (lane < 16) scores_s[wave * 16 + lane] = mval ? (s + qbk) : -1e9f;
    }
    __syncthreads();
    // phase C: softmax over 64 scores (wave 0)
    if (wave == 0) {
      const float sv = scores_s[lane];
      float m = sv;
#pragma unroll
      for (int o = 32; o > 0; o >>= 1) m = fmaxf(m, __shfl_xor(m, o));
      const float ev = expf(sv - m);
      float sum = ev;
#pragma unroll
      for (int o = 32; o > 0; o >>= 1) sum += __shfl_xor(sum, o);
      attn_s[lane] = ev / sum;
    }
    __syncthreads();
    // phase D: branch-free re-gather (L2-hot) + attn-weighted sum
    float p0 = 0.f, p1 = 0.f, p2 = 0.f, p3 = 0.f;
#pragma unroll
    for (int i = 0; i < 16; i++) {
      const int mki = (&m4[i / 4].x)[i % 4];
      const int ii = mki ? (&i4[i / 4].x)[i % 4] : 0;
      const int ri = mki ? (&r4[i / 4].x)[i % 4] : 0;
      const float a = attn_s[wave * 16 + i];  // exactly 0 for masked rows
      const float4 xe = *(const float4*)(ipc_emb + (size_t)ii * 256 + lane * 4);
      const float4 re = *(const float4*)(role_emb + (size_t)ri * 256 + lane * 4);
      p0 += a * (xe.x + re.x); p1 += a * (xe.y + re.y);
      p2 += a * (xe.z + re.z); p3 += a * (xe.w + re.w);
    }
    __syncthreads();  // sred region no longer read; reuse as part[4][256]
    *(float4*)&smem[wave * 256 + lane * 4] = make_float4(p0, p1, p2, p3);
    __syncthreads();
    xbar_g[(size_t)b * 256 + t] = smem[t] + smem[256 + t] + smem[512 + t] + smem[768 + t];
    return;
  }

  // ================= W1/W2 transpose path =================
  const int bid2 = bid - 2048;
  const float* W; bf16_t* Bft; int K, N, e, n0, k0;
  if (bid2 < 1024) {            // W1: K=512, N=1024, 128 tiles/expert
    W = W1; Bft = B1; K = 512; N = 1024;
    e = bid2 >> 7; const int r = bid2 & 127;
    n0 = (r & 15) * 64; k0 = (r >> 4) * 64;
  } else {                      // W2: K=1024, N=1024, 256 tiles/expert
    W = W2; Bft = B2; K = 1024; N = 1024;
    const int q = bid2 - 1024; e = q >> 8; const int r = q & 255;
    n0 = (r & 15) * 64; k0 = (r >> 4) * 64;
  }
  float (*tile)[65] = (float(*)[65])smem;  // 64x65 fits in 4480 floats
  const float* Wp = W + (size_t)e * K * N;
  bf16_t* Bp = Bft + (size_t)e * N * K;
  const int tq = t & 15, th = t >> 4;  // 16 x 16
#pragma unroll
  for (int i = 0; i < 4; i++) {
    const int row = th + 16 * i;  // k-dim
    *(float4*)&tile[row][tq * 4] = *(const float4*)(Wp + (size_t)(k0 + row) * N + n0 + tq * 4);
  }
  __syncthreads();
  const int sub = t >> 6;
  const int nk = K >> 5;
#pragma unroll
  for (int it = 0; it < 2; it++) {
    const int fid = sub + it * 4;            // 8 frag-tiles in a 64x64 tile
    const int ntl = fid & 3, ktl = fid >> 2;
    const int n_l = ntl * 16 + (lane & 15);
    const int k_l = ktl * 32 + (lane >> 4) * 8;
    bf16x8 o;
#pragma unroll
    for (int j = 0; j < 8; j++) o[j] = (bf16_t)tile[k_l + j][n_l];
    const size_t idx = ((((size_t)(n0 >> 4) + ntl) * nk + (k0 >> 5) + ktl) * 64 + lane) * 8;
    *(bf16x8*)(Bp + idx) = o;
  }
}

// ------------- pool: pooled = xbar@Wv + bv, LN, gate, top2 ------------------
// Waves split the d(K)-range so Wv is read once per block (64 MB total).
// Last block to finish (device-scope counter) runs the pack stage inline.
__global__ __launch_bounds__(256)
void pool_kernel(const float* __restrict__ xbar_g, const float* __restrict__ Wv,
                 const float* __restrict__ bvec,
                 const float* __restrict__ ln_g, const float* __restrict__ ln_b,
                 const float* __restrict__ gate_W, const float* __restrict__ gate_b,
                 const float* __restrict__ expert_biases,
                 float* __restrict__ out_idx_f, int* __restrict__ ws_idx,
                 float* __restrict__ ws_gw, int* __restrict__ done_ctr,
                 int* __restrict__ list_token, int* __restrict__ a_of,
                 int* __restrict__ offsets_g) {
  const int rb = blockIdx.x * 8;
  __shared__ __align__(16) float xs[8][256];       // 8 input rows
  __shared__ __align__(16) float pp[4][8][256];    // per-wave d-partials
  __shared__ int is_last;
  const int t = threadIdx.x, wave = t >> 6, lane = t & 63;
  for (int i = t; i < 512; i += 256)
    ((float4*)xs)[i] = ((const float4*)(xbar_g + (size_t)rb * 256))[i];
  __syncthreads();
  f32x4 acc[8];
#pragma unroll
  for (int r = 0; r < 8; r++) acc[r] = (f32x4){0.f, 0.f, 0.f, 0.f};
  const int dbase = wave * 64;
  for (int dd = 0; dd < 64; dd += 4) {
    float4 xr[8];
#pragma unroll
    for (int r = 0; r < 8; r++) xr[r] = *(const float4*)&xs[r][dbase + dd];  // broadcast
#pragma unroll
    for (int j = 0; j < 4; j++) {
      const float4 wv = *(const float4*)(Wv + (size_t)(dbase + dd + j) * 256 + lane * 4);
#pragma unroll
      for (int r = 0; r < 8; r++) {
        const float xv = (&xr[r].x)[j];
        acc[r][0] += xv * wv.x; acc[r][1] += xv * wv.y;
        acc[r][2] += xv * wv.z; acc[r][3] += xv * wv.w;
      }
    }
  }
#pragma unroll
  for (int r = 0; r < 8; r++) *(f32x4*)&pp[wave][r][lane * 4] = acc[r];
  __syncthreads();
  const float4 bvv = *(const float4*)(bvec + lane * 4);
  const float4 lg = *(const float4*)(ln_g + lane * 4);
  const float4 lb = *(const float4*)(ln_b + lane * 4);
#pragma unroll
  for (int rr = 0; rr < 2; rr++) {
    const int r = wave * 2 + rr;
    f32x4 v = *(const f32x4*)&pp[0][r][lane * 4];
#pragma unroll
    for (int w2 = 1; w2 < 4; w2++) {
      const f32x4 qv = *(const f32x4*)&pp[w2][r][lane * 4];
      v[0] += qv[0]; v[1] += qv[1]; v[2] += qv[2]; v[3] += qv[3];
    }
    v[0] += bvv.x; v[1] += bvv.y; v[2] += bvv.z; v[3] += bvv.w;
    float s1 = v[0] + v[1] + v[2] + v[3];
#pragma unroll
    for (int o = 32; o > 0; o >>= 1) s1 += __shfl_xor(s1, o);
    const float mu = s1 * (1.f / 256.f);
    const float4 df = make_float4(v[0] - mu, v[1] - mu, v[2] - mu, v[3] - mu);
    float s2 = df.x * df.x + df.y * df.y + df.z * df.z + df.w * df.w;
#pragma unroll
    for (int o = 32; o > 0; o >>= 1) s2 += __shfl_xor(s2, o);
    const float inv = 1.f / sqrtf(s2 * (1.f / 256.f) + LN_EPS);
    f32x4 rv;
    rv[0] = df.x * inv * lg.x + lb.x; rv[1] = df.y * inv * lg.y + lb.y;
    rv[2] = df.z * inv * lg.z + lb.z; rv[3] = df.w * inv * lg.w + lb.w;
    f32x4 pa = {0.f, 0.f, 0.f, 0.f}, pb = {0.f, 0.f, 0.f, 0.f};
#pragma unroll
    for (int k = 0; k < 4; k++) {
      const int d = lane * 4 + k;
      const f32x4 g0 = *(const f32x4*)(gate_W + d * 8);
      const f32x4 g1 = *(const f32x4*)(gate_W + d * 8 + 4);
      pa += rv[k] * g0;
      pb += rv[k] * g1;
    }
#pragma unroll
    for (int o = 32; o > 0; o >>= 1) {
      pa[0] += __shfl_down(pa[0], o); pa[1] += __shfl_down(pa[1], o);
      pa[2] += __shfl_down(pa[2], o); pa[3] += __shfl_down(pa[3], o);
      pb[0] += __shfl_down(pb[0], o); pb[1] += __shfl_down(pb[1], o);
      pb[2] += __shfl_down(pb[2], o); pb[3] += __shfl_down(pb[3], o);
    }
    if (lane == 0) {
      float aff[8];
#pragma unroll
      for (int j = 0; j < 4; j++) { aff[j] = pa[j] + gate_b[j]; aff[4 + j] = pb[j] + gate_b[4 + j]; }
      float b0 = -1e30f; int i0 = 0;
#pragma unroll
      for (int j = 0; j < 8; j++) {
        const float s = aff[j] + expert_biases[j];
        if (s > b0) { b0 = s; i0 = j; }
      }
      float b1v = -1e30f; int i1 = 0;
#pragma unroll
      for (int j = 0; j < 8; j++) {
        const float s = aff[j] + expert_biases[j];
        if (j != i0 && s > b1v) { b1v = s; i1 = j; }
      }
      const float a0 = aff[i0], a1 = aff[i1];
      const float m = fmaxf(a0, a1);
      const float e0 = expf(a0 - m), e1 = expf(a1 - m);
      const float invs = 1.f / (e0 + e1);
      const int bg = rb + r;
      ws_idx[bg * 2] = i0; ws_idx[bg * 2 + 1] = i1;
      ws_gw[bg * 2] = e0 * invs; ws_gw[bg * 2 + 1] = e1 * invs;
      out_idx_f[bg * 2] = (float)i0; out_idx_f[bg * 2 + 1] = (float)i1;
    }
  }
  // ---- last-block-done: run pack inline (device-scope handoff) ----
  __syncthreads();
  if (t == 0) {
    __threadfence();                       // release this block's ws_idx
    const int prev = atomicAdd(done_ctr, 1);
    is_last = (prev == (int)gridDim.x - 1);
  }
  __syncthreads();
  if (is_last) {
    __threadfence();                       // acquire all blocks' ws_idx
    __shared__ int cnt[8]; __shared__ int offp[9]; __shared__ int fill[8];
    if (t < 8) cnt[t] = 0;
    __syncthreads();
    for (int a = t; a < 4096; a += 256) atomicAdd(&cnt[ws_idx[a]], 1);
    __syncthreads();
    if (t == 0) {
      offp[0] = 0;
      for (int e = 0; e < 8; e++) offp[e + 1] = offp[e] + ((cnt[e] + 63) & ~63);
    }
    __syncthreads();
    if (t < 8) fill[t] = offp[t];
    if (t < 9) offsets_g[t] = offp[t];
    for (int a = t; a < 4608; a += 256) list_token[a] = 0;  // pad rows -> token 0
    __syncthreads();
    for (int a = t; a < 4096; a += 256) {
      const int e = ws_idx[a];
      const int pos = atomicAdd(&fill[e], 1);
      list_token[pos] = a >> 1;
      a_of[a] = pos;
    }
  }
}

// --------- GEMM-1: fused bib gather (fp32->bf16 in-register), FT-B ----------
// C[rows,NT] = cvt_bf16(bib[list_token[row]]) @ B1_e ; K=512.
template <int NT, bool RELU>
__global__ __launch_bounds__(256)
void expert_gemm_g1(const float* __restrict__ bib, const int* __restrict__ list_token,
                    const bf16_t* __restrict__ Bft, const float* __restrict__ bias,
                    bf16_t* __restrict__ C, const int* __restrict__ offsets) {
  constexpr int K = 512, nk = K / 32;
  const int e = blockIdx.z;
  const int seg_hi = offsets[e + 1];
  const int blk_row = offsets[e] + blockIdx.y * 128;
  if (blk_row >= seg_hi) return;
  const int wave = threadIdx.x >> 6, lane = threadIdx.x & 63;
  const int row0 = blk_row + wave * 32;
  if (row0 >= seg_hi) return;
  const int n0 = blockIdx.x * 64;
  const int tok0 = list_token[row0 + (lane & 15)];
  const int tok1 = list_token[row0 + 16 + (lane & 15)];
  const float* Ap0 = bib + (size_t)tok0 * 512 + (lane >> 4) * 8;
  const float* Ap1 = bib + (size_t)tok1 * 512 + (lane >> 4) * 8;
  const bf16_t* Bp = Bft + (size_t)e * NT * K + ((size_t)(n0 >> 4) * nk * 512 + lane * 8);
  f32x4 acc[2][4];
#pragma unroll
  for (int i = 0; i < 2; i++)
#pragma unroll
    for (int j = 0; j < 4; j++) acc[i][j] = (f32x4){0.f, 0.f, 0.f, 0.f};
  f4x2 aS[2][2]; bf16x8 bX[2][4];
  aS[0][0] = ldA8(Ap0); aS[0][1] = ldA8(Ap1);
#pragma unroll
  for (int ni = 0; ni < 4; ni++) bX[0][ni] = *(const bf16x8*)(Bp + (size_t)ni * nk * 512);
#pragma unroll
  for (int kt = 0; kt < nk; kt++) {
    const int cur = kt & 1, nxt = cur ^ 1;
    if (kt + 1 < nk) {
      aS[nxt][0] = ldA8(Ap0 + (kt + 1) * 32);
      aS[nxt][1] = ldA8(Ap1 + (kt + 1) * 32);
#pragma unroll
      for (int ni = 0; ni < 4; ni++)
        bX[nxt][ni] = *(const bf16x8*)(Bp + ((size_t)ni * nk + kt + 1) * 512);
    }
    const bf16x8 a0 = cvt8(aS[cur][0]), a1 = cvt8(aS[cur][1]);
#pragma unroll
    for (int ni = 0; ni < 4; ni++) {
      acc[0][ni] = __builtin_amdgcn_mfma_f32_16x16x32_bf16(a0, bX[cur][ni], acc[0][ni], 0, 0, 0);
      acc[1][ni] = __builtin_amdgcn_mfma_f32_16x16x32_bf16(a1, bX[cur][ni], acc[1][ni], 0, 0, 0);
    }
  }
  const int fr = lane & 15, q = lane >> 4;
#pragma unroll
  for (int ni = 0; ni < 4; ni++) {
    const int col = n0 + ni * 16 + fr;
    const float bv = bias[e * NT + col];
#pragma unroll
    for (int mi = 0; mi < 2; mi++) {
#pragma unroll
      for (int r = 0; r < 4; r++) {
        const int row = row0 + mi * 16 + q * 4 + r;
        float v = acc[mi][ni][r] + bv;
        if (RELU) v = fmaxf(v, 0.f);
        C[(size_t)row * NT + col] = (bf16_t)v;
      }
    }
  }
}

// ---------------- expert GEMM: LDS-free, barrier-free, FT-B -----------------
// NFRAG n-fragments of 16 per block (block covers 16*NFRAG output cols).
template <int K, int NT, int NFRAG, bool RELU, typename OUT_T>
__global__ __launch_bounds__(256)
void expert_gemm_ft(const bf16_t* __restrict__ A, const bf16_t* __restrict__ Bft,
                    const float* __restrict__ bias, OUT_T* __restrict__ C,
                    const int* __restrict__ offsets) {
  constexpr int nk = K / 32;
  const int e = blockIdx.z;
  const int seg_hi = offsets[e + 1];
  const int blk_row = offsets[e] + blockIdx.y * 128;
  if (blk_row >= seg_hi) return;
  const int wave = threadIdx.x >> 6, lane = threadIdx.x & 63;
  const int row0 = blk_row + wave * 32;
  if (row0 >= seg_hi) return;  // wave-uniform
  const int n0 = blockIdx.x * (16 * NFRAG);
  const bf16_t* Ap = A + (size_t)(row0 + (lane & 15)) * K + ((lane >> 4) * 8);
  const bf16_t* Bp = Bft + (size_t)e * NT * K + ((size_t)(n0 >> 4) * nk * 512 + lane * 8);
  f32x4 acc[2][NFRAG];
#pragma unroll
  for (int i = 0; i < 2; i++)
#pragma unroll
    for (int j = 0; j < NFRAG; j++) acc[i][j] = (f32x4){0.f, 0.f, 0.f, 0.f};
  bf16x8 aX[2][2], bX[2][NFRAG];
#pragma unroll
  for (int mi = 0; mi < 2; mi++) aX[0][mi] = *(const bf16x8*)(Ap + mi * 16 * K);
#pragma unroll
  for (int ni = 0; ni < NFRAG; ni++) bX[0][ni] = *(const bf16x8*)(Bp + (size_t)ni * nk * 512);
#pragma unroll
  for (int kt = 0; kt < nk; kt++) {
    const int cur = kt & 1, nxt = cur ^ 1;
    if (kt + 1 < nk) {
#pragma unroll
      for (int mi = 0; mi < 2; mi++)
        aX[nxt][mi] = *(const bf16x8*)(Ap + mi * 16 * K + (kt + 1) * 32);
#pragma unroll
      for (int ni = 0; ni < NFRAG; ni++)
        bX[nxt][ni] = *(const bf16x8*)(Bp + ((size_t)ni * nk + kt + 1) * 512);
    }
#pragma unroll
    for (int mi = 0; mi < 2; mi++)
#pragma unroll
      for (int ni = 0; ni < NFRAG; ni++)
        acc[mi][ni] = __builtin_amdgcn_mfma_f32_16x16x32_bf16(aX[cur][mi], bX[cur][ni], acc[mi][ni], 0, 0, 0);
  }
  const int fr = lane & 15, q = lane >> 4;
#pragma unroll
  for (int ni = 0; ni < NFRAG; ni++) {
    const int col = n0 + ni * 16 + fr;
    const float bv = bias[e * NT + col];
#pragma unroll
    for (int mi = 0; mi < 2; mi++) {
#pragma unroll
      for (int r = 0; r < 4; r++) {
        const int row = row0 + mi * 16 + q * 4 + r;
        float v = acc[mi][ni][r] + bv;
        if (RELU) v = fmaxf(v, 0.f);
        C[(size_t)row * NT + col] = (OUT_T)v;
      }
    }
  }
}

// --------------------- head: combine folded logits -------------------------
// logits[b,c] = g0*OcH[a0,c] + g1*OcH[a1,c] + head_b[c]  (b3h already in OcH)
__global__ __launch_bounds__(256)
void head_small(const float* __restrict__ OcH, const int* __restrict__ a_of,
                const float* __restrict__ ws_gw, const float* __restrict__ head_b,
                float* __restrict__ out) {
  const int tid = blockIdx.x * 256 + threadIdx.x;
  if (tid >= 20480) return;
  const int b = tid / 10, c = tid - b * 10;
  const int a0 = a_of[b * 2], a1 = a_of[b * 2 + 1];
  const float g0 = ws_gw[b * 2], g1 = ws_gw[b * 2 + 1];
  out[tid] = g0 * OcH[(size_t)a0 * 16 + c] + g1 * OcH[(size_t)a1 * 16 + c] + head_b[c];
}

// ------------------------------ launch --------------------------------------
extern "C" void kernel_launch(void* const* d_in, const int* in_sizes, int n_in,
                              void* d_out, int out_size, void* d_ws, size_t ws_size,
                              hipStream_t stream) {
  const int* ipc_idx = (const int*)d_in[0];
  const int* role_idx = (const int*)d_in[1];
  const float* bib = (const float*)d_in[2];
  const int* maskp = (const int*)d_in[3];
  const float* ipc_emb = (const float*)d_in[5];
  const float* role_emb = (const float*)d_in[6];
  const float* Wq = (const float*)d_in[7];
  const float* bq = (const float*)d_in[8];
  const float* Wk = (const float*)d_in[9];
  const float* bk = (const float*)d_in[10];
  const float* Wv = (const float*)d_in[11];
  const float* bv = (const float*)d_in[12];
  const float* gc = (const float*)d_in[13];
  const float* ln_g = (const float*)d_in[14];
  const float* ln_b = (const float*)d_in[15];
  const float* gate_W = (const float*)d_in[16];
  const float* gate_b = (const float*)d_in[17];
  const float* exp_b = (const float*)d_in[18];
  const float* W1 = (const float*)d_in[19];
  const float* b1 = (const float*)d_in[20];
  const float* W2 = (const float*)d_in[21];
  const float* b2 = (const float*)d_in[22];
  const float* W3 = (const float*)d_in[23];
  const float* b3 = (const float*)d_in[24];
  const float* head_W = (const float*)d_in[25];
  const float* head_b = (const float*)d_in[26];

  char* ws = (char*)d_ws;
  size_t off = 0;
  auto alloc = [&](size_t bytes) -> char* {
    char* p = ws + off;
    off += (bytes + 255) & ~(size_t)255;
    return p;
  };
  float* kq_qbk = (float*)alloc(257 * 4);
  float* xbar_g = (float*)alloc((size_t)2048 * 256 * 4);
  int* ws_idx = (int*)alloc(4096 * 4);
  float* ws_gw = (float*)alloc(4096 * 4);
  int* list_tok = (int*)alloc(4608 * 4);
  int* a_of = (int*)alloc(4096 * 4);
  int* offs = (int*)alloc(9 * 4);
  int* done_ctr = (int*)alloc(4);
  float* b3h = (float*)alloc(8 * 16 * 4);
  bf16_t* W1t = (bf16_t*)alloc((size_t)8 * 1024 * 512 * 2);
  bf16_t* W2t = (bf16_t*)alloc((size_t)8 * 1024 * 1024 * 2);
  bf16_t* B3h = (bf16_t*)alloc((size_t)8 * 16 * 1024 * 2);
  bf16_t* H1c = (bf16_t*)alloc((size_t)4608 * 1024 * 2);
  bf16_t* H2c = (bf16_t*)alloc((size_t)4608 * 1024 * 2);
  float* OcH = (float*)alloc((size_t)4608 * 16 * 4);
  (void)in_sizes; (void)n_in; (void)out_size; (void)ws_size;

  float* out_logits = (float*)d_out;          // [2048*10]
  float* out_idx = (float*)d_out + 20480;     // [2048*2] as float

  // 32 prep blocks + 128 fold blocks (fold overlaps prep's serial q-chain)
  prep_kernel<<<160, 256, 0, stream>>>(Wq, bq, Wk, bk, gc, kq_qbk, done_ctr,
                                       head_W, b3, W3, B3h, b3h);
  // 2048 xbar + 1024 W1-transpose + 2048 W2-transpose = 5120 (r9 structure)
  xbar_transpose<<<5120, 256, 0, stream>>>(W1, W2, W1t, W2t,
                                           ipc_idx, role_idx, maskp,
                                           ipc_emb, role_emb, kq_qbk, xbar_g);
  pool_kernel<<<256, 256, 0, stream>>>(xbar_g, Wv, bv, ln_g, ln_b, gate_W, gate_b,
                                       exp_b, out_idx, ws_idx, ws_gw,
                                       done_ctr, list_tok, a_of, offs);
  expert_gemm_g1<1024, true><<<dim3(16, 36, 8), 256, 0, stream>>>(bib, list_tok, W1t, b1, H1c, offs);
  expert_gemm_ft<1024, 1024, 4, true, bf16_t><<<dim3(16, 36, 8), 256, 0, stream>>>(H1c, W2t, b2, H2c, offs);
  expert_gemm_ft<1024, 16, 1, false, float><<<dim3(1, 36, 8), 256, 0, stream>>>(H2c, B3h, b3h, OcH, offs);
  head_small<<<80, 256, 0, stream>>>(OcH, a_of, ws_gw, head_b, out_logits);
}

// Round 9
// 325.296 us; speedup vs baseline: 1.1732x; 1.0524x over previous
//
#include <hip/hip_runtime.h>
#include <hip/hip_bf16.h>
#include <math.h>

// ---------------------------------------------------------------------------
// PatentCitationMoEModule — MI355X implementation, round 15
//  Round 14 (342.3 us) plus:
//   - xbar de-spilled: r11 introduced a runtime index into the m4/i4/r4
//     register arrays in phase B ((&m4[i_r/4].x)[i_r%4]) -> compiler put all
//     48 index regs in scratch (FETCH +20MB / WRITE +24MB vs r9, fused stuck
//     >=67us). Phase B now reloads maskp from memory (r9 form), and the
//     per-row state is packed into ONE unsigned per row (ii | ri<<18 |
//     valid<<31): 16 VGPR instead of 48, all accesses compile-time-indexed.
//     Masked rows pack to 0 -> gather the all-zero padding rows (exact).
//  Keeps: fold-in-prep, pack-in-pool merge, N=16 GEMM-3, trivial head.
// ---------------------------------------------------------------------------

#define LN_EPS 1e-5f

typedef __bf16 bf16_t;
typedef __bf16 bf16x8 __attribute__((ext_vector_type(8)));
typedef __bf16 bf16x4 __attribute__((ext_vector_type(4)));
typedef float f32x4 __attribute__((ext_vector_type(4)));

struct f4x2 { float4 a, b; };
__device__ __forceinline__ f4x2 ldA8(const float* p) {
  f4x2 v; v.a = *(const float4*)p; v.b = *(const float4*)(p + 4); return v;
}
__device__ __forceinline__ bf16x8 cvt8(const f4x2& v) {
  bf16x8 o;
  o[0] = (bf16_t)v.a.x; o[1] = (bf16_t)v.a.y; o[2] = (bf16_t)v.a.z; o[3] = (bf16_t)v.a.w;
  o[4] = (bf16_t)v.b.x; o[5] = (bf16_t)v.b.y; o[6] = (bf16_t)v.b.z; o[7] = (bf16_t)v.b.w;
  return o;
}

// -------------------- prep: kq + b3h + MFMA W3@head_W fold ------------------
// bi<32  : kq_out[0..255] = Wk @ (gc@Wq + bq); kq_out[256] = q.bk;
//          blocks 16..23 (wave 2) also b3h[e] = b3_e @ head_W (pad 10->16).
// bi>=32 : fold — B3h_ft[e] = bf16(W3_e) @ bf16(head_W) straight into FT-B
//          layout. 128 blocks, 64 rows each (1 m-tile/wave). head_W staged
//          in LDS per block (no cross-block dependency).
__global__ __launch_bounds__(256)
void prep_kernel(const float* __restrict__ Wq, const float* __restrict__ bq,
                 const float* __restrict__ Wk, const float* __restrict__ bk,
                 const float* __restrict__ gc, float* __restrict__ kq_out,
                 int* __restrict__ done_ctr,
                 const float* __restrict__ head_W, const float* __restrict__ b3,
                 const float* __restrict__ W3, bf16_t* __restrict__ B3h,
                 float* __restrict__ b3h_g) {
  __shared__ __align__(16) float smem[5120];   // prep: q[256]+red[4]; fold: head_W
  const int t = threadIdx.x, bi = blockIdx.x;
  const int lane = t & 63, wave = t >> 6;

  if (bi >= 32) {
    // ================= fold path =================
    const int bi2 = bi - 32;                  // 0..127
    const int e = bi2 >> 4, chunk = bi2 & 15;
    // stage head_W (512x10 fp32 = 20 KB) into LDS
    for (int i = t; i < 5120; i += 256) smem[i] = head_W[i];
    __syncthreads();
    const int row0 = chunk * 64 + wave * 16;
    const int c = lane & 15, koff = (lane >> 4) * 8;
    const float* Ap = W3 + ((size_t)e * 1024 + row0 + (lane & 15)) * 512 + (lane >> 4) * 8;
    f32x4 acc = (f32x4){0.f, 0.f, 0.f, 0.f};
#pragma unroll
    for (int kt = 0; kt < 16; kt++) {
      const bf16x8 a0 = cvt8(ldA8(Ap + kt * 32));
      bf16x8 b8;
#pragma unroll
      for (int j = 0; j < 8; j++) {
        const int k = kt * 32 + koff + j;
        b8[j] = (c < 10) ? (bf16_t)smem[k * 10 + c] : (bf16_t)0.f;
      }
      acc = __builtin_amdgcn_mfma_f32_16x16x32_bf16(a0, b8, acc, 0, 0, 0);
    }
    // scatter into B3h FT-B layout; jp 4-consecutive -> one 8 B store
    const int qq = lane >> 4;
    const int krow = row0 + qq * 4;
    const int ktp = krow >> 5;
    const int lanep = c | (((krow >> 3) & 3) << 4);
    const int jp = krow & 7;
    bf16x4 o4;
    o4[0] = (bf16_t)acc[0]; o4[1] = (bf16_t)acc[1];
    o4[2] = (bf16_t)acc[2]; o4[3] = (bf16_t)acc[3];
    *(bf16x4*)(B3h + (size_t)e * 16 * 1024 + ((size_t)ktp * 64 + lanep) * 8 + jp) = o4;
    return;
  }

  // ================= prep path =================
  float* q = smem;            // [256]
  float* red = smem + 256;    // [4]
  if (bi == 0 && t == 0) *done_ctr = 0;
  float s = bq[t];
  for (int d = 0; d < 256; d++) s += gc[d] * Wq[d * 256 + t];
  q[t] = s;
  __syncthreads();
  const int rl = t >> 5, sl = t & 31;
  const int r = bi * 8 + rl;
  float p = 0.f;
#pragma unroll
  for (int i = 0; i < 8; i++) { const int d = sl + 32 * i; p += Wk[r * 256 + d] * q[d]; }
#pragma unroll
  for (int o = 16; o > 0; o >>= 1) p += __shfl_down(p, o, 32);
  if (sl == 0) kq_out[r] = p;
  if (bi == 0) {
    float z2 = q[t] * bk[t];
#pragma unroll
    for (int o = 32; o > 0; o >>= 1) z2 += __shfl_down(z2, o);
    if (lane == 0) red[wave] = z2;
    __syncthreads();
    if (t == 0) kq_out[256] = red[0] + red[1] + red[2] + red[3];
  }
  // ---- b3h[e] = b3_e @ head_W (blocks 16..23, wave 2) ----
  if (bi >= 16 && bi < 24 && wave == 2) {
    const int e = bi - 16;
    float pc[10];
#pragma unroll
    for (int c2 = 0; c2 < 10; c2++) pc[c2] = 0.f;
    for (int jj = 0; jj < 8; jj++) {
      const int j = lane + jj * 64;
      const float bv = b3[e * 512 + j];
#pragma unroll
      for (int c2 = 0; c2 < 10; c2++) pc[c2] += bv * head_W[j * 10 + c2];
    }
#pragma unroll
    for (int c2 = 0; c2 < 10; c2++) {
#pragma unroll
      for (int o = 32; o > 0; o >>= 1) pc[c2] += __shfl_down(pc[c2], o);
    }
    if (lane == 0) {
#pragma unroll
      for (int c2 = 0; c2 < 10; c2++) b3h_g[e * 16 + c2] = pc[c2];
#pragma unroll
      for (int c2 = 10; c2 < 16; c2++) b3h_g[e * 16 + c2] = 0.f;
    }
  }
}

// ---------------- merged: xbar (bid<2048) + W1/W2 transpose -----------------
// FT-B: frag (nt,kt) = 64 lanes x 8 bf16; lane holds n=nt*16+(lane&15),
// k = kt*32+(lane>>4)*8 .. +7.  Flat elem offset: ((nt*(K/32)+kt)*64+lane)*8.
__global__ __launch_bounds__(256)
void xbar_transpose(const float* __restrict__ W1, const float* __restrict__ W2,
                    bf16_t* __restrict__ B1, bf16_t* __restrict__ B2,
                    const int* __restrict__ ipc_idx, const int* __restrict__ role_idx,
                    const int* __restrict__ maskp,
                    const float* __restrict__ ipc_emb, const float* __restrict__ role_emb,
                    const float* __restrict__ kq_qbk, float* __restrict__ xbar_g) {
  __shared__ __align__(16) float smem[4480];  // 17.9 KB, aliased per path
  const int bid = blockIdx.x;
  const int t = threadIdx.x, lane = t & 63;

  if (bid < 2048) {
    // ========== xbar path: packed per-row state, no dynamic reg index ======
    const int b = bid, wave = t >> 6;
    float* sred = smem;                 // [4 waves][64 lanes][17] partials
    float* scores_s = smem + 4352;      // [64]
    float* attn_s = smem + 4416;        // [64]
    const float4 kq = *(const float4*)(kq_qbk + lane * 4);
    const float qbk = kq_qbk[256];
    const int rbase = b * 64 + wave * 16;
    // packed row state: ii (17b) | ri<<18 (4b) | valid<<31; masked -> 0
    // (row 0 of both tables is the all-zero padding row).
    unsigned pk[16];
#pragma unroll
    for (int j = 0; j < 4; j++) {
      const int4 mm = *(const int4*)(maskp + rbase + j * 4);
      const int4 iv = *(const int4*)(ipc_idx + rbase + j * 4);
      const int4 rv = *(const int4*)(role_idx + rbase + j * 4);
      pk[j * 4 + 0] = mm.x ? ((unsigned)iv.x | ((unsigned)rv.x << 18) | 0x80000000u) : 0u;
      pk[j * 4 + 1] = mm.y ? ((unsigned)iv.y | ((unsigned)rv.y << 18) | 0x80000000u) : 0u;
      pk[j * 4 + 2] = mm.z ? ((unsigned)iv.z | ((unsigned)rv.z << 18) | 0x80000000u) : 0u;
      pk[j * 4 + 3] = mm.w ? ((unsigned)iv.w | ((unsigned)rv.w << 18) | 0x80000000u) : 0u;
    }
    // phase A: branch-free gather + per-lane dot
#pragma unroll
    for (int i = 0; i < 16; i++) {
      const unsigned p = pk[i];
      const int ii = (int)(p & 0x3FFFFu);
      const int ri = (int)((p >> 18) & 0xFu);
      const float4 xe = *(const float4*)(ipc_emb + (size_t)ii * 256 + lane * 4);
      const float4 re = *(const float4*)(role_emb + (size_t)ri * 256 + lane * 4);
      sred[(wave * 64 + lane) * 17 + i] =
          (xe.x + re.x) * kq.x + (xe.y + re.y) * kq.y +
          (xe.z + re.z) * kq.z + (xe.w + re.w) * kq.w;
    }
    __syncthreads();
    // phase B: per-wave LDS-transpose reduce; mask reloaded from memory
    // (L2-hot) — NO runtime index into register arrays (rule #20).
    {
      const int i_r = lane & 15, g = lane >> 4;
      float s = 0.f;
#pragma unroll
      for (int j = 0; j < 16; j++) s += sred[(wave * 64 + g * 16 + j) * 17 + i_r];
      s += __shfl_xor(s, 16);
      s += __shfl_xor(s, 32);
      const int mval = maskp[rbase + i_r];
      if (lane < 16) scores_s[wave * 16 + lane] = mval ? (s + qbk) : -1e9f;
    }
    __syncthreads();
    // phase C: softmax over 64 scores (wave 0)
    if (wave == 0) {
      const float sv = scores_s[lane];
      float m = sv;
#pragma unroll
      for (int o = 32; o > 0; o >>= 1) m = fmaxf(m, __shfl_xor(m, o));
      const float ev = expf(sv - m);
      float sum = ev;
#pragma unroll
      for (int o = 32; o > 0; o >>= 1) sum += __shfl_xor(sum, o);
      attn_s[lane] = ev / sum;
    }
    __syncthreads();
    // phase D: branch-free re-gather (L2/L3-hot) + attn-weighted sum
    float p0 = 0.f, p1 = 0.f, p2 = 0.f, p3 = 0.f;
#pragma unroll
    for (int i = 0; i < 16; i++) {
      const unsigned p = pk[i];
      const int ii = (int)(p & 0x3FFFFu);
      const int ri = (int)((p >> 18) & 0xFu);
      const float a = attn_s[wave * 16 + i];  // exactly 0 for masked rows
      const float4 xe = *(const float4*)(ipc_emb + (size_t)ii * 256 + lane * 4);
      const float4 re = *(const float4*)(role_emb + (size_t)ri * 256 + lane * 4);
      p0 += a * (xe.x + re.x); p1 += a * (xe.y + re.y);
      p2 += a * (xe.z + re.z); p3 += a * (xe.w + re.w);
    }
    __syncthreads();  // sred region no longer read; reuse as part[4][256]
    *(float4*)&smem[wave * 256 + lane * 4] = make_float4(p0, p1, p2, p3);
    __syncthreads();
    xbar_g[(size_t)b * 256 + t] = smem[t] + smem[256 + t] + smem[512 + t] + smem[768 + t];
    return;
  }

  // ================= W1/W2 transpose path =================
  const int bid2 = bid - 2048;
  const float* W; bf16_t* Bft; int K, N, e, n0, k0;
  if (bid2 < 1024) {            // W1: K=512, N=1024, 128 tiles/expert
    W = W1; Bft = B1; K = 512; N = 1024;
    e = bid2 >> 7; const int r = bid2 & 127;
    n0 = (r & 15) * 64; k0 = (r >> 4) * 64;
  } else {                      // W2: K=1024, N=1024, 256 tiles/expert
    W = W2; Bft = B2; K = 1024; N = 1024;
    const int q = bid2 - 1024; e = q >> 8; const int r = q & 255;
    n0 = (r & 15) * 64; k0 = (r >> 4) * 64;
  }
  float (*tile)[65] = (float(*)[65])smem;  // 64x65 fits in 4480 floats
  const float* Wp = W + (size_t)e * K * N;
  bf16_t* Bp = Bft + (size_t)e * N * K;
  const int tq = t & 15, th = t >> 4;  // 16 x 16
#pragma unroll
  for (int i = 0; i < 4; i++) {
    const int row = th + 16 * i;  // k-dim
    *(float4*)&tile[row][tq * 4] = *(const float4*)(Wp + (size_t)(k0 + row) * N + n0 + tq * 4);
  }
  __syncthreads();
  const int sub = t >> 6;
  const int nk = K >> 5;
#pragma unroll
  for (int it = 0; it < 2; it++) {
    const int fid = sub + it * 4;            // 8 frag-tiles in a 64x64 tile
    const int ntl = fid & 3, ktl = fid >> 2;
    const int n_l = ntl * 16 + (lane & 15);
    const int k_l = ktl * 32 + (lane >> 4) * 8;
    bf16x8 o;
#pragma unroll
    for (int j = 0; j < 8; j++) o[j] = (bf16_t)tile[k_l + j][n_l];
    const size_t idx = ((((size_t)(n0 >> 4) + ntl) * nk + (k0 >> 5) + ktl) * 64 + lane) * 8;
    *(bf16x8*)(Bp + idx) = o;
  }
}

// ------------- pool: pooled = xbar@Wv + bv, LN, gate, top2 ------------------
// Waves split the d(K)-range so Wv is read once per block (64 MB total).
// Last block to finish (device-scope counter) runs the pack stage inline.
__global__ __launch_bounds__(256)
void pool_kernel(const float* __restrict__ xbar_g, const float* __restrict__ Wv,
                 const float* __restrict__ bvec,
                 const float* __restrict__ ln_g, const float* __restrict__ ln_b,
                 const float* __restrict__ gate_W, const float* __restrict__ gate_b,
                 const float* __restrict__ expert_biases,
                 float* __restrict__ out_idx_f, int* __restrict__ ws_idx,
                 float* __restrict__ ws_gw, int* __restrict__ done_ctr,
                 int* __restrict__ list_token, int* __restrict__ a_of,
                 int* __restrict__ offsets_g) {
  const int rb = blockIdx.x * 8;
  __shared__ __align__(16) float xs[8][256];       // 8 input rows
  __shared__ __align__(16) float pp[4][8][256];    // per-wave d-partials
  __shared__ int is_last;
  const int t = threadIdx.x, wave = t >> 6, lane = t & 63;
  for (int i = t; i < 512; i += 256)
    ((float4*)xs)[i] = ((const float4*)(xbar_g + (size_t)rb * 256))[i];
  __syncthreads();
  f32x4 acc[8];
#pragma unroll
  for (int r = 0; r < 8; r++) acc[r] = (f32x4){0.f, 0.f, 0.f, 0.f};
  const int dbase = wave * 64;
  for (int dd = 0; dd < 64; dd += 4) {
    float4 xr[8];
#pragma unroll
    for (int r = 0; r < 8; r++) xr[r] = *(const float4*)&xs[r][dbase + dd];  // broadcast
#pragma unroll
    for (int j = 0; j < 4; j++) {
      const float4 wv = *(const float4*)(Wv + (size_t)(dbase + dd + j) * 256 + lane * 4);
#pragma unroll
      for (int r = 0; r < 8; r++) {
        const float xv = (&xr[r].x)[j];
        acc[r][0] += xv * wv.x; acc[r][1] += xv * wv.y;
        acc[r][2] += xv * wv.z; acc[r][3] += xv * wv.w;
      }
    }
  }
#pragma unroll
  for (int r = 0; r < 8; r++) *(f32x4*)&pp[wave][r][lane * 4] = acc[r];
  __syncthreads();
  const float4 bvv = *(const float4*)(bvec + lane * 4);
  const float4 lg = *(const float4*)(ln_g + lane * 4);
  const float4 lb = *(const float4*)(ln_b + lane * 4);
#pragma unroll
  for (int rr = 0; rr < 2; rr++) {
    const int r = wave * 2 + rr;
    f32x4 v = *(const f32x4*)&pp[0][r][lane * 4];
#pragma unroll
    for (int w2 = 1; w2 < 4; w2++) {
      const f32x4 qv = *(const f32x4*)&pp[w2][r][lane * 4];
      v[0] += qv[0]; v[1] += qv[1]; v[2] += qv[2]; v[3] += qv[3];
    }
    v[0] += bvv.x; v[1] += bvv.y; v[2] += bvv.z; v[3] += bvv.w;
    float s1 = v[0] + v[1] + v[2] + v[3];
#pragma unroll
    for (int o = 32; o > 0; o >>= 1) s1 += __shfl_xor(s1, o);
    const float mu = s1 * (1.f / 256.f);
    const float4 df = make_float4(v[0] - mu, v[1] - mu, v[2] - mu, v[3] - mu);
    float s2 = df.x * df.x + df.y * df.y + df.z * df.z + df.w * df.w;
#pragma unroll
    for (int o = 32; o > 0; o >>= 1) s2 += __shfl_xor(s2, o);
    const float inv = 1.f / sqrtf(s2 * (1.f / 256.f) + LN_EPS);
    f32x4 rv;
    rv[0] = df.x * inv * lg.x + lb.x; rv[1] = df.y * inv * lg.y + lb.y;
    rv[2] = df.z * inv * lg.z + lb.z; rv[3] = df.w * inv * lg.w + lb.w;
    f32x4 pa = {0.f, 0.f, 0.f, 0.f}, pb = {0.f, 0.f, 0.f, 0.f};
#pragma unroll
    for (int k = 0; k < 4; k++) {
      const int d = lane * 4 + k;
      const f32x4 g0 = *(const f32x4*)(gate_W + d * 8);
      const f32x4 g1 = *(const f32x4*)(gate_W + d * 8 + 4);
      pa += rv[k] * g0;
      pb += rv[k] * g1;
    }
#pragma unroll
    for (int o = 32; o > 0; o >>= 1) {
      pa[0] += __shfl_down(pa[0], o); pa[1] += __shfl_down(pa[1], o);
      pa[2] += __shfl_down(pa[2], o); pa[3] += __shfl_down(pa[3], o);
      pb[0] += __shfl_down(pb[0], o); pb[1] += __shfl_down(pb[1], o);
      pb[2] += __shfl_down(pb[2], o); pb[3] += __shfl_down(pb[3], o);
    }
    if (lane == 0) {
      float aff[8];
#pragma unroll
      for (int j = 0; j < 4; j++) { aff[j] = pa[j] + gate_b[j]; aff[4 + j] = pb[j] + gate_b[4 + j]; }
      float b0 = -1e30f; int i0 = 0;
#pragma unroll
      for (int j = 0; j < 8; j++) {
        const float s = aff[j] + expert_biases[j];
        if (s > b0) { b0 = s; i0 = j; }
      }
      float b1v = -1e30f; int i1 = 0;
#pragma unroll
      for (int j = 0; j < 8; j++) {
        const float s = aff[j] + expert_biases[j];
        if (j != i0 && s > b1v) { b1v = s; i1 = j; }
      }
      const float a0 = aff[i0], a1 = aff[i1];
      const float m = fmaxf(a0, a1);
      const float e0 = expf(a0 - m), e1 = expf(a1 - m);
      const float invs = 1.f / (e0 + e1);
      const int bg = rb + r;
      ws_idx[bg * 2] = i0; ws_idx[bg * 2 + 1] = i1;
      ws_gw[bg * 2] = e0 * invs; ws_gw[bg * 2 + 1] = e1 * invs;
      out_idx_f[bg * 2] = (float)i0; out_idx_f[bg * 2 + 1] = (float)i1;
    }
  }
  // ---- last-block-done: run pack inline (device-scope handoff) ----
  __syncthreads();
  if (t == 0) {
    __threadfence();                       // release this block's ws_idx
    const int prev = atomicAdd(done_ctr, 1);
    is_last = (prev == (int)gridDim.x - 1);
  }
  __syncthreads();
  if (is_last) {
    __threadfence();                       // acquire all blocks' ws_idx
    __shared__ int cnt[8]; __shared__ int offp[9]; __shared__ int fill[8];
    if (t < 8) cnt[t] = 0;
    __syncthreads();
    for (int a = t; a < 4096; a += 256) atomicAdd(&cnt[ws_idx[a]], 1);
    __syncthreads();
    if (t == 0) {
      offp[0] = 0;
      for (int e = 0; e < 8; e++) offp[e + 1] = offp[e] + ((cnt[e] + 63) & ~63);
    }
    __syncthreads();
    if (t < 8) fill[t] = offp[t];
    if (t < 9) offsets_g[t] = offp[t];
    for (int a = t; a < 4608; a += 256) list_token[a] = 0;  // pad rows -> token 0
    __syncthreads();
    for (int a = t; a < 4096; a += 256) {
      const int e = ws_idx[a];
      const int pos = atomicAdd(&fill[e], 1);
      list_token[pos] = a >> 1;
      a_of[a] = pos;
    }
  }
}

// --------- GEMM-1: fused bib gather (fp32->bf16 in-register), FT-B ----------
// C[rows,NT] = cvt_bf16(bib[list_token[row]]) @ B1_e ; K=512.
template <int NT, bool RELU>
__global__ __launch_bounds__(256)
void expert_gemm_g1(const float* __restrict__ bib, const int* __restrict__ list_token,
                    const bf16_t* __restrict__ Bft, const float* __restrict__ bias,
                    bf16_t* __restrict__ C, const int* __restrict__ offsets) {
  constexpr int K = 512, nk = K / 32;
  const int e = blockIdx.z;
  const int seg_hi = offsets[e + 1];
  const int blk_row = offsets[e] + blockIdx.y * 128;
  if (blk_row >= seg_hi) return;
  const int wave = threadIdx.x >> 6, lane = threadIdx.x & 63;
  const int row0 = blk_row + wave * 32;
  if (row0 >= seg_hi) return;
  const int n0 = blockIdx.x * 64;
  const int tok0 = list_token[row0 + (lane & 15)];
  const int tok1 = list_token[row0 + 16 + (lane & 15)];
  const float* Ap0 = bib + (size_t)tok0 * 512 + (lane >> 4) * 8;
  const float* Ap1 = bib + (size_t)tok1 * 512 + (lane >> 4) * 8;
  const bf16_t* Bp = Bft + (size_t)e * NT * K + ((size_t)(n0 >> 4) * nk * 512 + lane * 8);
  f32x4 acc[2][4];
#pragma unroll
  for (int i = 0; i < 2; i++)
#pragma unroll
    for (int j = 0; j < 4; j++) acc[i][j] = (f32x4){0.f, 0.f, 0.f, 0.f};
  f4x2 aS[2][2]; bf16x8 bX[2][4];
  aS[0][0] = ldA8(Ap0); aS[0][1] = ldA8(Ap1);
#pragma unroll
  for (int ni = 0; ni < 4; ni++) bX[0][ni] = *(const bf16x8*)(Bp + (size_t)ni * nk * 512);
#pragma unroll
  for (int kt = 0; kt < nk; kt++) {
    const int cur = kt & 1, nxt = cur ^ 1;
    if (kt + 1 < nk) {
      aS[nxt][0] = ldA8(Ap0 + (kt + 1) * 32);
      aS[nxt][1] = ldA8(Ap1 + (kt + 1) * 32);
#pragma unroll
      for (int ni = 0; ni < 4; ni++)
        bX[nxt][ni] = *(const bf16x8*)(Bp + ((size_t)ni * nk + kt + 1) * 512);
    }
    const bf16x8 a0 = cvt8(aS[cur][0]), a1 = cvt8(aS[cur][1]);
#pragma unroll
    for (int ni = 0; ni < 4; ni++) {
      acc[0][ni] = __builtin_amdgcn_mfma_f32_16x16x32_bf16(a0, bX[cur][ni], acc[0][ni], 0, 0, 0);
      acc[1][ni] = __builtin_amdgcn_mfma_f32_16x16x32_bf16(a1, bX[cur][ni], acc[1][ni], 0, 0, 0);
    }
  }
  const int fr = lane & 15, q = lane >> 4;
#pragma unroll
  for (int ni = 0; ni < 4; ni++) {
    const int col = n0 + ni * 16 + fr;
    const float bv = bias[e * NT + col];
#pragma unroll
    for (int mi = 0; mi < 2; mi++) {
#pragma unroll
      for (int r = 0; r < 4; r++) {
        const int row = row0 + mi * 16 + q * 4 + r;
        float v = acc[mi][ni][r] + bv;
        if (RELU) v = fmaxf(v, 0.f);
        C[(size_t)row * NT + col] = (bf16_t)v;
      }
    }
  }
}

// ---------------- expert GEMM: LDS-free, barrier-free, FT-B -----------------
// NFRAG n-fragments of 16 per block (block covers 16*NFRAG output cols).
template <int K, int NT, int NFRAG, bool RELU, typename OUT_T>
__global__ __launch_bounds__(256)
void expert_gemm_ft(const bf16_t* __restrict__ A, const bf16_t* __restrict__ Bft,
                    const float* __restrict__ bias, OUT_T* __restrict__ C,
                    const int* __restrict__ offsets) {
  constexpr int nk = K / 32;
  const int e = blockIdx.z;
  const int seg_hi = offsets[e + 1];
  const int blk_row = offsets[e] + blockIdx.y * 128;
  if (blk_row >= seg_hi) return;
  const int wave = threadIdx.x >> 6, lane = threadIdx.x & 63;
  const int row0 = blk_row + wave * 32;
  if (row0 >= seg_hi) return;  // wave-uniform
  const int n0 = blockIdx.x * (16 * NFRAG);
  const bf16_t* Ap = A + (size_t)(row0 + (lane & 15)) * K + ((lane >> 4) * 8);
  const bf16_t* Bp = Bft + (size_t)e * NT * K + ((size_t)(n0 >> 4) * nk * 512 + lane * 8);
  f32x4 acc[2][NFRAG];
#pragma unroll
  for (int i = 0; i < 2; i++)
#pragma unroll
    for (int j = 0; j < NFRAG; j++) acc[i][j] = (f32x4){0.f, 0.f, 0.f, 0.f};
  bf16x8 aX[2][2], bX[2][NFRAG];
#pragma unroll
  for (int mi = 0; mi < 2; mi++) aX[0][mi] = *(const bf16x8*)(Ap + mi * 16 * K);
#pragma unroll
  for (int ni = 0; ni < NFRAG; ni++) bX[0][ni] = *(const bf16x8*)(Bp + (size_t)ni * nk * 512);
#pragma unroll
  for (int kt = 0; kt < nk; kt++) {
    const int cur = kt & 1, nxt = cur ^ 1;
    if (kt + 1 < nk) {
#pragma unroll
      for (int mi = 0; mi < 2; mi++)
        aX[nxt][mi] = *(const bf16x8*)(Ap + mi * 16 * K + (kt + 1) * 32);
#pragma unroll
      for (int ni = 0; ni < NFRAG; ni++)
        bX[nxt][ni] = *(const bf16x8*)(Bp + ((size_t)ni * nk + kt + 1) * 512);
    }
#pragma unroll
    for (int mi = 0; mi < 2; mi++)
#pragma unroll
      for (int ni = 0; ni < NFRAG; ni++)
        acc[mi][ni] = __builtin_amdgcn_mfma_f32_16x16x32_bf16(aX[cur][mi], bX[cur][ni], acc[mi][ni], 0, 0, 0);
  }
  const int fr = lane & 15, q = lane >> 4;
#pragma unroll
  for (int ni = 0; ni < NFRAG; ni++) {
    const int col = n0 + ni * 16 + fr;
    const float bv = bias[e * NT + col];
#pragma unroll
    for (int mi = 0; mi < 2; mi++) {
#pragma unroll
      for (int r = 0; r < 4; r++) {
        const int row = row0 + mi * 16 + q * 4 + r;
        float v = acc[mi][ni][r] + bv;
        if (RELU) v = fmaxf(v, 0.f);
        C[(size_t)row * NT + col] = (OUT_T)v;
      }
    }
  }
}

// --------------------- head: combine folded logits -------------------------
// logits[b,c] = g0*OcH[a0,c] + g1*OcH[a1,c] + head_b[c]  (b3h already in OcH)
__global__ __launch_bounds__(256)
void head_small(const float* __restrict__ OcH, const int* __restrict__ a_of,
                const float* __restrict__ ws_gw, const float* __restrict__ head_b,
                float* __restrict__ out) {
  const int tid = blockIdx.x * 256 + threadIdx.x;
  if (tid >= 20480) return;
  const int b = tid / 10, c = tid - b * 10;
  const int a0 = a_of[b * 2], a1 = a_of[b * 2 + 1];
  const float g0 = ws_gw[b * 2], g1 = ws_gw[b * 2 + 1];
  out[tid] = g0 * OcH[(size_t)a0 * 16 + c] + g1 * OcH[(size_t)a1 * 16 + c] + head_b[c];
}

// ------------------------------ launch --------------------------------------
extern "C" void kernel_launch(void* const* d_in, const int* in_sizes, int n_in,
                              void* d_out, int out_size, void* d_ws, size_t ws_size,
                              hipStream_t stream) {
  const int* ipc_idx = (const int*)d_in[0];
  const int* role_idx = (const int*)d_in[1];
  const float* bib = (const float*)d_in[2];
  const int* maskp = (const int*)d_in[3];
  const float* ipc_emb = (const float*)d_in[5];
  const float* role_emb = (const float*)d_in[6];
  const float* Wq = (const float*)d_in[7];
  const float* bq = (const float*)d_in[8];
  const float* Wk = (const float*)d_in[9];
  const float* bk = (const float*)d_in[10];
  const float* Wv = (const float*)d_in[11];
  const float* bv = (const float*)d_in[12];
  const float* gc = (const float*)d_in[13];
  const float* ln_g = (const float*)d_in[14];
  const float* ln_b = (const float*)d_in[15];
  const float* gate_W = (const float*)d_in[16];
  const float* gate_b = (const float*)d_in[17];
  const float* exp_b = (const float*)d_in[18];
  const float* W1 = (const float*)d_in[19];
  const float* b1 = (const float*)d_in[20];
  const float* W2 = (const float*)d_in[21];
  const float* b2 = (const float*)d_in[22];
  const float* W3 = (const float*)d_in[23];
  const float* b3 = (const float*)d_in[24];
  const float* head_W = (const float*)d_in[25];
  const float* head_b = (const float*)d_in[26];

  char* ws = (char*)d_ws;
  size_t off = 0;
  auto alloc = [&](size_t bytes) -> char* {
    char* p = ws + off;
    off += (bytes + 255) & ~(size_t)255;
    return p;
  };
  float* kq_qbk = (float*)alloc(257 * 4);
  float* xbar_g = (float*)alloc((size_t)2048 * 256 * 4);
  int* ws_idx = (int*)alloc(4096 * 4);
  float* ws_gw = (float*)alloc(4096 * 4);
  int* list_tok = (int*)alloc(4608 * 4);
  int* a_of = (int*)alloc(4096 * 4);
  int* offs = (int*)alloc(9 * 4);
  int* done_ctr = (int*)alloc(4);
  float* b3h = (float*)alloc(8 * 16 * 4);
  bf16_t* W1t = (bf16_t*)alloc((size_t)8 * 1024 * 512 * 2);
  bf16_t* W2t = (bf16_t*)alloc((size_t)8 * 1024 * 1024 * 2);
  bf16_t* B3h = (bf16_t*)alloc((size_t)8 * 16 * 1024 * 2);
  bf16_t* H1c = (bf16_t*)alloc((size_t)4608 * 1024 * 2);
  bf16_t* H2c = (bf16_t*)alloc((size_t)4608 * 1024 * 2);
  float* OcH = (float*)alloc((size_t)4608 * 16 * 4);
  (void)in_sizes; (void)n_in; (void)out_size; (void)ws_size;

  float* out_logits = (float*)d_out;          // [2048*10]
  float* out_idx = (float*)d_out + 20480;     // [2048*2] as float

  // 32 prep blocks + 128 fold blocks (fold overlaps prep's serial q-chain)
  prep_kernel<<<160, 256, 0, stream>>>(Wq, bq, Wk, bk, gc, kq_qbk, done_ctr,
                                       head_W, b3, W3, B3h, b3h);
  // 2048 xbar + 1024 W1-transpose + 2048 W2-transpose = 5120 (r9 structure)
  xbar_transpose<<<5120, 256, 0, stream>>>(W1, W2, W1t, W2t,
                                           ipc_idx, role_idx, maskp,
                                           ipc_emb, role_emb, kq_qbk, xbar_g);
  pool_kernel<<<256, 256, 0, stream>>>(xbar_g, Wv, bv, ln_g, ln_b, gate_W, gate_b,
                                       exp_b, out_idx, ws_idx, ws_gw,
                                       done_ctr, list_tok, a_of, offs);
  expert_gemm_g1<1024, true><<<dim3(16, 36, 8), 256, 0, stream>>>(bib, list_tok, W1t, b1, H1c, offs);
  expert_gemm_ft<1024, 1024, 4, true, bf16_t><<<dim3(16, 36, 8), 256, 0, stream>>>(H1c, W2t, b2, H2c, offs);
  expert_gemm_ft<1024, 16, 1, false, float><<<dim3(1, 36, 8), 256, 0, stream>>>(H2c, B3h, b3h, OcH, offs);
  head_small<<<80, 256, 0, stream>>>(OcH, a_of, ws_gw, head_b, out_logits);
}

// Round 10
// 320.906 us; speedup vs baseline: 1.1892x; 1.0137x over previous
//
#include <hip/hip_runtime.h>
#include <hip/hip_bf16.h>
#include <math.h>

// ---------------------------------------------------------------------------
// PatentCitationMoEModule — MI355X implementation, round 16
//  Round 15 (325.3 us) plus:
//   - W1/W2 transposes MOVED from the fused kernel into prep: they have no
//     kq dependency and fill prep's ~220 idle CUs, while in the fused grid
//     they ran as a sequential ~20us tail after xbar's full-machine
//     residency generation (2048 blocks = exactly 8/CU x 256).
//   - xbar is now a pure 2048-block dispatch (clean regalloc, no co-compiled
//     transpose path) with redundant per-wave softmax: every wave reduces
//     the 64 scores itself; attn broadcast via __shfl(ev, const-lane).
//     5 barriers -> 3.
//  Keeps: pk-packed indices (no dynamic reg index), fold-in-prep,
//  pack-in-pool merge, N=16 GEMM-3, trivial head.
// ---------------------------------------------------------------------------

#define LN_EPS 1e-5f

typedef __bf16 bf16_t;
typedef __bf16 bf16x8 __attribute__((ext_vector_type(8)));
typedef __bf16 bf16x4 __attribute__((ext_vector_type(4)));
typedef float f32x4 __attribute__((ext_vector_type(4)));

struct f4x2 { float4 a, b; };
__device__ __forceinline__ f4x2 ldA8(const float* p) {
  f4x2 v; v.a = *(const float4*)p; v.b = *(const float4*)(p + 4); return v;
}
__device__ __forceinline__ bf16x8 cvt8(const f4x2& v) {
  bf16x8 o;
  o[0] = (bf16_t)v.a.x; o[1] = (bf16_t)v.a.y; o[2] = (bf16_t)v.a.z; o[3] = (bf16_t)v.a.w;
  o[4] = (bf16_t)v.b.x; o[5] = (bf16_t)v.b.y; o[6] = (bf16_t)v.b.z; o[7] = (bf16_t)v.b.w;
  return o;
}

// ------ prep: kq + b3h + MFMA W3@head_W fold + W1/W2 transpose->FT ---------
// bi 0..31    : kq_out[0..255] = Wk @ (gc@Wq + bq); kq_out[256] = q.bk;
//               bi 16..23 (wave 2) also b3h[e] = b3_e @ head_W (pad 10->16).
// bi 32..159  : fold — B3h_ft[e] = bf16(W3_e) @ bf16(head_W) into FT-B.
// bi 160..1183: W1 transpose (128 tiles/expert).
// bi 1184..   : W2 transpose (256 tiles/expert).
// kq first so its serial chain starts at t=0; transposes fill the idle CUs.
__global__ __launch_bounds__(256)
void prep_kernel(const float* __restrict__ Wq, const float* __restrict__ bq,
                 const float* __restrict__ Wk, const float* __restrict__ bk,
                 const float* __restrict__ gc, float* __restrict__ kq_out,
                 int* __restrict__ done_ctr,
                 const float* __restrict__ head_W, const float* __restrict__ b3,
                 const float* __restrict__ W3, bf16_t* __restrict__ B3h,
                 float* __restrict__ b3h_g,
                 const float* __restrict__ W1, const float* __restrict__ W2,
                 bf16_t* __restrict__ B1, bf16_t* __restrict__ B2) {
  __shared__ __align__(16) float smem[5120];  // kq: q+red; fold: head_W; transpose: 64x65
  const int t = threadIdx.x, bi = blockIdx.x;
  const int lane = t & 63, wave = t >> 6;

  if (bi >= 160) {
    // ================= W1/W2 transpose path =================
    const int bid2 = bi - 160;
    const float* W; bf16_t* Bft; int K, N, e, n0, k0;
    if (bid2 < 1024) {            // W1: K=512, N=1024, 128 tiles/expert
      W = W1; Bft = B1; K = 512; N = 1024;
      e = bid2 >> 7; const int r = bid2 & 127;
      n0 = (r & 15) * 64; k0 = (r >> 4) * 64;
    } else {                      // W2: K=1024, N=1024, 256 tiles/expert
      W = W2; Bft = B2; K = 1024; N = 1024;
      const int q = bid2 - 1024; e = q >> 8; const int r = q & 255;
      n0 = (r & 15) * 64; k0 = (r >> 4) * 64;
    }
    float (*tile)[65] = (float(*)[65])smem;  // 64x65 = 4160 floats
    const float* Wp = W + (size_t)e * K * N;
    bf16_t* Bp = Bft + (size_t)e * N * K;
    const int tq = t & 15, th = t >> 4;  // 16 x 16
#pragma unroll
    for (int i = 0; i < 4; i++) {
      const int row = th + 16 * i;  // k-dim
      *(float4*)&tile[row][tq * 4] = *(const float4*)(Wp + (size_t)(k0 + row) * N + n0 + tq * 4);
    }
    __syncthreads();
    const int sub = t >> 6;
    const int nk = K >> 5;
#pragma unroll
    for (int it = 0; it < 2; it++) {
      const int fid = sub + it * 4;            // 8 frag-tiles in a 64x64 tile
      const int ntl = fid & 3, ktl = fid >> 2;
      const int n_l = ntl * 16 + (lane & 15);
      const int k_l = ktl * 32 + (lane >> 4) * 8;
      bf16x8 o;
#pragma unroll
      for (int j = 0; j < 8; j++) o[j] = (bf16_t)tile[k_l + j][n_l];
      const size_t idx = ((((size_t)(n0 >> 4) + ntl) * nk + (k0 >> 5) + ktl) * 64 + lane) * 8;
      *(bf16x8*)(Bp + idx) = o;
    }
    return;
  }

  if (bi >= 32) {
    // ================= fold path =================
    const int bi2 = bi - 32;                  // 0..127
    const int e = bi2 >> 4, chunk = bi2 & 15;
    // stage head_W (512x10 fp32 = 20 KB) into LDS
    for (int i = t; i < 5120; i += 256) smem[i] = head_W[i];
    __syncthreads();
    const int row0 = chunk * 64 + wave * 16;
    const int c = lane & 15, koff = (lane >> 4) * 8;
    const float* Ap = W3 + ((size_t)e * 1024 + row0 + (lane & 15)) * 512 + (lane >> 4) * 8;
    f32x4 acc = (f32x4){0.f, 0.f, 0.f, 0.f};
#pragma unroll
    for (int kt = 0; kt < 16; kt++) {
      const bf16x8 a0 = cvt8(ldA8(Ap + kt * 32));
      bf16x8 b8;
#pragma unroll
      for (int j = 0; j < 8; j++) {
        const int k = kt * 32 + koff + j;
        b8[j] = (c < 10) ? (bf16_t)smem[k * 10 + c] : (bf16_t)0.f;
      }
      acc = __builtin_amdgcn_mfma_f32_16x16x32_bf16(a0, b8, acc, 0, 0, 0);
    }
    // scatter into B3h FT-B layout; jp 4-consecutive -> one 8 B store
    const int qq = lane >> 4;
    const int krow = row0 + qq * 4;
    const int ktp = krow >> 5;
    const int lanep = c | (((krow >> 3) & 3) << 4);
    const int jp = krow & 7;
    bf16x4 o4;
    o4[0] = (bf16_t)acc[0]; o4[1] = (bf16_t)acc[1];
    o4[2] = (bf16_t)acc[2]; o4[3] = (bf16_t)acc[3];
    *(bf16x4*)(B3h + (size_t)e * 16 * 1024 + ((size_t)ktp * 64 + lanep) * 8 + jp) = o4;
    return;
  }

  // ================= kq path =================
  float* q = smem;            // [256]
  float* red = smem + 256;    // [4]
  if (bi == 0 && t == 0) *done_ctr = 0;
  float s = bq[t];
  for (int d = 0; d < 256; d++) s += gc[d] * Wq[d * 256 + t];
  q[t] = s;
  __syncthreads();
  const int rl = t >> 5, sl = t & 31;
  const int r = bi * 8 + rl;
  float p = 0.f;
#pragma unroll
  for (int i = 0; i < 8; i++) { const int d = sl + 32 * i; p += Wk[r * 256 + d] * q[d]; }
#pragma unroll
  for (int o = 16; o > 0; o >>= 1) p += __shfl_down(p, o, 32);
  if (sl == 0) kq_out[r] = p;
  if (bi == 0) {
    float z2 = q[t] * bk[t];
#pragma unroll
    for (int o = 32; o > 0; o >>= 1) z2 += __shfl_down(z2, o);
    if (lane == 0) red[wave] = z2;
    __syncthreads();
    if (t == 0) kq_out[256] = red[0] + red[1] + red[2] + red[3];
  }
  // ---- b3h[e] = b3_e @ head_W (blocks 16..23, wave 2) ----
  if (bi >= 16 && bi < 24 && wave == 2) {
    const int e = bi - 16;
    float pc[10];
#pragma unroll
    for (int c2 = 0; c2 < 10; c2++) pc[c2] = 0.f;
    for (int jj = 0; jj < 8; jj++) {
      const int j = lane + jj * 64;
      const float bv = b3[e * 512 + j];
#pragma unroll
      for (int c2 = 0; c2 < 10; c2++) pc[c2] += bv * head_W[j * 10 + c2];
    }
#pragma unroll
    for (int c2 = 0; c2 < 10; c2++) {
#pragma unroll
      for (int o = 32; o > 0; o >>= 1) pc[c2] += __shfl_down(pc[c2], o);
    }
    if (lane == 0) {
#pragma unroll
      for (int c2 = 0; c2 < 10; c2++) b3h_g[e * 16 + c2] = pc[c2];
#pragma unroll
      for (int c2 = 10; c2 < 16; c2++) b3h_g[e * 16 + c2] = 0.f;
    }
  }
}

// ---------------- xbar: pure 2048-block dispatch, 3 barriers ----------------
__global__ __launch_bounds__(256)
void xbar_kernel(const int* __restrict__ ipc_idx, const int* __restrict__ role_idx,
                 const int* __restrict__ maskp,
                 const float* __restrict__ ipc_emb, const float* __restrict__ role_emb,
                 const float* __restrict__ kq_qbk, float* __restrict__ xbar_g) {
  __shared__ __align__(16) float smem[4416];  // sred[4*64*17] + scores[64]
  const int b = blockIdx.x;
  const int t = threadIdx.x, lane = t & 63, wave = t >> 6;
  float* sred = smem;                 // [4 waves][64 lanes][17] partials
  float* scores_s = smem + 4352;      // [64]
  const float4 kq = *(const float4*)(kq_qbk + lane * 4);
  const float qbk = kq_qbk[256];
  const int rbase = b * 64 + wave * 16;
  // packed row state: ii (18b) | ri<<18 (4b) | valid<<31; masked -> 0
  // (row 0 of both tables is the all-zero padding row).
  unsigned pk[16];
#pragma unroll
  for (int j = 0; j < 4; j++) {
    const int4 mm = *(const int4*)(maskp + rbase + j * 4);
    const int4 iv = *(const int4*)(ipc_idx + rbase + j * 4);
    const int4 rv = *(const int4*)(role_idx + rbase + j * 4);
    pk[j * 4 + 0] = mm.x ? ((unsigned)iv.x | ((unsigned)rv.x << 18) | 0x80000000u) : 0u;
    pk[j * 4 + 1] = mm.y ? ((unsigned)iv.y | ((unsigned)rv.y << 18) | 0x80000000u) : 0u;
    pk[j * 4 + 2] = mm.z ? ((unsigned)iv.z | ((unsigned)rv.z << 18) | 0x80000000u) : 0u;
    pk[j * 4 + 3] = mm.w ? ((unsigned)iv.w | ((unsigned)rv.w << 18) | 0x80000000u) : 0u;
  }
  // phase A: branch-free gather + per-lane dot
#pragma unroll
  for (int i = 0; i < 16; i++) {
    const unsigned p = pk[i];
    const int ii = (int)(p & 0x3FFFFu);
    const int ri = (int)((p >> 18) & 0xFu);
    const float4 xe = *(const float4*)(ipc_emb + (size_t)ii * 256 + lane * 4);
    const float4 re = *(const float4*)(role_emb + (size_t)ri * 256 + lane * 4);
    sred[(wave * 64 + lane) * 17 + i] =
        (xe.x + re.x) * kq.x + (xe.y + re.y) * kq.y +
        (xe.z + re.z) * kq.z + (xe.w + re.w) * kq.w;
  }
  __syncthreads();
  // phase B: per-wave LDS-transpose reduce; mask reloaded from memory
  // (L2-hot) — no runtime index into register arrays (rule #20).
  {
    const int i_r = lane & 15, g = lane >> 4;
    float s = 0.f;
#pragma unroll
    for (int j = 0; j < 16; j++) s += sred[(wave * 64 + g * 16 + j) * 17 + i_r];
    s += __shfl_xor(s, 16);
    s += __shfl_xor(s, 32);
    const int mval = maskp[rbase + i_r];
    if (lane < 16) scores_s[wave * 16 + lane] = mval ? (s + qbk) : -1e9f;
  }
  __syncthreads();
  // phase C' (redundant per-wave softmax) + D (re-gather + weighted sum)
  const float sv = scores_s[lane];
  float m = sv;
#pragma unroll
  for (int o = 32; o > 0; o >>= 1) m = fmaxf(m, __shfl_xor(m, o));
  const float ev = expf(sv - m);   // exactly 0 for masked rows
  float sum = ev;
#pragma unroll
  for (int o = 32; o > 0; o >>= 1) sum += __shfl_xor(sum, o);
  const float inv = 1.f / sum;
  float p0 = 0.f, p1 = 0.f, p2 = 0.f, p3 = 0.f;
#pragma unroll
  for (int i = 0; i < 16; i++) {
    const unsigned p = pk[i];
    const int ii = (int)(p & 0x3FFFFu);
    const int ri = (int)((p >> 18) & 0xFu);
    const float a = __shfl(ev, wave * 16 + i) * inv;   // const lane per i
    const float4 xe = *(const float4*)(ipc_emb + (size_t)ii * 256 + lane * 4);
    const float4 re = *(const float4*)(role_emb + (size_t)ri * 256 + lane * 4);
    p0 += a * (xe.x + re.x); p1 += a * (xe.y + re.y);
    p2 += a * (xe.z + re.z); p3 += a * (xe.w + re.w);
  }
  __syncthreads();  // all waves past phase-B reads; reuse sred as part[4][256]
  *(float4*)&smem[wave * 256 + lane * 4] = make_float4(p0, p1, p2, p3);
  __syncthreads();
  xbar_g[(size_t)b * 256 + t] = smem[t] + smem[256 + t] + smem[512 + t] + smem[768 + t];
}

// ------------- pool: pooled = xbar@Wv + bv, LN, gate, top2 ------------------
// Waves split the d(K)-range so Wv is read once per block (64 MB total).
// Last block to finish (device-scope counter) runs the pack stage inline.
__global__ __launch_bounds__(256)
void pool_kernel(const float* __restrict__ xbar_g, const float* __restrict__ Wv,
                 const float* __restrict__ bvec,
                 const float* __restrict__ ln_g, const float* __restrict__ ln_b,
                 const float* __restrict__ gate_W, const float* __restrict__ gate_b,
                 const float* __restrict__ expert_biases,
                 float* __restrict__ out_idx_f, int* __restrict__ ws_idx,
                 float* __restrict__ ws_gw, int* __restrict__ done_ctr,
                 int* __restrict__ list_token, int* __restrict__ a_of,
                 int* __restrict__ offsets_g) {
  const int rb = blockIdx.x * 8;
  __shared__ __align__(16) float xs[8][256];       // 8 input rows
  __shared__ __align__(16) float pp[4][8][256];    // per-wave d-partials
  __shared__ int is_last;
  const int t = threadIdx.x, wave = t >> 6, lane = t & 63;
  for (int i = t; i < 512; i += 256)
    ((float4*)xs)[i] = ((const float4*)(xbar_g + (size_t)rb * 256))[i];
  __syncthreads();
  f32x4 acc[8];
#pragma unroll
  for (int r = 0; r < 8; r++) acc[r] = (f32x4){0.f, 0.f, 0.f, 0.f};
  const int dbase = wave * 64;
  for (int dd = 0; dd < 64; dd += 4) {
    float4 xr[8];
#pragma unroll
    for (int r = 0; r < 8; r++) xr[r] = *(const float4*)&xs[r][dbase + dd];  // broadcast
#pragma unroll
    for (int j = 0; j < 4; j++) {
      const float4 wv = *(const float4*)(Wv + (size_t)(dbase + dd + j) * 256 + lane * 4);
#pragma unroll
      for (int r = 0; r < 8; r++) {
        const float xv = (&xr[r].x)[j];
        acc[r][0] += xv * wv.x; acc[r][1] += xv * wv.y;
        acc[r][2] += xv * wv.z; acc[r][3] += xv * wv.w;
      }
    }
  }
#pragma unroll
  for (int r = 0; r < 8; r++) *(f32x4*)&pp[wave][r][lane * 4] = acc[r];
  __syncthreads();
  const float4 bvv = *(const float4*)(bvec + lane * 4);
  const float4 lg = *(const float4*)(ln_g + lane * 4);
  const float4 lb = *(const float4*)(ln_b + lane * 4);
#pragma unroll
  for (int rr = 0; rr < 2; rr++) {
    const int r = wave * 2 + rr;
    f32x4 v = *(const f32x4*)&pp[0][r][lane * 4];
#pragma unroll
    for (int w2 = 1; w2 < 4; w2++) {
      const f32x4 qv = *(const f32x4*)&pp[w2][r][lane * 4];
      v[0] += qv[0]; v[1] += qv[1]; v[2] += qv[2]; v[3] += qv[3];
    }
    v[0] += bvv.x; v[1] += bvv.y; v[2] += bvv.z; v[3] += bvv.w;
    float s1 = v[0] + v[1] + v[2] + v[3];
#pragma unroll
    for (int o = 32; o > 0; o >>= 1) s1 += __shfl_xor(s1, o);
    const float mu = s1 * (1.f / 256.f);
    const float4 df = make_float4(v[0] - mu, v[1] - mu, v[2] - mu, v[3] - mu);
    float s2 = df.x * df.x + df.y * df.y + df.z * df.z + df.w * df.w;
#pragma unroll
    for (int o = 32; o > 0; o >>= 1) s2 += __shfl_xor(s2, o);
    const float inv = 1.f / sqrtf(s2 * (1.f / 256.f) + LN_EPS);
    f32x4 rv;
    rv[0] = df.x * inv * lg.x + lb.x; rv[1] = df.y * inv * lg.y + lb.y;
    rv[2] = df.z * inv * lg.z + lb.z; rv[3] = df.w * inv * lg.w + lb.w;
    f32x4 pa = {0.f, 0.f, 0.f, 0.f}, pb = {0.f, 0.f, 0.f, 0.f};
#pragma unroll
    for (int k = 0; k < 4; k++) {
      const int d = lane * 4 + k;
      const f32x4 g0 = *(const f32x4*)(gate_W + d * 8);
      const f32x4 g1 = *(const f32x4*)(gate_W + d * 8 + 4);
      pa += rv[k] * g0;
      pb += rv[k] * g1;
    }
#pragma unroll
    for (int o = 32; o > 0; o >>= 1) {
      pa[0] += __shfl_down(pa[0], o); pa[1] += __shfl_down(pa[1], o);
      pa[2] += __shfl_down(pa[2], o); pa[3] += __shfl_down(pa[3], o);
      pb[0] += __shfl_down(pb[0], o); pb[1] += __shfl_down(pb[1], o);
      pb[2] += __shfl_down(pb[2], o); pb[3] += __shfl_down(pb[3], o);
    }
    if (lane == 0) {
      float aff[8];
#pragma unroll
      for (int j = 0; j < 4; j++) { aff[j] = pa[j] + gate_b[j]; aff[4 + j] = pb[j] + gate_b[4 + j]; }
      float b0 = -1e30f; int i0 = 0;
#pragma unroll
      for (int j = 0; j < 8; j++) {
        const float s = aff[j] + expert_biases[j];
        if (s > b0) { b0 = s; i0 = j; }
      }
      float b1v = -1e30f; int i1 = 0;
#pragma unroll
      for (int j = 0; j < 8; j++) {
        const float s = aff[j] + expert_biases[j];
        if (j != i0 && s > b1v) { b1v = s; i1 = j; }
      }
      const float a0 = aff[i0], a1 = aff[i1];
      const float m = fmaxf(a0, a1);
      const float e0 = expf(a0 - m), e1 = expf(a1 - m);
      const float invs = 1.f / (e0 + e1);
      const int bg = rb + r;
      ws_idx[bg * 2] = i0; ws_idx[bg * 2 + 1] = i1;
      ws_gw[bg * 2] = e0 * invs; ws_gw[bg * 2 + 1] = e1 * invs;
      out_idx_f[bg * 2] = (float)i0; out_idx_f[bg * 2 + 1] = (float)i1;
    }
  }
  // ---- last-block-done: run pack inline (device-scope handoff) ----
  __syncthreads();
  if (t == 0) {
    __threadfence();                       // release this block's ws_idx
    const int prev = atomicAdd(done_ctr, 1);
    is_last = (prev == (int)gridDim.x - 1);
  }
  __syncthreads();
  if (is_last) {
    __threadfence();                       // acquire all blocks' ws_idx
    __shared__ int cnt[8]; __shared__ int offp[9]; __shared__ int fill[8];
    if (t < 8) cnt[t] = 0;
    __syncthreads();
    for (int a = t; a < 4096; a += 256) atomicAdd(&cnt[ws_idx[a]], 1);
    __syncthreads();
    if (t == 0) {
      offp[0] = 0;
      for (int e = 0; e < 8; e++) offp[e + 1] = offp[e] + ((cnt[e] + 63) & ~63);
    }
    __syncthreads();
    if (t < 8) fill[t] = offp[t];
    if (t < 9) offsets_g[t] = offp[t];
    for (int a = t; a < 4608; a += 256) list_token[a] = 0;  // pad rows -> token 0
    __syncthreads();
    for (int a = t; a < 4096; a += 256) {
      const int e = ws_idx[a];
      const int pos = atomicAdd(&fill[e], 1);
      list_token[pos] = a >> 1;
      a_of[a] = pos;
    }
  }
}

// --------- GEMM-1: fused bib gather (fp32->bf16 in-register), FT-B ----------
// C[rows,NT] = cvt_bf16(bib[list_token[row]]) @ B1_e ; K=512.
template <int NT, bool RELU>
__global__ __launch_bounds__(256)
void expert_gemm_g1(const float* __restrict__ bib, const int* __restrict__ list_token,
                    const bf16_t* __restrict__ Bft, const float* __restrict__ bias,
                    bf16_t* __restrict__ C, const int* __restrict__ offsets) {
  constexpr int K = 512, nk = K / 32;
  const int e = blockIdx.z;
  const int seg_hi = offsets[e + 1];
  const int blk_row = offsets[e] + blockIdx.y * 128;
  if (blk_row >= seg_hi) return;
  const int wave = threadIdx.x >> 6, lane = threadIdx.x & 63;
  const int row0 = blk_row + wave * 32;
  if (row0 >= seg_hi) return;
  const int n0 = blockIdx.x * 64;
  const int tok0 = list_token[row0 + (lane & 15)];
  const int tok1 = list_token[row0 + 16 + (lane & 15)];
  const float* Ap0 = bib + (size_t)tok0 * 512 + (lane >> 4) * 8;
  const float* Ap1 = bib + (size_t)tok1 * 512 + (lane >> 4) * 8;
  const bf16_t* Bp = Bft + (size_t)e * NT * K + ((size_t)(n0 >> 4) * nk * 512 + lane * 8);
  f32x4 acc[2][4];
#pragma unroll
  for (int i = 0; i < 2; i++)
#pragma unroll
    for (int j = 0; j < 4; j++) acc[i][j] = (f32x4){0.f, 0.f, 0.f, 0.f};
  f4x2 aS[2][2]; bf16x8 bX[2][4];
  aS[0][0] = ldA8(Ap0); aS[0][1] = ldA8(Ap1);
#pragma unroll
  for (int ni = 0; ni < 4; ni++) bX[0][ni] = *(const bf16x8*)(Bp + (size_t)ni * nk * 512);
#pragma unroll
  for (int kt = 0; kt < nk; kt++) {
    const int cur = kt & 1, nxt = cur ^ 1;
    if (kt + 1 < nk) {
      aS[nxt][0] = ldA8(Ap0 + (kt + 1) * 32);
      aS[nxt][1] = ldA8(Ap1 + (kt + 1) * 32);
#pragma unroll
      for (int ni = 0; ni < 4; ni++)
        bX[nxt][ni] = *(const bf16x8*)(Bp + ((size_t)ni * nk + kt + 1) * 512);
    }
    const bf16x8 a0 = cvt8(aS[cur][0]), a1 = cvt8(aS[cur][1]);
#pragma unroll
    for (int ni = 0; ni < 4; ni++) {
      acc[0][ni] = __builtin_amdgcn_mfma_f32_16x16x32_bf16(a0, bX[cur][ni], acc[0][ni], 0, 0, 0);
      acc[1][ni] = __builtin_amdgcn_mfma_f32_16x16x32_bf16(a1, bX[cur][ni], acc[1][ni], 0, 0, 0);
    }
  }
  const int fr = lane & 15, q = lane >> 4;
#pragma unroll
  for (int ni = 0; ni < 4; ni++) {
    const int col = n0 + ni * 16 + fr;
    const float bv = bias[e * NT + col];
#pragma unroll
    for (int mi = 0; mi < 2; mi++) {
#pragma unroll
      for (int r = 0; r < 4; r++) {
        const int row = row0 + mi * 16 + q * 4 + r;
        float v = acc[mi][ni][r] + bv;
        if (RELU) v = fmaxf(v, 0.f);
        C[(size_t)row * NT + col] = (bf16_t)v;
      }
    }
  }
}

// ---------------- expert GEMM: LDS-free, barrier-free, FT-B -----------------
// NFRAG n-fragments of 16 per block (block covers 16*NFRAG output cols).
template <int K, int NT, int NFRAG, bool RELU, typename OUT_T>
__global__ __launch_bounds__(256)
void expert_gemm_ft(const bf16_t* __restrict__ A, const bf16_t* __restrict__ Bft,
                    const float* __restrict__ bias, OUT_T* __restrict__ C,
                    const int* __restrict__ offsets) {
  constexpr int nk = K / 32;
  const int e = blockIdx.z;
  const int seg_hi = offsets[e + 1];
  const int blk_row = offsets[e] + blockIdx.y * 128;
  if (blk_row >= seg_hi) return;
  const int wave = threadIdx.x >> 6, lane = threadIdx.x & 63;
  const int row0 = blk_row + wave * 32;
  if (row0 >= seg_hi) return;  // wave-uniform
  const int n0 = blockIdx.x * (16 * NFRAG);
  const bf16_t* Ap = A + (size_t)(row0 + (lane & 15)) * K + ((lane >> 4) * 8);
  const bf16_t* Bp = Bft + (size_t)e * NT * K + ((size_t)(n0 >> 4) * nk * 512 + lane * 8);
  f32x4 acc[2][NFRAG];
#pragma unroll
  for (int i = 0; i < 2; i++)
#pragma unroll
    for (int j = 0; j < NFRAG; j++) acc[i][j] = (f32x4){0.f, 0.f, 0.f, 0.f};
  bf16x8 aX[2][2], bX[2][NFRAG];
#pragma unroll
  for (int mi = 0; mi < 2; mi++) aX[0][mi] = *(const bf16x8*)(Ap + mi * 16 * K);
#pragma unroll
  for (int ni = 0; ni < NFRAG; ni++) bX[0][ni] = *(const bf16x8*)(Bp + (size_t)ni * nk * 512);
#pragma unroll
  for (int kt = 0; kt < nk; kt++) {
    const int cur = kt & 1, nxt = cur ^ 1;
    if (kt + 1 < nk) {
#pragma unroll
      for (int mi = 0; mi < 2; mi++)
        aX[nxt][mi] = *(const bf16x8*)(Ap + mi * 16 * K + (kt + 1) * 32);
#pragma unroll
      for (int ni = 0; ni < NFRAG; ni++)
        bX[nxt][ni] = *(const bf16x8*)(Bp + ((size_t)ni * nk + kt + 1) * 512);
    }
#pragma unroll
    for (int mi = 0; mi < 2; mi++)
#pragma unroll
      for (int ni = 0; ni < NFRAG; ni++)
        acc[mi][ni] = __builtin_amdgcn_mfma_f32_16x16x32_bf16(aX[cur][mi], bX[cur][ni], acc[mi][ni], 0, 0, 0);
  }
  const int fr = lane & 15, q = lane >> 4;
#pragma unroll
  for (int ni = 0; ni < NFRAG; ni++) {
    const int col = n0 + ni * 16 + fr;
    const float bv = bias[e * NT + col];
#pragma unroll
    for (int mi = 0; mi < 2; mi++) {
#pragma unroll
      for (int r = 0; r < 4; r++) {
        const int row = row0 + mi * 16 + q * 4 + r;
        float v = acc[mi][ni][r] + bv;
        if (RELU) v = fmaxf(v, 0.f);
        C[(size_t)row * NT + col] = (OUT_T)v;
      }
    }
  }
}

// --------------------- head: combine folded logits -------------------------
// logits[b,c] = g0*OcH[a0,c] + g1*OcH[a1,c] + head_b[c]  (b3h already in OcH)
__global__ __launch_bounds__(256)
void head_small(const float* __restrict__ OcH, const int* __restrict__ a_of,
                const float* __restrict__ ws_gw, const float* __restrict__ head_b,
                float* __restrict__ out) {
  const int tid = blockIdx.x * 256 + threadIdx.x;
  if (tid >= 20480) return;
  const int b = tid / 10, c = tid - b * 10;
  const int a0 = a_of[b * 2], a1 = a_of[b * 2 + 1];
  const float g0 = ws_gw[b * 2], g1 = ws_gw[b * 2 + 1];
  out[tid] = g0 * OcH[(size_t)a0 * 16 + c] + g1 * OcH[(size_t)a1 * 16 + c] + head_b[c];
}

// ------------------------------ launch --------------------------------------
extern "C" void kernel_launch(void* const* d_in, const int* in_sizes, int n_in,
                              void* d_out, int out_size, void* d_ws, size_t ws_size,
                              hipStream_t stream) {
  const int* ipc_idx = (const int*)d_in[0];
  const int* role_idx = (const int*)d_in[1];
  const float* bib = (const float*)d_in[2];
  const int* maskp = (const int*)d_in[3];
  const float* ipc_emb = (const float*)d_in[5];
  const float* role_emb = (const float*)d_in[6];
  const float* Wq = (const float*)d_in[7];
  const float* bq = (const float*)d_in[8];
  const float* Wk = (const float*)d_in[9];
  const float* bk = (const float*)d_in[10];
  const float* Wv = (const float*)d_in[11];
  const float* bv = (const float*)d_in[12];
  const float* gc = (const float*)d_in[13];
  const float* ln_g = (const float*)d_in[14];
  const float* ln_b = (const float*)d_in[15];
  const float* gate_W = (const float*)d_in[16];
  const float* gate_b = (const float*)d_in[17];
  const float* exp_b = (const float*)d_in[18];
  const float* W1 = (const float*)d_in[19];
  const float* b1 = (const float*)d_in[20];
  const float* W2 = (const float*)d_in[21];
  const float* b2 = (const float*)d_in[22];
  const float* W3 = (const float*)d_in[23];
  const float* b3 = (const float*)d_in[24];
  const float* head_W = (const float*)d_in[25];
  const float* head_b = (const float*)d_in[26];

  char* ws = (char*)d_ws;
  size_t off = 0;
  auto alloc = [&](size_t bytes) -> char* {
    char* p = ws + off;
    off += (bytes + 255) & ~(size_t)255;
    return p;
  };
  float* kq_qbk = (float*)alloc(257 * 4);
  float* xbar_g = (float*)alloc((size_t)2048 * 256 * 4);
  int* ws_idx = (int*)alloc(4096 * 4);
  float* ws_gw = (float*)alloc(4096 * 4);
  int* list_tok = (int*)alloc(4608 * 4);
  int* a_of = (int*)alloc(4096 * 4);
  int* offs = (int*)alloc(9 * 4);
  int* done_ctr = (int*)alloc(4);
  float* b3h = (float*)alloc(8 * 16 * 4);
  bf16_t* W1t = (bf16_t*)alloc((size_t)8 * 1024 * 512 * 2);
  bf16_t* W2t = (bf16_t*)alloc((size_t)8 * 1024 * 1024 * 2);
  bf16_t* B3h = (bf16_t*)alloc((size_t)8 * 16 * 1024 * 2);
  bf16_t* H1c = (bf16_t*)alloc((size_t)4608 * 1024 * 2);
  bf16_t* H2c = (bf16_t*)alloc((size_t)4608 * 1024 * 2);
  float* OcH = (float*)alloc((size_t)4608 * 16 * 4);
  (void)in_sizes; (void)n_in; (void)out_size; (void)ws_size;

  float* out_logits = (float*)d_out;          // [2048*10]
  float* out_idx = (float*)d_out + 20480;     // [2048*2] as float

  // 32 kq + 128 fold + 1024 W1-transpose + 2048 W2-transpose = 3232
  prep_kernel<<<3232, 256, 0, stream>>>(Wq, bq, Wk, bk, gc, kq_qbk, done_ctr,
                                        head_W, b3, W3, B3h, b3h,
                                        W1, W2, W1t, W2t);
  xbar_kernel<<<2048, 256, 0, stream>>>(ipc_idx, role_idx, maskp,
                                        ipc_emb, role_emb, kq_qbk, xbar_g);
  pool_kernel<<<256, 256, 0, stream>>>(xbar_g, Wv, bv, ln_g, ln_b, gate_W, gate_b,
                                       exp_b, out_idx, ws_idx, ws_gw,
                                       done_ctr, list_tok, a_of, offs);
  expert_gemm_g1<1024, true><<<dim3(16, 36, 8), 256, 0, stream>>>(bib, list_tok, W1t, b1, H1c, offs);
  expert_gemm_ft<1024, 1024, 4, true, bf16_t><<<dim3(16, 36, 8), 256, 0, stream>>>(H1c, W2t, b2, H2c, offs);
  expert_gemm_ft<1024, 16, 1, false, float><<<dim3(1, 36, 8), 256, 0, stream>>>(H2c, B3h, b3h, OcH, offs);
  head_small<<<80, 256, 0, stream>>>(OcH, a_of, ws_gw, head_b, out_logits);
}